// Round 18
// baseline (223.269 us; speedup 1.0000x reference)
//
#include <hip/hip_runtime.h>
#include <math.h>

#define NN 20000   // nodes
#define NE 480000  // edges
#define NB 4       // batch
#define ND 32      // dim
#define NR 474     // relations
#define NL 3       // layers
#define NT 64      // tails
#define M_TOT (NB * NN)   // 80000 node-rows
#define LROW 168          // padded LDS row (bf16 units)
#define AFF_CAP 1024      // layer-0 affected entries (~100)

typedef __attribute__((ext_vector_type(8))) short bf16x8v;
typedef __attribute__((ext_vector_type(4))) float f32x4v;

// RNE split of f32 into bf16 hi + bf16 lo (a ~= hi + lo, err ~2^-18 rel)
__device__ inline void bf16split(float a, unsigned short& h, unsigned short& l) {
    unsigned u = __float_as_uint(a);
    unsigned r = u + 0x7FFFu + ((u >> 16) & 1u);
    h = (unsigned short)(r >> 16);
    float fh = __uint_as_float((unsigned)h << 16);
    float res = a - fh;
    unsigned v = __float_as_uint(res);
    unsigned r2 = v + 0x7FFFu + ((v >> 16) & 1u);
    l = (unsigned short)(r2 >> 16);
}

// ---------------- CSR build ----------------
__global__ __launch_bounds__(256) void count_kernel(const int* __restrict__ dst,
                                                    int* __restrict__ indeg) {
    int e = blockIdx.x * blockDim.x + threadIdx.x;
    if (e < NE) atomicAdd(&indeg[dst[e]], 1);
}

// parallel per-node prep: wave-scan + ONE atomic per wave for the slab allocator
__global__ __launch_bounds__(256) void nodeprep_kernel(
    const int* __restrict__ indeg, int* __restrict__ offsets,
    int* __restrict__ bucketCnt, float* __restrict__ logsum,
    int* __restrict__ edgeTotal) {
    __shared__ int hcnt[256];
    int t = threadIdx.x;
    hcnt[t] = 0;
    __syncthreads();

    int n = blockIdx.x * 256 + t;
    int lane = t & 63;
    int dg = (n < NN) ? indeg[n] : 0;
    float v = (n < NN) ? logf((float)(dg + 2)) : 0.f;   // log(deg+1), deg = indeg+1

    int inc = dg;
    #pragma unroll
    for (int o = 1; o < 64; o <<= 1) {
        int u = __shfl_up(inc, o, 64);
        if (lane >= o) inc += u;
    }
    int waveTot = __shfl(inc, 63, 64);
    int base = 0;
    if (lane == 63) base = atomicAdd(edgeTotal, waveTot);   // 1 atomic per wave
    base = __shfl(base, 63, 64);
    if (n < NN) {
        offsets[n] = base + inc - dg;
        atomicAdd(&hcnt[dg > 255 ? 255 : dg], 1);           // LDS histogram
    }
    #pragma unroll
    for (int o = 32; o > 0; o >>= 1) v += __shfl_down(v, o, 64);
    if (lane == 0) atomicAdd(logsum, v);
    __syncthreads();
    if (hcnt[t]) atomicAdd(&bucketCnt[t], hcnt[t]);         // spread over 256 addrs
}

// 1-block: exclusive prefix over bucket counts + zero-background gate flags
__global__ __launch_bounds__(256) void bucket_prefix_kernel(
    const int* __restrict__ bucketCnt, int* __restrict__ bucketCursor,
    const float* __restrict__ layer_b, int* __restrict__ zb) {
    __shared__ int s[256];
    int t = threadIdx.x;
    s[t] = bucketCnt[t];
    __syncthreads();
    for (int off = 1; off < 256; off <<= 1) {
        int v = (t >= off) ? s[t - off] : 0;
        __syncthreads();
        s[t] += v;
        __syncthreads();
    }
    bucketCursor[t] = s[t] - bucketCnt[t];       // exclusive base
    if (t == 0) {
        int a = 1, b = 1;
        for (int j = 0; j < ND; ++j) {
            if (layer_b[j] > 0.f) a = 0;
            if (layer_b[ND + j] > 0.f) b = 0;
        }
        zb[0] = a;            // background of hidden1 is zero
        zb[1] = a && b;       // background of hidden2 is zero
    }
}

// parallel per-node: block-level two-phase bucket placement (LDS rank + slab atomic)
__global__ __launch_bounds__(256) void sortmap_kernel(
    const int* __restrict__ indeg, const int* __restrict__ offsets,
    int* __restrict__ bucketCursor, const float* __restrict__ logsum,
    int* __restrict__ ipern, int2* __restrict__ begdeg,
    float2* __restrict__ scales2, int* __restrict__ hpos,
    const int* __restrict__ h_index) {
    __shared__ int hcnt[256];
    __shared__ int hbase[256];
    int t = threadIdx.x;
    hcnt[t] = 0;
    __syncthreads();

    int n = blockIdx.x * 256 + t;
    int dg = 0, bkt = 0, rank = 0;
    if (n < NN) {
        dg = indeg[n];
        bkt = dg > 255 ? 255 : dg;
        rank = atomicAdd(&hcnt[bkt], 1);         // intra-block rank (LDS)
    }
    __syncthreads();
    if (hcnt[t]) hbase[t] = atomicAdd(&bucketCursor[t], hcnt[t]);  // slab per (block,bucket)
    __syncthreads();
    if (n >= NN) return;
    int pos = hbase[bkt] + rank;
    ipern[n] = pos;
    begdeg[pos] = make_int2(offsets[n], dg);
    float fac = (float)NN / *logsum;
    float scl = logf((float)(dg + 2)) * fac;
    scales2[pos] = make_float2(scl, 1.0f / fmaxf(scl, 1e-2f));
    #pragma unroll
    for (int b = 0; b < NB; ++b)
        if (n == h_index[b]) hpos[b] = pos;
}

// csr scatter + layer-0 frontier marking (f1 flags + affList) + head rows (tail block)
#define SCAT_BLKS (NE / 256)   // 1875 exact
__global__ __launch_bounds__(256) void scatter_kernel(const int* __restrict__ src,
                                                      const int* __restrict__ dst,
                                                      const int* __restrict__ etype,
                                                      const int* __restrict__ offsets,
                                                      const int* __restrict__ ipern,
                                                      int* __restrict__ cursor,
                                                      int2* __restrict__ csr,
                                                      const int* __restrict__ h_index,
                                                      const int* __restrict__ hpos,
                                                      unsigned char* __restrict__ f1,
                                                      int* __restrict__ affCnt,
                                                      int4* __restrict__ affList) {
    if (blockIdx.x == SCAT_BLKS) {               // head rows
        int b = threadIdx.x;
        if (b < NB) {
            int hp = hpos[b];
            f1[b * NN + hp] = 1;
            int p = atomicAdd(affCnt, 1);
            if (p < AFF_CAP) affList[p] = make_int4(b, hp, -1, 0);
        }
        return;
    }
    int e = blockIdx.x * 256 + threadIdx.x;
    int dn = dst[e];
    int sn = src[e];
    int pos = atomicAdd(&cursor[dn], 1);
    csr[offsets[dn] + pos] = make_int2(ipern[sn] * (ND * 4), etype[e] * (ND * 4));
    #pragma unroll
    for (int b = 0; b < NB; ++b) {
        if (sn == h_index[b]) {
            int dp = ipern[dn];
            f1[b * NN + dp] = 1;
            int p = atomicAdd(affCnt, 1);
            if (p < AFF_CAP) affList[p] = make_int4(b, dp, etype[e], 0);
        }
    }
}

// frontier propagation: rows with any in-edge from a flagged src get flagged
__global__ __launch_bounds__(256) void mark_kernel(
    const int* __restrict__ src, const int* __restrict__ dst,
    const int* __restrict__ ipern,
    const unsigned char* __restrict__ fa, const unsigned char* __restrict__ fb,
    unsigned char* __restrict__ fout) {
    int e = blockIdx.x * 256 + threadIdx.x;
    if (e >= NE) return;
    int sp = ipern[src[e]];
    int dp = -1;
    #pragma unroll
    for (int b = 0; b < NB; ++b) {
        if (fa[b * NN + sp] | fb[b * NN + sp]) {
            if (dp < 0) dp = ipern[dst[e]];
            fout[b * NN + dp] = 1;
        }
    }
}

// compact (fa|fb|fc | !zb[zidx]) over (b,pos) space into a work list
__global__ __launch_bounds__(256) void compact_kernel(
    const unsigned char* __restrict__ fa, const unsigned char* __restrict__ fb,
    const unsigned char* __restrict__ fc, const int* __restrict__ zb, int zidx,
    int* __restrict__ cnt, int* __restrict__ list) {
    int i = blockIdx.x * 256 + threadIdx.x;
    bool take = false;
    if (i < M_TOT) take = (!zb[zidx]) || fa[i] || fb[i] || fc[i];
    unsigned long long m = __ballot(take);
    int lane = threadIdx.x & 63;
    int nw = __popcll(m);
    int base = 0;
    if (lane == 0 && nw) base = atomicAdd(cnt, nw);
    base = __shfl(base, 0, 64);
    if (take) list[base + __popcll(m & ((1ULL << lane) - 1))] = i;
}

// uniform-background fill: out = relu(bias) everywhere (list kernel overwrites frontier)
__global__ __launch_bounds__(256) void fill_kernel(float* __restrict__ hnew,
                                                   const float* __restrict__ bias) {
    __shared__ float rb[ND];
    if (threadIdx.x < ND) rb[threadIdx.x] = fmaxf(bias[threadIdx.x], 0.f);
    __syncthreads();
    int i = blockIdx.x * 256 + threadIdx.x;      // over M_TOT*8 float4 slots
    if (i >= M_TOT * 8) return;
    int q = (i & 7) * 4;
    ((float4*)hnew)[i] = make_float4(rb[q], rb[q + 1], rb[q + 2], rb[q + 3]);
}

// layer-0 exact recompute for affected rows (messages = q (x) rel0[et] only)
__global__ __launch_bounds__(64) void fixup_kernel(
    float* __restrict__ hnew,
    const float* __restrict__ rel0, const float* __restrict__ W0,
    const float* __restrict__ bias, const float2* __restrict__ scales2,
    const int2* __restrict__ begdeg,
    const int* __restrict__ hpos, const int* __restrict__ r_index,
    const float* __restrict__ qw,
    const int* __restrict__ affCnt, const int4* __restrict__ affList) {
    __shared__ float F[5][ND];
    __shared__ int4 ent[AFF_CAP];
    int cnt = *affCnt;
    if (cnt > AFF_CAP) cnt = AFF_CAP;
    int t = threadIdx.x;
    for (int i = t; i < cnt; i += 64) ent[i] = affList[i];
    __syncthreads();
    if (blockIdx.x >= cnt) return;

    int4 me = ent[blockIdx.x];
    int b = me.x, row = me.y;
    for (int i = 0; i < (int)blockIdx.x; ++i) {      // dedupe
        int4 o = ent[i];
        if (o.x == b && o.y == row) return;
    }
    int hp = hpos[b];
    const float* q = qw + r_index[b] * ND;
    int deg = begdeg[row].y;

    if (t < ND) {
        int j = t;
        float qj = q[j];
        int nhead = 0;
        float s = 0.f, ss = 0.f, mx = -INFINITY, mn = INFINITY;
        for (int i = 0; i < cnt; ++i) {
            int4 o = ent[i];
            if (o.x == b && o.y == row && o.z >= 0) {
                float m = qj * rel0[((size_t)b * NR + o.z) * ND + j];
                s += m; ss = fmaf(m, m, ss);
                mx = fmaxf(mx, m); mn = fminf(mn, m);
                ++nhead;
            }
        }
        float bm = (row == hp) ? qj : 0.f;
        s += bm; ss = fmaf(bm, bm, ss);
        mx = fmaxf(mx, bm); mn = fminf(mn, bm);
        if (deg - nhead > 0) { mx = fmaxf(mx, 0.f); mn = fminf(mn, 0.f); }
        float inv = 1.0f / (float)(deg + 1);
        float mean = s * inv;
        F[0][j] = bm;
        F[1][j] = mean;
        F[2][j] = mx;
        F[3][j] = mn;
        F[4][j] = sqrtf(fmaxf(ss * inv - mean * mean, 0.f));
    }
    __syncthreads();

    int j = t & 31, kh = t >> 5;
    float2 sc = scales2[row];
    float acc = (kh == 0) ? bias[j] : 0.f;
    #pragma unroll
    for (int kk = 0; kk < 16; ++kk) {
        int k = kh * 16 + kk;
        acc = fmaf(F[0][k], W0[k * 32 + j], acc);
    }
    #pragma unroll
    for (int f = 1; f < 5; ++f) {
        #pragma unroll
        for (int kk = 0; kk < 16; ++kk) {
            int k = kh * 16 + kk;
            float a = F[f][k];
            int r0 = (f - 1) * 32 + 32 + k;
            acc = fmaf(a, W0[r0 * 32 + j], acc);
            acc = fmaf(a * sc.x, W0[(r0 + 128) * 32 + j], acc);
            acc = fmaf(a * sc.y, W0[(r0 + 256) * 32 + j], acc);
        }
    }
    acc += __shfl_down(acc, 32, 64);
    if (t < ND) {
        size_t o = ((size_t)b * NN + row) * ND + j;
        hnew[o] = fmaxf(acc, 0.f) + F[0][j];
    }
}

// ---------------- rel embeddings (4 batches/thread) + W pack, one kernel ----------------
#define REL_T (NL * NR * ND)              // 45504
#define REL_BLOCKS ((REL_T + 255) / 256)  // 178
__global__ __launch_bounds__(256) void relwpack_kernel(
    const float* __restrict__ qw, const int* __restrict__ r_index,
    const float* __restrict__ rlw, float* __restrict__ rel,
    const float* __restrict__ W, unsigned short* __restrict__ Wph,
    unsigned short* __restrict__ Wpl) {
    if (blockIdx.x < REL_BLOCKS) {
        int i = blockIdx.x * 256 + threadIdx.x;
        if (i >= REL_T) return;
        int d = i & (ND - 1);
        int rd = i >> 5;
        int r = rd % NR;
        int l = rd / NR;
        const float* q0 = qw + r_index[0] * ND;
        const float* q1 = qw + r_index[1] * ND;
        const float* q2 = qw + r_index[2] * ND;
        const float* q3 = qw + r_index[3] * ND;
        const float* w = rlw + (size_t)l * ND * NR * ND + (size_t)r * ND + d;
        float a0 = 0.f, a1 = 0.f, a2 = 0.f, a3 = 0.f;
        #pragma unroll
        for (int k = 0; k < ND; ++k) {
            float wk = w[(size_t)k * NR * ND];
            a0 = fmaf(q0[k], wk, a0); a1 = fmaf(q1[k], wk, a1);
            a2 = fmaf(q2[k], wk, a2); a3 = fmaf(q3[k], wk, a3);
        }
        size_t o = ((size_t)l * NB * NR + r) * ND + d;
        rel[o] = a0;
        rel[o + (size_t)NR * ND] = a1;
        rel[o + (size_t)2 * NR * ND] = a2;
        rel[o + (size_t)3 * NR * ND] = a3;
    } else {
        int t = (blockIdx.x - REL_BLOCKS) * 256 + threadIdx.x;
        if (t >= NL * 2 * 13 * 64) return;
        int lane = t & 63;
        int u = t >> 6;
        int s = u % 13;
        int nt = (u / 13) % 2;
        int l = u / 26;
        int n = nt * 16 + (lane & 15);
        int k0 = s * 32 + (lane >> 4) * 8;
        size_t ob = (size_t)t * 8;
        #pragma unroll
        for (int e = 0; e < 8; ++e) {
            float w = W[(size_t)l * 416 * 32 + (size_t)(k0 + e) * 32 + n];
            unsigned short h8, l8;
            bf16split(w, h8, l8);
            Wph[ob + e] = h8;
            Wpl[ob + e] = l8;
        }
    }
}

// ---------------- list-driven fused layer (R14 body; rows from work list) ----------------
__global__ __launch_bounds__(256, 4) void list_layer_kernel(
    const float* __restrict__ hin, float* __restrict__ hnew,
    const float* __restrict__ rel,               // [B][R][D] this layer
    const unsigned short* __restrict__ Wph, const unsigned short* __restrict__ Wpl,
    const float* __restrict__ bias, const float2* __restrict__ scales2,
    const int2* __restrict__ begdeg, const int2* __restrict__ csr,
    const int* __restrict__ hpos, const int* __restrict__ r_index,
    const float* __restrict__ qw,
    const int* __restrict__ cnt, const int* __restrict__ list) {
    __shared__ __align__(16) unsigned short ldsAh[32][LROW];
    __shared__ __align__(16) unsigned short ldsAl[32][LROW];

    int n = *cnt;
    int blk = blockIdx.x;
    if (blk * 32 >= n) return;                   // block-uniform early exit

    int tid = threadIdx.x;
    int lane = tid & 63;
    int w = tid >> 6;                            // 0..3
    int r8 = lane >> 3;
    int d0 = (lane & 7) * 4;                     // dim quartet
    int d4 = d0 * 4;                             // byte offset
    int rowl = w * 8 + r8;                       // 0..31
    int li = blk * 32 + rowl;
    bool act = li < n;
    int idx = act ? list[li] : list[0];          // dummy -> valid row 0
    int b = idx / NN;
    int sidx = idx - b * NN;
    const char* hbB = (const char*)hin + (size_t)b * (NN * ND * 4) + d4;
    const char* reB = (const char*)rel + (size_t)b * (NR * ND * 4) + d4;

    float sv[4], ssv[4], mxv[4], mnv[4];
    {
        float4 bm4 = make_float4(0.f, 0.f, 0.f, 0.f);
        if (sidx == hpos[b]) bm4 = *(const float4*)(qw + r_index[b] * ND + d0);
        float bm[4] = {bm4.x, bm4.y, bm4.z, bm4.w};
        #pragma unroll
        for (int c = 0; c < 4; ++c) {
            sv[c] = bm[c]; ssv[c] = bm[c] * bm[c]; mxv[c] = bm[c]; mnv[c] = bm[c];
        }
    }

    int2 bd = begdeg[sidx];
    int beg = bd.x, dg = bd.y, end = beg + dg;
#define EDGE1(E)                                                                  \
    {                                                                             \
        int2 a0 = csr[E];                                                         \
        float4 h0 = *(const float4*)(hbB + a0.x);                                 \
        float4 r0 = *(const float4*)(reB + a0.y);                                 \
        float m0[4] = {h0.x * r0.x, h0.y * r0.y, h0.z * r0.z, h0.w * r0.w};       \
        _Pragma("unroll")                                                         \
        for (int c = 0; c < 4; ++c) {                                             \
            sv[c] += m0[c];                                                       \
            ssv[c] = fmaf(m0[c], m0[c], ssv[c]);                                  \
            mxv[c] = fmaxf(mxv[c], m0[c]);                                        \
            mnv[c] = fminf(mnv[c], m0[c]);                                        \
        }                                                                         \
    }
    int e = beg;
    if ((e & 1) && e < end) { EDGE1(e); ++e; }   // align to 16B for int4 loads
    int n8 = (end - e) >> 3;                     // 8-edge chunks
    const int4* cp = (const int4*)(csr + e);
    e += n8 * 8;
    int4 k0, k1, k2, k3;
    if (n8 > 0) { k0 = cp[0]; k1 = cp[1]; k2 = cp[2]; k3 = cp[3]; }
    for (int i = 0; i < n8; ++i) {
        float4 h0 = *(const float4*)(hbB + k0.x), r0 = *(const float4*)(reB + k0.y);
        float4 h1 = *(const float4*)(hbB + k0.z), r1 = *(const float4*)(reB + k0.w);
        float4 h2 = *(const float4*)(hbB + k1.x), r2 = *(const float4*)(reB + k1.y);
        float4 h3 = *(const float4*)(hbB + k1.z), r3 = *(const float4*)(reB + k1.w);
        float4 h4 = *(const float4*)(hbB + k2.x), r4 = *(const float4*)(reB + k2.y);
        float4 h5 = *(const float4*)(hbB + k2.z), r5 = *(const float4*)(reB + k2.w);
        float4 h6 = *(const float4*)(hbB + k3.x), r6 = *(const float4*)(reB + k3.y);
        float4 h7 = *(const float4*)(hbB + k3.z), r7 = *(const float4*)(reB + k3.w);
        cp += 4;
        if (i + 1 < n8) { k0 = cp[0]; k1 = cp[1]; k2 = cp[2]; k3 = cp[3]; }
        float m0[4] = {h0.x * r0.x, h0.y * r0.y, h0.z * r0.z, h0.w * r0.w};
        float m1[4] = {h1.x * r1.x, h1.y * r1.y, h1.z * r1.z, h1.w * r1.w};
        float m2[4] = {h2.x * r2.x, h2.y * r2.y, h2.z * r2.z, h2.w * r2.w};
        float m3[4] = {h3.x * r3.x, h3.y * r3.y, h3.z * r3.z, h3.w * r3.w};
        float m4[4] = {h4.x * r4.x, h4.y * r4.y, h4.z * r4.z, h4.w * r4.w};
        float m5[4] = {h5.x * r5.x, h5.y * r5.y, h5.z * r5.z, h5.w * r5.w};
        float m6[4] = {h6.x * r6.x, h6.y * r6.y, h6.z * r6.z, h6.w * r6.w};
        float m7[4] = {h7.x * r7.x, h7.y * r7.y, h7.z * r7.z, h7.w * r7.w};
        #pragma unroll
        for (int c = 0; c < 4; ++c) {
            sv[c] += ((m0[c] + m1[c]) + (m2[c] + m3[c])) +
                     ((m4[c] + m5[c]) + (m6[c] + m7[c]));
            ssv[c] = fmaf(m0[c], m0[c], ssv[c]);
            ssv[c] = fmaf(m1[c], m1[c], ssv[c]);
            ssv[c] = fmaf(m2[c], m2[c], ssv[c]);
            ssv[c] = fmaf(m3[c], m3[c], ssv[c]);
            ssv[c] = fmaf(m4[c], m4[c], ssv[c]);
            ssv[c] = fmaf(m5[c], m5[c], ssv[c]);
            ssv[c] = fmaf(m6[c], m6[c], ssv[c]);
            ssv[c] = fmaf(m7[c], m7[c], ssv[c]);
            mxv[c] = fmaxf(fmaxf(mxv[c], m0[c]), m1[c]);
            mxv[c] = fmaxf(fmaxf(mxv[c], m2[c]), m3[c]);
            mxv[c] = fmaxf(fmaxf(mxv[c], m4[c]), m5[c]);
            mxv[c] = fmaxf(fmaxf(mxv[c], m6[c]), m7[c]);
            mnv[c] = fminf(fminf(mnv[c], m0[c]), m1[c]);
            mnv[c] = fminf(fminf(mnv[c], m2[c]), m3[c]);
            mnv[c] = fminf(fminf(mnv[c], m4[c]), m5[c]);
            mnv[c] = fminf(fminf(mnv[c], m6[c]), m7[c]);
        }
    }
    if (e + 4 <= end) {                          // one 4-edge block
        int4 c01 = *(const int4*)(csr + e);
        int4 c23 = *(const int4*)(csr + e + 2);
        float4 h0 = *(const float4*)(hbB + c01.x), r0 = *(const float4*)(reB + c01.y);
        float4 h1 = *(const float4*)(hbB + c01.z), r1 = *(const float4*)(reB + c01.w);
        float4 h2 = *(const float4*)(hbB + c23.x), r2 = *(const float4*)(reB + c23.y);
        float4 h3 = *(const float4*)(hbB + c23.z), r3 = *(const float4*)(reB + c23.w);
        float m0[4] = {h0.x * r0.x, h0.y * r0.y, h0.z * r0.z, h0.w * r0.w};
        float m1[4] = {h1.x * r1.x, h1.y * r1.y, h1.z * r1.z, h1.w * r1.w};
        float m2[4] = {h2.x * r2.x, h2.y * r2.y, h2.z * r2.z, h2.w * r2.w};
        float m3[4] = {h3.x * r3.x, h3.y * r3.y, h3.z * r3.z, h3.w * r3.w};
        #pragma unroll
        for (int c = 0; c < 4; ++c) {
            sv[c] += (m0[c] + m1[c]) + (m2[c] + m3[c]);
            ssv[c] = fmaf(m0[c], m0[c], ssv[c]);
            ssv[c] = fmaf(m1[c], m1[c], ssv[c]);
            ssv[c] = fmaf(m2[c], m2[c], ssv[c]);
            ssv[c] = fmaf(m3[c], m3[c], ssv[c]);
            mxv[c] = fmaxf(fmaxf(mxv[c], m0[c]), m1[c]);
            mxv[c] = fmaxf(fmaxf(mxv[c], m2[c]), m3[c]);
            mnv[c] = fminf(fminf(mnv[c], m0[c]), m1[c]);
            mnv[c] = fminf(fminf(mnv[c], m2[c]), m3[c]);
        }
        e += 4;
    }
    for (; e < end; ++e) EDGE1(e);
#undef EDGE1

    float degf = (float)(dg + 1);
    float inv = 1.0f / degf;
    float4 h4 = *(const float4*)(hbB + sidx * (ND * 4));
    float hself[4] = {h4.x, h4.y, h4.z, h4.w};

    #pragma unroll
    for (int f = 0; f < 5; ++f) {
        float vals[4];
        #pragma unroll
        for (int c = 0; c < 4; ++c) {
            float v;
            if (f == 0) v = hself[c];
            else if (f == 1) v = sv[c] * inv;
            else if (f == 2) v = mxv[c];
            else if (f == 3) v = mnv[c];
            else {
                float mean = sv[c] * inv;
                v = sqrtf(fmaxf(ssv[c] * inv - mean * mean, 0.f));
            }
            vals[c] = v;
        }
        ushort4 vh, vl;
        bf16split(vals[0], vh.x, vl.x);
        bf16split(vals[1], vh.y, vl.y);
        bf16split(vals[2], vh.z, vl.z);
        bf16split(vals[3], vh.w, vl.w);
        *(ushort4*)&ldsAh[rowl][f * 32 + d0] = vh;
        *(ushort4*)&ldsAl[rowl][f * 32 + d0] = vl;
    }
    __syncthreads();

    // -------- phase 2: MFMA update --------
    int mt = w >> 1, nt = w & 1;
    int am = lane & 15, kg = lane >> 4;
    int arow = mt * 16 + am;
    const bf16x8v* Bh = (const bf16x8v*)(Wph + (size_t)nt * 13 * 64 * 8);
    const bf16x8v* Bl = (const bf16x8v*)(Wpl + (size_t)nt * 13 * 64 * 8);

    f32x4v acc_a = {0.f, 0.f, 0.f, 0.f};
    f32x4v acc2  = {0.f, 0.f, 0.f, 0.f};
    f32x4v acc3  = {0.f, 0.f, 0.f, 0.f};

#define STEP(S, ACC)                                                              \
    {                                                                             \
        bf16x8v bh = Bh[(S) * 64 + lane];                                         \
        bf16x8v bl = Bl[(S) * 64 + lane];                                         \
        ACC = __builtin_amdgcn_mfma_f32_16x16x32_bf16(ah, bh, ACC, 0, 0, 0);      \
        ACC = __builtin_amdgcn_mfma_f32_16x16x32_bf16(ah, bl, ACC, 0, 0, 0);      \
        ACC = __builtin_amdgcn_mfma_f32_16x16x32_bf16(al, bh, ACC, 0, 0, 0);      \
    }
    #pragma unroll
    for (int c = 0; c < 5; ++c) {
        bf16x8v ah = *(const bf16x8v*)&ldsAh[arow][c * 32 + kg * 8];
        bf16x8v al = *(const bf16x8v*)&ldsAl[arow][c * 32 + kg * 8];
        if (c == 0) {
            STEP(0, acc_a)
        } else {
            STEP(c, acc_a)
            STEP(c + 4, acc2)
            STEP(c + 8, acc3)
        }
    }
#undef STEP

    int j = nt * 16 + am;
    float bj = bias[j];
    #pragma unroll
    for (int rr = 0; rr < 4; ++rr) {
        int gi = blk * 32 + mt * 16 + 4 * kg + rr;
        if (gi < n) {
            int ix = list[gi];
            int bb = ix / NN;
            int pp = ix - bb * NN;
            float2 sc = scales2[pp];
            float v = acc_a[rr] + sc.x * acc2[rr] + sc.y * acc3[rr] + bj;
            size_t o = (size_t)ix * 32 + j;
            hnew[o] = fmaxf(v, 0.f) + hin[o];
        }
    }
}

// ---------------- final MLP scorer: block per (b,t), lane per hidden unit ----------------
__global__ __launch_bounds__(64) void score_kernel(
    const float* __restrict__ hidden, const int* __restrict__ t_index,
    const int* __restrict__ ipern,
    const int* __restrict__ r_index, const float* __restrict__ qw,
    const float* __restrict__ w1, const float* __restrict__ b1,
    const float* __restrict__ w2, const float* __restrict__ b2,
    float* __restrict__ out) {
    int i = blockIdx.x;                       // 0..NB*NT-1
    int b = i / NT;
    int j = threadIdx.x;                      // 0..63
    int node = ipern[t_index[i]];             // sorted-space row
    __shared__ float feat[2 * ND];
    if (j < ND) feat[j] = hidden[((size_t)b * NN + node) * ND + j];
    else feat[j] = qw[r_index[b] * ND + (j - ND)];
    __syncthreads();
    float a = b1[j];
    #pragma unroll
    for (int kk = 0; kk < 2 * ND; ++kk) a = fmaf(feat[kk], w1[kk * 2 * ND + j], a);
    float v = fmaxf(a, 0.f) * w2[j];
    #pragma unroll
    for (int off = 32; off > 0; off >>= 1) v += __shfl_down(v, off, 64);
    if (j == 0) out[i] = v + b2[0];
}

extern "C" void kernel_launch(void* const* d_in, const int* in_sizes, int n_in,
                              void* d_out, int out_size, void* d_ws, size_t ws_size,
                              hipStream_t stream) {
    (void)in_sizes; (void)n_in; (void)out_size; (void)ws_size;
    const int* edge_index = (const int*)d_in[0];     // [2][E]
    const int* edge_type  = (const int*)d_in[1];     // [E]
    const int* h_index    = (const int*)d_in[2];     // [B]
    const int* r_index    = (const int*)d_in[3];     // [B]
    const int* t_index    = (const int*)d_in[4];     // [B][T]
    const float* query_weight = (const float*)d_in[5];  // [R][D]
    const float* rel_lin_w    = (const float*)d_in[6];  // [L][D][R*D]
    const float* layer_w      = (const float*)d_in[7];  // [L][13D][D]
    const float* layer_b      = (const float*)d_in[8];  // [L][D]
    const float* mlp_w1 = (const float*)d_in[9];
    const float* mlp_b1 = (const float*)d_in[10];
    const float* mlp_w2 = (const float*)d_in[11];
    const float* mlp_b2 = (const float*)d_in[12];
    float* out = (float*)d_out;

    const int* src = edge_index;
    const int* dst = edge_index + NE;

    char* wsp = (char*)d_ws;
    size_t off = 0;
    auto alloc = [&](size_t bytes) -> void* {
        void* p = wsp + off;
        off += (bytes + 255) & ~(size_t)255;
        return p;
    };
    float* hA      = (float*)alloc(sizeof(float) * M_TOT * ND);
    float* hB      = (float*)alloc(sizeof(float) * M_TOT * ND);
    unsigned short* Wph = (unsigned short*)alloc(sizeof(unsigned short) * NL * 2 * 13 * 64 * 8);
    unsigned short* Wpl = (unsigned short*)alloc(sizeof(unsigned short) * NL * 2 * 13 * 64 * 8);
    float* rel     = (float*)alloc(sizeof(float) * NL * NB * NR * ND);
    int2*  csr     = (int2*)alloc(sizeof(int2) * NE);
    int*   offsets = (int*)alloc(sizeof(int) * NN);
    int*   ic      = (int*)alloc(sizeof(int) * 2 * NN);   // indeg | cursor
    int*   indeg   = ic;
    int*   cursor  = ic + NN;
    int*   ipern   = (int*)alloc(sizeof(int) * NN);
    int2*  begdeg  = (int2*)alloc(sizeof(int2) * NN);
    float2* scales2 = (float2*)alloc(sizeof(float2) * NN);
    int*   hpos    = (int*)alloc(sizeof(int) * NB);
    // ---- zeroed region start ----
    int*   bucketCnt    = (int*)alloc(sizeof(int) * 256);
    int*   bucketCursor = (int*)alloc(sizeof(int) * 256);
    float* logsum  = (float*)alloc(sizeof(float) * 1);
    int*   edgeTotal = (int*)alloc(sizeof(int) * 1);
    int*   affCnt  = (int*)alloc(sizeof(int) * 1);
    int*   cnt2    = (int*)alloc(sizeof(int) * 1);
    int*   cnt3    = (int*)alloc(sizeof(int) * 1);
    unsigned char* f1 = (unsigned char*)alloc(M_TOT);
    unsigned char* f2 = (unsigned char*)alloc(M_TOT);
    unsigned char* f3 = (unsigned char*)alloc(M_TOT);
    size_t zbytes = (size_t)((char*)(f3 + M_TOT) - (char*)bucketCnt);
    // ---- zeroed region end ----
    int*   zb      = (int*)alloc(sizeof(int) * 2);
    int4*  affList = (int4*)alloc(sizeof(int4) * AFF_CAP);
    int*   list2   = (int*)alloc(sizeof(int) * M_TOT);
    int*   list3   = (int*)alloc(sizeof(int) * M_TOT);

    hipMemsetAsync(ic, 0, sizeof(int) * 2 * NN, stream);
    hipMemsetAsync(bucketCnt, 0, zbytes, stream);

    count_kernel<<<(NE + 255) / 256, 256, 0, stream>>>(dst, indeg);
    nodeprep_kernel<<<(NN + 255) / 256, 256, 0, stream>>>(indeg, offsets, bucketCnt,
                                                          logsum, edgeTotal);
    bucket_prefix_kernel<<<1, 256, 0, stream>>>(bucketCnt, bucketCursor, layer_b, zb);
    sortmap_kernel<<<(NN + 255) / 256, 256, 0, stream>>>(indeg, offsets, bucketCursor,
                                                         logsum, ipern, begdeg, scales2,
                                                         hpos, h_index);
    scatter_kernel<<<SCAT_BLKS + 1, 256, 0, stream>>>(src, dst, edge_type, offsets,
                                                      ipern, cursor, csr,
                                                      h_index, hpos, f1, affCnt, affList);
    relwpack_kernel<<<REL_BLOCKS + (NL * 2 * 13 * 64 + 255) / 256, 256, 0, stream>>>(
        query_weight, r_index, rel_lin_w, rel, layer_w, Wph, Wpl);

    // ---- layer 0: fill + sparse fixup (boundary sparsity is structural) ----
    fill_kernel<<<(M_TOT * 8 + 255) / 256, 256, 0, stream>>>(hA, layer_b);
    fixup_kernel<<<AFF_CAP, 64, 0, stream>>>(hA, rel, layer_w, layer_b, scales2,
                                             begdeg, hpos, r_index, query_weight,
                                             affCnt, affList);

    // ---- layer 1: frontier2 = reach<=2 (or all rows if background nonzero) ----
    mark_kernel<<<(NE + 255) / 256, 256, 0, stream>>>(src, dst, ipern, f1, f1, f2);
    compact_kernel<<<(M_TOT + 255) / 256, 256, 0, stream>>>(f1, f2, f2, zb, 0, cnt2, list2);
    fill_kernel<<<(M_TOT * 8 + 255) / 256, 256, 0, stream>>>(hB, layer_b + ND);
    list_layer_kernel<<<M_TOT / 32, 256, 0, stream>>>(
        hA, hB, rel + (size_t)1 * NB * NR * ND,
        Wph + (size_t)1 * 2 * 13 * 64 * 8, Wpl + (size_t)1 * 2 * 13 * 64 * 8,
        layer_b + ND, scales2, begdeg, csr, hpos, r_index, query_weight, cnt2, list2);

    // ---- layer 2: frontier3 = reach<=3 (or all rows) ----
    mark_kernel<<<(NE + 255) / 256, 256, 0, stream>>>(src, dst, ipern, f1, f2, f3);
    compact_kernel<<<(M_TOT + 255) / 256, 256, 0, stream>>>(f1, f2, f3, zb, 1, cnt3, list3);
    fill_kernel<<<(M_TOT * 8 + 255) / 256, 256, 0, stream>>>(hA, layer_b + 2 * ND);
    list_layer_kernel<<<M_TOT / 32, 256, 0, stream>>>(
        hB, hA, rel + (size_t)2 * NB * NR * ND,
        Wph + (size_t)2 * 2 * 13 * 64 * 8, Wpl + (size_t)2 * 2 * 13 * 64 * 8,
        layer_b + 2 * ND, scales2, begdeg, csr, hpos, r_index, query_weight, cnt3, list3);

    score_kernel<<<NB * NT, 64, 0, stream>>>(hA, t_index, ipern, r_index, query_weight,
                                             mlp_w1, mlp_b1, mlp_w2, mlp_b2, out);
}

// Round 19
// 210.985 us; speedup vs baseline: 1.0582x; 1.0582x over previous
//
#include <hip/hip_runtime.h>
#include <math.h>

#define NN 20000   // nodes
#define NE 480000  // edges
#define NB 4       // batch
#define ND 32      // dim
#define NR 474     // relations
#define NL 3       // layers
#define NT 64      // tails
#define M_TOT (NB * NN)   // 80000 node-rows
#define LROW 168          // padded LDS row (bf16 units)
#define AFF_CAP 1024      // layer-0 affected entries (~100)

typedef __attribute__((ext_vector_type(8))) short bf16x8v;
typedef __attribute__((ext_vector_type(4))) float f32x4v;

// RNE split of f32 into bf16 hi + bf16 lo (a ~= hi + lo, err ~2^-18 rel)
__device__ inline void bf16split(float a, unsigned short& h, unsigned short& l) {
    unsigned u = __float_as_uint(a);
    unsigned r = u + 0x7FFFu + ((u >> 16) & 1u);
    h = (unsigned short)(r >> 16);
    float fh = __uint_as_float((unsigned)h << 16);
    float res = a - fh;
    unsigned v = __float_as_uint(res);
    unsigned r2 = v + 0x7FFFu + ((v >> 16) & 1u);
    l = (unsigned short)(r2 >> 16);
}

// ---------------- CSR build ----------------
__global__ __launch_bounds__(256) void count_kernel(const int* __restrict__ dst,
                                                    int* __restrict__ indeg) {
    int e = blockIdx.x * blockDim.x + threadIdx.x;
    if (e < NE) atomicAdd(&indeg[dst[e]], 1);
}

// parallel per-node prep: wave-scan + ONE atomic per wave for the slab allocator
__global__ __launch_bounds__(256) void nodeprep_kernel(
    const int* __restrict__ indeg, int* __restrict__ offsets,
    int* __restrict__ bucketCnt, float* __restrict__ logsum,
    int* __restrict__ edgeTotal) {
    __shared__ int hcnt[256];
    int t = threadIdx.x;
    hcnt[t] = 0;
    __syncthreads();

    int n = blockIdx.x * 256 + t;
    int lane = t & 63;
    int dg = (n < NN) ? indeg[n] : 0;
    float v = (n < NN) ? logf((float)(dg + 2)) : 0.f;   // log(deg+1), deg = indeg+1

    int inc = dg;
    #pragma unroll
    for (int o = 1; o < 64; o <<= 1) {
        int u = __shfl_up(inc, o, 64);
        if (lane >= o) inc += u;
    }
    int waveTot = __shfl(inc, 63, 64);
    int base = 0;
    if (lane == 63) base = atomicAdd(edgeTotal, waveTot);   // 1 atomic per wave
    base = __shfl(base, 63, 64);
    if (n < NN) {
        offsets[n] = base + inc - dg;
        atomicAdd(&hcnt[dg > 255 ? 255 : dg], 1);           // LDS histogram
    }
    #pragma unroll
    for (int o = 32; o > 0; o >>= 1) v += __shfl_down(v, o, 64);
    if (lane == 0) atomicAdd(logsum, v);
    __syncthreads();
    if (hcnt[t]) atomicAdd(&bucketCnt[t], hcnt[t]);         // spread over 256 addrs
}

// 1-block: exclusive prefix over bucket counts + zero-background gate flags
__global__ __launch_bounds__(256) void bucket_prefix_kernel(
    const int* __restrict__ bucketCnt, int* __restrict__ bucketCursor,
    const float* __restrict__ layer_b, int* __restrict__ zb) {
    __shared__ int s[256];
    int t = threadIdx.x;
    s[t] = bucketCnt[t];
    __syncthreads();
    for (int off = 1; off < 256; off <<= 1) {
        int v = (t >= off) ? s[t - off] : 0;
        __syncthreads();
        s[t] += v;
        __syncthreads();
    }
    bucketCursor[t] = s[t] - bucketCnt[t];       // exclusive base
    if (t == 0) {
        int a = 1, b = 1;
        for (int j = 0; j < ND; ++j) {
            if (layer_b[j] > 0.f) a = 0;
            if (layer_b[ND + j] > 0.f) b = 0;
        }
        zb[0] = a;            // background of hidden1 is zero
        zb[1] = a && b;       // background of hidden2 is zero
    }
}

// parallel per-node: bucket placement (LDS rank + slab atomic); also invp (pos->node)
__global__ __launch_bounds__(256) void sortmap_kernel(
    const int* __restrict__ indeg, const int* __restrict__ offsets,
    int* __restrict__ bucketCursor, const float* __restrict__ logsum,
    int* __restrict__ ipern, int* __restrict__ invp, int2* __restrict__ begdeg,
    float2* __restrict__ scales2, int* __restrict__ hpos,
    const int* __restrict__ h_index) {
    __shared__ int hcnt[256];
    __shared__ int hbase[256];
    int t = threadIdx.x;
    hcnt[t] = 0;
    __syncthreads();

    int n = blockIdx.x * 256 + t;
    int dg = 0, bkt = 0, rank = 0;
    if (n < NN) {
        dg = indeg[n];
        bkt = dg > 255 ? 255 : dg;
        rank = atomicAdd(&hcnt[bkt], 1);         // intra-block rank (LDS)
    }
    __syncthreads();
    if (hcnt[t]) hbase[t] = atomicAdd(&bucketCursor[t], hcnt[t]);  // slab per (block,bucket)
    __syncthreads();
    if (n >= NN) return;
    int pos = hbase[bkt] + rank;
    ipern[n] = pos;
    invp[pos] = n;
    begdeg[pos] = make_int2(offsets[n], dg);
    float fac = (float)NN / *logsum;
    float scl = logf((float)(dg + 2)) * fac;
    scales2[pos] = make_float2(scl, 1.0f / fmaxf(scl, 1e-2f));
    #pragma unroll
    for (int b = 0; b < NB; ++b)
        if (n == h_index[b]) hpos[b] = pos;
}

// csr scatter + layer-0 bitmask frontier (node space) + affList + head rows (tail block)
#define SCAT_BLKS (NE / 256)   // 1875 exact
__global__ __launch_bounds__(256) void scatter_kernel(const int* __restrict__ src,
                                                      const int* __restrict__ dst,
                                                      const int* __restrict__ etype,
                                                      const int* __restrict__ offsets,
                                                      const int* __restrict__ ipern,
                                                      int* __restrict__ cursor,
                                                      int2* __restrict__ csr,
                                                      const int* __restrict__ h_index,
                                                      const int* __restrict__ hpos,
                                                      int* __restrict__ f1n,
                                                      int* __restrict__ affCnt,
                                                      int4* __restrict__ affList) {
    if (blockIdx.x == SCAT_BLKS) {               // head rows
        int b = threadIdx.x;
        if (b < NB) {
            atomicOr(&f1n[h_index[b]], 1 << b);
            int p = atomicAdd(affCnt, 1);
            if (p < AFF_CAP) affList[p] = make_int4(b, hpos[b], -1, 0);
        }
        return;
    }
    int e = blockIdx.x * 256 + threadIdx.x;
    int dn = dst[e];
    int sn = src[e];
    int pos = atomicAdd(&cursor[dn], 1);
    csr[offsets[dn] + pos] = make_int2(ipern[sn] * (ND * 4), etype[e] * (ND * 4));
    #pragma unroll
    for (int b = 0; b < NB; ++b) {
        if (sn == h_index[b]) {
            atomicOr(&f1n[dn], 1 << b);
            int p = atomicAdd(affCnt, 1);
            if (p < AFF_CAP) affList[p] = make_int4(b, ipern[dn], etype[e], 0);
        }
    }
}

// bitmask frontier propagation: Fout[dst] |= (fa|fb)[src]; ~2 scattered 4B loads/edge
__global__ __launch_bounds__(256) void mark_kernel(
    const int* __restrict__ src, const int* __restrict__ dst,
    const int* __restrict__ fa, const int* __restrict__ fb,
    int* __restrict__ fout) {
    int e = blockIdx.x * 256 + threadIdx.x;
    if (e >= NE) return;
    int s = src[e];
    int v = fa[s] | fb[s];
    if (v) atomicOr(&fout[dst[e]], v);
}

// compact (bit b of fa|fb|fc over nodes, or everything if !zb[zidx]) into work list.
// i = b*NN+pos ascending -> per-batch degree-ascending order preserved via invp.
__global__ __launch_bounds__(256) void compact_kernel(
    const int* __restrict__ fa, const int* __restrict__ fb,
    const int* __restrict__ fc, const int* __restrict__ invp,
    const int* __restrict__ zb, int zidx,
    int* __restrict__ cnt, int* __restrict__ list) {
    int i = blockIdx.x * 256 + threadIdx.x;
    bool take = false;
    if (i < M_TOT) {
        int b = i / NN;
        int pos = i - b * NN;
        int n = invp[pos];
        int m = fa[n] | fb[n] | fc[n];
        take = (!zb[zidx]) || ((m >> b) & 1);
    }
    unsigned long long msk = __ballot(take);
    int lane = threadIdx.x & 63;
    int nw = __popcll(msk);
    int base = 0;
    if (lane == 0 && nw) base = atomicAdd(cnt, nw);
    base = __shfl(base, 0, 64);
    if (take) list[base + __popcll(msk & ((1ULL << lane) - 1))] = i;
}

// uniform-background fill: out = relu(bias) everywhere (list kernel overwrites frontier)
__global__ __launch_bounds__(256) void fill_kernel(float* __restrict__ hnew,
                                                   const float* __restrict__ bias) {
    __shared__ float rb[ND];
    if (threadIdx.x < ND) rb[threadIdx.x] = fmaxf(bias[threadIdx.x], 0.f);
    __syncthreads();
    int i = blockIdx.x * 256 + threadIdx.x;      // over M_TOT*8 float4 slots
    if (i >= M_TOT * 8) return;
    int q = (i & 7) * 4;
    ((float4*)hnew)[i] = make_float4(rb[q], rb[q + 1], rb[q + 2], rb[q + 3]);
}

// layer-0 exact recompute for affected rows (messages = q (x) rel0[et] only)
__global__ __launch_bounds__(64) void fixup_kernel(
    float* __restrict__ hnew,
    const float* __restrict__ rel0, const float* __restrict__ W0,
    const float* __restrict__ bias, const float2* __restrict__ scales2,
    const int2* __restrict__ begdeg,
    const int* __restrict__ hpos, const int* __restrict__ r_index,
    const float* __restrict__ qw,
    const int* __restrict__ affCnt, const int4* __restrict__ affList) {
    __shared__ float F[5][ND];
    __shared__ int4 ent[AFF_CAP];
    int cnt = *affCnt;
    if (cnt > AFF_CAP) cnt = AFF_CAP;
    int t = threadIdx.x;
    for (int i = t; i < cnt; i += 64) ent[i] = affList[i];
    __syncthreads();
    if (blockIdx.x >= cnt) return;

    int4 me = ent[blockIdx.x];
    int b = me.x, row = me.y;
    for (int i = 0; i < (int)blockIdx.x; ++i) {      // dedupe
        int4 o = ent[i];
        if (o.x == b && o.y == row) return;
    }
    int hp = hpos[b];
    const float* q = qw + r_index[b] * ND;
    int deg = begdeg[row].y;

    if (t < ND) {
        int j = t;
        float qj = q[j];
        int nhead = 0;
        float s = 0.f, ss = 0.f, mx = -INFINITY, mn = INFINITY;
        for (int i = 0; i < cnt; ++i) {
            int4 o = ent[i];
            if (o.x == b && o.y == row && o.z >= 0) {
                float m = qj * rel0[((size_t)b * NR + o.z) * ND + j];
                s += m; ss = fmaf(m, m, ss);
                mx = fmaxf(mx, m); mn = fminf(mn, m);
                ++nhead;
            }
        }
        float bm = (row == hp) ? qj : 0.f;
        s += bm; ss = fmaf(bm, bm, ss);
        mx = fmaxf(mx, bm); mn = fminf(mn, bm);
        if (deg - nhead > 0) { mx = fmaxf(mx, 0.f); mn = fminf(mn, 0.f); }
        float inv = 1.0f / (float)(deg + 1);
        float mean = s * inv;
        F[0][j] = bm;
        F[1][j] = mean;
        F[2][j] = mx;
        F[3][j] = mn;
        F[4][j] = sqrtf(fmaxf(ss * inv - mean * mean, 0.f));
    }
    __syncthreads();

    int j = t & 31, kh = t >> 5;
    float2 sc = scales2[row];
    float acc = (kh == 0) ? bias[j] : 0.f;
    #pragma unroll
    for (int kk = 0; kk < 16; ++kk) {
        int k = kh * 16 + kk;
        acc = fmaf(F[0][k], W0[k * 32 + j], acc);
    }
    #pragma unroll
    for (int f = 1; f < 5; ++f) {
        #pragma unroll
        for (int kk = 0; kk < 16; ++kk) {
            int k = kh * 16 + kk;
            float a = F[f][k];
            int r0 = (f - 1) * 32 + 32 + k;
            acc = fmaf(a, W0[r0 * 32 + j], acc);
            acc = fmaf(a * sc.x, W0[(r0 + 128) * 32 + j], acc);
            acc = fmaf(a * sc.y, W0[(r0 + 256) * 32 + j], acc);
        }
    }
    acc += __shfl_down(acc, 32, 64);
    if (t < ND) {
        size_t o = ((size_t)b * NN + row) * ND + j;
        hnew[o] = fmaxf(acc, 0.f) + F[0][j];
    }
}

// ---------------- rel embeddings (4 batches/thread) + W pack, one kernel ----------------
#define REL_T (NL * NR * ND)              // 45504
#define REL_BLOCKS ((REL_T + 255) / 256)  // 178
__global__ __launch_bounds__(256) void relwpack_kernel(
    const float* __restrict__ qw, const int* __restrict__ r_index,
    const float* __restrict__ rlw, float* __restrict__ rel,
    const float* __restrict__ W, unsigned short* __restrict__ Wph,
    unsigned short* __restrict__ Wpl) {
    if (blockIdx.x < REL_BLOCKS) {
        int i = blockIdx.x * 256 + threadIdx.x;
        if (i >= REL_T) return;
        int d = i & (ND - 1);
        int rd = i >> 5;
        int r = rd % NR;
        int l = rd / NR;
        const float* q0 = qw + r_index[0] * ND;
        const float* q1 = qw + r_index[1] * ND;
        const float* q2 = qw + r_index[2] * ND;
        const float* q3 = qw + r_index[3] * ND;
        const float* w = rlw + (size_t)l * ND * NR * ND + (size_t)r * ND + d;
        float a0 = 0.f, a1 = 0.f, a2 = 0.f, a3 = 0.f;
        #pragma unroll
        for (int k = 0; k < ND; ++k) {
            float wk = w[(size_t)k * NR * ND];
            a0 = fmaf(q0[k], wk, a0); a1 = fmaf(q1[k], wk, a1);
            a2 = fmaf(q2[k], wk, a2); a3 = fmaf(q3[k], wk, a3);
        }
        size_t o = ((size_t)l * NB * NR + r) * ND + d;
        rel[o] = a0;
        rel[o + (size_t)NR * ND] = a1;
        rel[o + (size_t)2 * NR * ND] = a2;
        rel[o + (size_t)3 * NR * ND] = a3;
    } else {
        int t = (blockIdx.x - REL_BLOCKS) * 256 + threadIdx.x;
        if (t >= NL * 2 * 13 * 64) return;
        int lane = t & 63;
        int u = t >> 6;
        int s = u % 13;
        int nt = (u / 13) % 2;
        int l = u / 26;
        int n = nt * 16 + (lane & 15);
        int k0 = s * 32 + (lane >> 4) * 8;
        size_t ob = (size_t)t * 8;
        #pragma unroll
        for (int e = 0; e < 8; ++e) {
            float w = W[(size_t)l * 416 * 32 + (size_t)(k0 + e) * 32 + n];
            unsigned short h8, l8;
            bf16split(w, h8, l8);
            Wph[ob + e] = h8;
            Wpl[ob + e] = l8;
        }
    }
}

// ---------------- list-driven fused layer (R14 body; rows from work list) ----------------
__global__ __launch_bounds__(256, 4) void list_layer_kernel(
    const float* __restrict__ hin, float* __restrict__ hnew,
    const float* __restrict__ rel,               // [B][R][D] this layer
    const unsigned short* __restrict__ Wph, const unsigned short* __restrict__ Wpl,
    const float* __restrict__ bias, const float2* __restrict__ scales2,
    const int2* __restrict__ begdeg, const int2* __restrict__ csr,
    const int* __restrict__ hpos, const int* __restrict__ r_index,
    const float* __restrict__ qw,
    const int* __restrict__ cnt, const int* __restrict__ list) {
    __shared__ __align__(16) unsigned short ldsAh[32][LROW];
    __shared__ __align__(16) unsigned short ldsAl[32][LROW];

    int n = *cnt;
    int blk = blockIdx.x;
    if (blk * 32 >= n) return;                   // block-uniform early exit

    int tid = threadIdx.x;
    int lane = tid & 63;
    int w = tid >> 6;                            // 0..3
    int r8 = lane >> 3;
    int d0 = (lane & 7) * 4;                     // dim quartet
    int d4 = d0 * 4;                             // byte offset
    int rowl = w * 8 + r8;                       // 0..31
    int li = blk * 32 + rowl;
    bool act = li < n;
    int idx = act ? list[li] : list[0];          // dummy -> valid row 0
    int b = idx / NN;
    int sidx = idx - b * NN;
    const char* hbB = (const char*)hin + (size_t)b * (NN * ND * 4) + d4;
    const char* reB = (const char*)rel + (size_t)b * (NR * ND * 4) + d4;

    float sv[4], ssv[4], mxv[4], mnv[4];
    {
        float4 bm4 = make_float4(0.f, 0.f, 0.f, 0.f);
        if (sidx == hpos[b]) bm4 = *(const float4*)(qw + r_index[b] * ND + d0);
        float bm[4] = {bm4.x, bm4.y, bm4.z, bm4.w};
        #pragma unroll
        for (int c = 0; c < 4; ++c) {
            sv[c] = bm[c]; ssv[c] = bm[c] * bm[c]; mxv[c] = bm[c]; mnv[c] = bm[c];
        }
    }

    int2 bd = begdeg[sidx];
    int beg = bd.x, dg = bd.y, end = beg + dg;
#define EDGE1(E)                                                                  \
    {                                                                             \
        int2 a0 = csr[E];                                                         \
        float4 h0 = *(const float4*)(hbB + a0.x);                                 \
        float4 r0 = *(const float4*)(reB + a0.y);                                 \
        float m0[4] = {h0.x * r0.x, h0.y * r0.y, h0.z * r0.z, h0.w * r0.w};       \
        _Pragma("unroll")                                                         \
        for (int c = 0; c < 4; ++c) {                                             \
            sv[c] += m0[c];                                                       \
            ssv[c] = fmaf(m0[c], m0[c], ssv[c]);                                  \
            mxv[c] = fmaxf(mxv[c], m0[c]);                                        \
            mnv[c] = fminf(mnv[c], m0[c]);                                        \
        }                                                                         \
    }
    int e = beg;
    if ((e & 1) && e < end) { EDGE1(e); ++e; }   // align to 16B for int4 loads
    int n8 = (end - e) >> 3;                     // 8-edge chunks
    const int4* cp = (const int4*)(csr + e);
    e += n8 * 8;
    int4 k0, k1, k2, k3;
    if (n8 > 0) { k0 = cp[0]; k1 = cp[1]; k2 = cp[2]; k3 = cp[3]; }
    for (int i = 0; i < n8; ++i) {
        float4 h0 = *(const float4*)(hbB + k0.x), r0 = *(const float4*)(reB + k0.y);
        float4 h1 = *(const float4*)(hbB + k0.z), r1 = *(const float4*)(reB + k0.w);
        float4 h2 = *(const float4*)(hbB + k1.x), r2 = *(const float4*)(reB + k1.y);
        float4 h3 = *(const float4*)(hbB + k1.z), r3 = *(const float4*)(reB + k1.w);
        float4 h4 = *(const float4*)(hbB + k2.x), r4 = *(const float4*)(reB + k2.y);
        float4 h5 = *(const float4*)(hbB + k2.z), r5 = *(const float4*)(reB + k2.w);
        float4 h6 = *(const float4*)(hbB + k3.x), r6 = *(const float4*)(reB + k3.y);
        float4 h7 = *(const float4*)(hbB + k3.z), r7 = *(const float4*)(reB + k3.w);
        cp += 4;
        if (i + 1 < n8) { k0 = cp[0]; k1 = cp[1]; k2 = cp[2]; k3 = cp[3]; }
        float m0[4] = {h0.x * r0.x, h0.y * r0.y, h0.z * r0.z, h0.w * r0.w};
        float m1[4] = {h1.x * r1.x, h1.y * r1.y, h1.z * r1.z, h1.w * r1.w};
        float m2[4] = {h2.x * r2.x, h2.y * r2.y, h2.z * r2.z, h2.w * r2.w};
        float m3[4] = {h3.x * r3.x, h3.y * r3.y, h3.z * r3.z, h3.w * r3.w};
        float m4[4] = {h4.x * r4.x, h4.y * r4.y, h4.z * r4.z, h4.w * r4.w};
        float m5[4] = {h5.x * r5.x, h5.y * r5.y, h5.z * r5.z, h5.w * r5.w};
        float m6[4] = {h6.x * r6.x, h6.y * r6.y, h6.z * r6.z, h6.w * r6.w};
        float m7[4] = {h7.x * r7.x, h7.y * r7.y, h7.z * r7.z, h7.w * r7.w};
        #pragma unroll
        for (int c = 0; c < 4; ++c) {
            sv[c] += ((m0[c] + m1[c]) + (m2[c] + m3[c])) +
                     ((m4[c] + m5[c]) + (m6[c] + m7[c]));
            ssv[c] = fmaf(m0[c], m0[c], ssv[c]);
            ssv[c] = fmaf(m1[c], m1[c], ssv[c]);
            ssv[c] = fmaf(m2[c], m2[c], ssv[c]);
            ssv[c] = fmaf(m3[c], m3[c], ssv[c]);
            ssv[c] = fmaf(m4[c], m4[c], ssv[c]);
            ssv[c] = fmaf(m5[c], m5[c], ssv[c]);
            ssv[c] = fmaf(m6[c], m6[c], ssv[c]);
            ssv[c] = fmaf(m7[c], m7[c], ssv[c]);
            mxv[c] = fmaxf(fmaxf(mxv[c], m0[c]), m1[c]);
            mxv[c] = fmaxf(fmaxf(mxv[c], m2[c]), m3[c]);
            mxv[c] = fmaxf(fmaxf(mxv[c], m4[c]), m5[c]);
            mxv[c] = fmaxf(fmaxf(mxv[c], m6[c]), m7[c]);
            mnv[c] = fminf(fminf(mnv[c], m0[c]), m1[c]);
            mnv[c] = fminf(fminf(mnv[c], m2[c]), m3[c]);
            mnv[c] = fminf(fminf(mnv[c], m4[c]), m5[c]);
            mnv[c] = fminf(fminf(mnv[c], m6[c]), m7[c]);
        }
    }
    if (e + 4 <= end) {                          // one 4-edge block
        int4 c01 = *(const int4*)(csr + e);
        int4 c23 = *(const int4*)(csr + e + 2);
        float4 h0 = *(const float4*)(hbB + c01.x), r0 = *(const float4*)(reB + c01.y);
        float4 h1 = *(const float4*)(hbB + c01.z), r1 = *(const float4*)(reB + c01.w);
        float4 h2 = *(const float4*)(hbB + c23.x), r2 = *(const float4*)(reB + c23.y);
        float4 h3 = *(const float4*)(hbB + c23.z), r3 = *(const float4*)(reB + c23.w);
        float m0[4] = {h0.x * r0.x, h0.y * r0.y, h0.z * r0.z, h0.w * r0.w};
        float m1[4] = {h1.x * r1.x, h1.y * r1.y, h1.z * r1.z, h1.w * r1.w};
        float m2[4] = {h2.x * r2.x, h2.y * r2.y, h2.z * r2.z, h2.w * r2.w};
        float m3[4] = {h3.x * r3.x, h3.y * r3.y, h3.z * r3.z, h3.w * r3.w};
        #pragma unroll
        for (int c = 0; c < 4; ++c) {
            sv[c] += (m0[c] + m1[c]) + (m2[c] + m3[c]);
            ssv[c] = fmaf(m0[c], m0[c], ssv[c]);
            ssv[c] = fmaf(m1[c], m1[c], ssv[c]);
            ssv[c] = fmaf(m2[c], m2[c], ssv[c]);
            ssv[c] = fmaf(m3[c], m3[c], ssv[c]);
            mxv[c] = fmaxf(fmaxf(mxv[c], m0[c]), m1[c]);
            mxv[c] = fmaxf(fmaxf(mxv[c], m2[c]), m3[c]);
            mnv[c] = fminf(fminf(mnv[c], m0[c]), m1[c]);
            mnv[c] = fminf(fminf(mnv[c], m2[c]), m3[c]);
        }
        e += 4;
    }
    for (; e < end; ++e) EDGE1(e);
#undef EDGE1

    float degf = (float)(dg + 1);
    float inv = 1.0f / degf;
    float4 h4 = *(const float4*)(hbB + sidx * (ND * 4));
    float hself[4] = {h4.x, h4.y, h4.z, h4.w};

    #pragma unroll
    for (int f = 0; f < 5; ++f) {
        float vals[4];
        #pragma unroll
        for (int c = 0; c < 4; ++c) {
            float v;
            if (f == 0) v = hself[c];
            else if (f == 1) v = sv[c] * inv;
            else if (f == 2) v = mxv[c];
            else if (f == 3) v = mnv[c];
            else {
                float mean = sv[c] * inv;
                v = sqrtf(fmaxf(ssv[c] * inv - mean * mean, 0.f));
            }
            vals[c] = v;
        }
        ushort4 vh, vl;
        bf16split(vals[0], vh.x, vl.x);
        bf16split(vals[1], vh.y, vl.y);
        bf16split(vals[2], vh.z, vl.z);
        bf16split(vals[3], vh.w, vl.w);
        *(ushort4*)&ldsAh[rowl][f * 32 + d0] = vh;
        *(ushort4*)&ldsAl[rowl][f * 32 + d0] = vl;
    }
    __syncthreads();

    // -------- phase 2: MFMA update --------
    int mt = w >> 1, nt = w & 1;
    int am = lane & 15, kg = lane >> 4;
    int arow = mt * 16 + am;
    const bf16x8v* Bh = (const bf16x8v*)(Wph + (size_t)nt * 13 * 64 * 8);
    const bf16x8v* Bl = (const bf16x8v*)(Wpl + (size_t)nt * 13 * 64 * 8);

    f32x4v acc_a = {0.f, 0.f, 0.f, 0.f};
    f32x4v acc2  = {0.f, 0.f, 0.f, 0.f};
    f32x4v acc3  = {0.f, 0.f, 0.f, 0.f};

#define STEP(S, ACC)                                                              \
    {                                                                             \
        bf16x8v bh = Bh[(S) * 64 + lane];                                         \
        bf16x8v bl = Bl[(S) * 64 + lane];                                         \
        ACC = __builtin_amdgcn_mfma_f32_16x16x32_bf16(ah, bh, ACC, 0, 0, 0);      \
        ACC = __builtin_amdgcn_mfma_f32_16x16x32_bf16(ah, bl, ACC, 0, 0, 0);      \
        ACC = __builtin_amdgcn_mfma_f32_16x16x32_bf16(al, bh, ACC, 0, 0, 0);      \
    }
    #pragma unroll
    for (int c = 0; c < 5; ++c) {
        bf16x8v ah = *(const bf16x8v*)&ldsAh[arow][c * 32 + kg * 8];
        bf16x8v al = *(const bf16x8v*)&ldsAl[arow][c * 32 + kg * 8];
        if (c == 0) {
            STEP(0, acc_a)
        } else {
            STEP(c, acc_a)
            STEP(c + 4, acc2)
            STEP(c + 8, acc3)
        }
    }
#undef STEP

    int j = nt * 16 + am;
    float bj = bias[j];
    #pragma unroll
    for (int rr = 0; rr < 4; ++rr) {
        int gi = blk * 32 + mt * 16 + 4 * kg + rr;
        if (gi < n) {
            int ix = list[gi];
            int bb = ix / NN;
            int pp = ix - bb * NN;
            float2 sc = scales2[pp];
            float v = acc_a[rr] + sc.x * acc2[rr] + sc.y * acc3[rr] + bj;
            size_t o = (size_t)ix * 32 + j;
            hnew[o] = fmaxf(v, 0.f) + hin[o];
        }
    }
}

// ---------------- final MLP scorer: block per (b,t), lane per hidden unit ----------------
__global__ __launch_bounds__(64) void score_kernel(
    const float* __restrict__ hidden, const int* __restrict__ t_index,
    const int* __restrict__ ipern,
    const int* __restrict__ r_index, const float* __restrict__ qw,
    const float* __restrict__ w1, const float* __restrict__ b1,
    const float* __restrict__ w2, const float* __restrict__ b2,
    float* __restrict__ out) {
    int i = blockIdx.x;                       // 0..NB*NT-1
    int b = i / NT;
    int j = threadIdx.x;                      // 0..63
    int node = ipern[t_index[i]];             // sorted-space row
    __shared__ float feat[2 * ND];
    if (j < ND) feat[j] = hidden[((size_t)b * NN + node) * ND + j];
    else feat[j] = qw[r_index[b] * ND + (j - ND)];
    __syncthreads();
    float a = b1[j];
    #pragma unroll
    for (int kk = 0; kk < 2 * ND; ++kk) a = fmaf(feat[kk], w1[kk * 2 * ND + j], a);
    float v = fmaxf(a, 0.f) * w2[j];
    #pragma unroll
    for (int off = 32; off > 0; off >>= 1) v += __shfl_down(v, off, 64);
    if (j == 0) out[i] = v + b2[0];
}

extern "C" void kernel_launch(void* const* d_in, const int* in_sizes, int n_in,
                              void* d_out, int out_size, void* d_ws, size_t ws_size,
                              hipStream_t stream) {
    (void)in_sizes; (void)n_in; (void)out_size; (void)ws_size;
    const int* edge_index = (const int*)d_in[0];     // [2][E]
    const int* edge_type  = (const int*)d_in[1];     // [E]
    const int* h_index    = (const int*)d_in[2];     // [B]
    const int* r_index    = (const int*)d_in[3];     // [B]
    const int* t_index    = (const int*)d_in[4];     // [B][T]
    const float* query_weight = (const float*)d_in[5];  // [R][D]
    const float* rel_lin_w    = (const float*)d_in[6];  // [L][D][R*D]
    const float* layer_w      = (const float*)d_in[7];  // [L][13D][D]
    const float* layer_b      = (const float*)d_in[8];  // [L][D]
    const float* mlp_w1 = (const float*)d_in[9];
    const float* mlp_b1 = (const float*)d_in[10];
    const float* mlp_w2 = (const float*)d_in[11];
    const float* mlp_b2 = (const float*)d_in[12];
    float* out = (float*)d_out;

    const int* src = edge_index;
    const int* dst = edge_index + NE;

    char* wsp = (char*)d_ws;
    size_t off = 0;
    auto alloc = [&](size_t bytes) -> void* {
        void* p = wsp + off;
        off += (bytes + 255) & ~(size_t)255;
        return p;
    };
    float* hA      = (float*)alloc(sizeof(float) * M_TOT * ND);
    float* hB      = (float*)alloc(sizeof(float) * M_TOT * ND);
    unsigned short* Wph = (unsigned short*)alloc(sizeof(unsigned short) * NL * 2 * 13 * 64 * 8);
    unsigned short* Wpl = (unsigned short*)alloc(sizeof(unsigned short) * NL * 2 * 13 * 64 * 8);
    float* rel     = (float*)alloc(sizeof(float) * NL * NB * NR * ND);
    int2*  csr     = (int2*)alloc(sizeof(int2) * NE);
    int*   offsets = (int*)alloc(sizeof(int) * NN);
    int*   ic      = (int*)alloc(sizeof(int) * 2 * NN);   // indeg | cursor
    int*   indeg   = ic;
    int*   cursor  = ic + NN;
    int*   ipern   = (int*)alloc(sizeof(int) * NN);
    int*   invp    = (int*)alloc(sizeof(int) * NN);
    int2*  begdeg  = (int2*)alloc(sizeof(int2) * NN);
    float2* scales2 = (float2*)alloc(sizeof(float2) * NN);
    int*   hpos    = (int*)alloc(sizeof(int) * NB);
    // ---- zeroed region start ----
    int*   bucketCnt    = (int*)alloc(sizeof(int) * 256);
    int*   bucketCursor = (int*)alloc(sizeof(int) * 256);
    float* logsum  = (float*)alloc(sizeof(float) * 1);
    int*   edgeTotal = (int*)alloc(sizeof(int) * 1);
    int*   affCnt  = (int*)alloc(sizeof(int) * 1);
    int*   cnt2    = (int*)alloc(sizeof(int) * 1);
    int*   cnt3    = (int*)alloc(sizeof(int) * 1);
    int*   f1n     = (int*)alloc(sizeof(int) * NN);
    int*   f2n     = (int*)alloc(sizeof(int) * NN);
    int*   f3n     = (int*)alloc(sizeof(int) * NN);
    size_t zbytes = (size_t)((char*)(f3n + NN) - (char*)bucketCnt);
    // ---- zeroed region end ----
    int*   zb      = (int*)alloc(sizeof(int) * 2);
    int4*  affList = (int4*)alloc(sizeof(int4) * AFF_CAP);
    int*   list2   = (int*)alloc(sizeof(int) * M_TOT);
    int*   list3   = (int*)alloc(sizeof(int) * M_TOT);

    hipMemsetAsync(ic, 0, sizeof(int) * 2 * NN, stream);
    hipMemsetAsync(bucketCnt, 0, zbytes, stream);

    count_kernel<<<(NE + 255) / 256, 256, 0, stream>>>(dst, indeg);
    nodeprep_kernel<<<(NN + 255) / 256, 256, 0, stream>>>(indeg, offsets, bucketCnt,
                                                          logsum, edgeTotal);
    bucket_prefix_kernel<<<1, 256, 0, stream>>>(bucketCnt, bucketCursor, layer_b, zb);
    sortmap_kernel<<<(NN + 255) / 256, 256, 0, stream>>>(indeg, offsets, bucketCursor,
                                                         logsum, ipern, invp, begdeg,
                                                         scales2, hpos, h_index);
    scatter_kernel<<<SCAT_BLKS + 1, 256, 0, stream>>>(src, dst, edge_type, offsets,
                                                      ipern, cursor, csr,
                                                      h_index, hpos, f1n, affCnt, affList);
    relwpack_kernel<<<REL_BLOCKS + (NL * 2 * 13 * 64 + 255) / 256, 256, 0, stream>>>(
        query_weight, r_index, rel_lin_w, rel, layer_w, Wph, Wpl);

    // ---- layer 0: fill + sparse fixup (boundary sparsity is structural) ----
    fill_kernel<<<(M_TOT * 8 + 255) / 256, 256, 0, stream>>>(hA, layer_b);
    fixup_kernel<<<AFF_CAP, 64, 0, stream>>>(hA, rel, layer_w, layer_b, scales2,
                                             begdeg, hpos, r_index, query_weight,
                                             affCnt, affList);

    // ---- layer 1: frontier2 = reach<=2 (or all rows if background nonzero) ----
    mark_kernel<<<(NE + 255) / 256, 256, 0, stream>>>(src, dst, f1n, f1n, f2n);
    compact_kernel<<<(M_TOT + 255) / 256, 256, 0, stream>>>(f1n, f2n, f2n, invp, zb, 0,
                                                            cnt2, list2);
    fill_kernel<<<(M_TOT * 8 + 255) / 256, 256, 0, stream>>>(hB, layer_b + ND);
    list_layer_kernel<<<M_TOT / 32, 256, 0, stream>>>(
        hA, hB, rel + (size_t)1 * NB * NR * ND,
        Wph + (size_t)1 * 2 * 13 * 64 * 8, Wpl + (size_t)1 * 2 * 13 * 64 * 8,
        layer_b + ND, scales2, begdeg, csr, hpos, r_index, query_weight, cnt2, list2);

    // ---- layer 2: frontier3 = reach<=3 (or all rows) ----
    mark_kernel<<<(NE + 255) / 256, 256, 0, stream>>>(src, dst, f1n, f2n, f3n);
    compact_kernel<<<(M_TOT + 255) / 256, 256, 0, stream>>>(f1n, f2n, f3n, invp, zb, 1,
                                                            cnt3, list3);
    fill_kernel<<<(M_TOT * 8 + 255) / 256, 256, 0, stream>>>(hA, layer_b + 2 * ND);
    list_layer_kernel<<<M_TOT / 32, 256, 0, stream>>>(
        hB, hA, rel + (size_t)2 * NB * NR * ND,
        Wph + (size_t)2 * 2 * 13 * 64 * 8, Wpl + (size_t)2 * 2 * 13 * 64 * 8,
        layer_b + 2 * ND, scales2, begdeg, csr, hpos, r_index, query_weight, cnt3, list3);

    score_kernel<<<NB * NT, 64, 0, stream>>>(hA, t_index, ipern, r_index, query_weight,
                                             mlp_w1, mlp_b1, mlp_w2, mlp_b2, out);
}

// Round 20
// 162.600 us; speedup vs baseline: 1.3731x; 1.2976x over previous
//
#include <hip/hip_runtime.h>
#include <math.h>

#define NN 20000   // nodes
#define NE 480000  // edges
#define NB 4       // batch
#define ND 32      // dim
#define NR 474     // relations
#define NL 3       // layers
#define NT 64      // tails
#define M_TOT (NB * NN)   // 80000 node-rows
#define LROW 168          // padded LDS row (bf16 units)
#define AFF_CAP 1024      // layer-0 affected entries (~100)

typedef __attribute__((ext_vector_type(8))) short bf16x8v;
typedef __attribute__((ext_vector_type(4))) float f32x4v;

// RNE split of f32 into bf16 hi + bf16 lo (a ~= hi + lo, err ~2^-18 rel)
__device__ inline void bf16split(float a, unsigned short& h, unsigned short& l) {
    unsigned u = __float_as_uint(a);
    unsigned r = u + 0x7FFFu + ((u >> 16) & 1u);
    h = (unsigned short)(r >> 16);
    float fh = __uint_as_float((unsigned)h << 16);
    float res = a - fh;
    unsigned v = __float_as_uint(res);
    unsigned r2 = v + 0x7FFFu + ((v >> 16) & 1u);
    l = (unsigned short)(r2 >> 16);
}

// ---------------- CSR count + layer-0 frontier bits (f1n: heads + head-out dsts) ----------------
__global__ __launch_bounds__(256) void count_kernel(const int* __restrict__ src,
                                                    const int* __restrict__ dst,
                                                    const int* __restrict__ h_index,
                                                    int* __restrict__ indeg,
                                                    int* __restrict__ f1n) {
    int e = blockIdx.x * blockDim.x + threadIdx.x;
    if (e < NB) atomicOr(&f1n[h_index[e]], 1 << e);       // head rows
    if (e >= NE) return;
    int dn = dst[e];
    atomicAdd(&indeg[dn], 1);
    int sn = src[e];
    #pragma unroll
    for (int b = 0; b < NB; ++b)
        if (sn == h_index[b]) atomicOr(&f1n[dn], 1 << b);
}

// parallel per-node prep: wave-scan + ONE atomic per wave for the slab allocator
__global__ __launch_bounds__(256) void nodeprep_kernel(
    const int* __restrict__ indeg, int* __restrict__ offsets,
    int* __restrict__ bucketCnt, float* __restrict__ logsum,
    int* __restrict__ edgeTotal) {
    __shared__ int hcnt[256];
    int t = threadIdx.x;
    hcnt[t] = 0;
    __syncthreads();

    int n = blockIdx.x * 256 + t;
    int lane = t & 63;
    int dg = (n < NN) ? indeg[n] : 0;
    float v = (n < NN) ? logf((float)(dg + 2)) : 0.f;   // log(deg+1), deg = indeg+1

    int inc = dg;
    #pragma unroll
    for (int o = 1; o < 64; o <<= 1) {
        int u = __shfl_up(inc, o, 64);
        if (lane >= o) inc += u;
    }
    int waveTot = __shfl(inc, 63, 64);
    int base = 0;
    if (lane == 63) base = atomicAdd(edgeTotal, waveTot);   // 1 atomic per wave
    base = __shfl(base, 63, 64);
    if (n < NN) {
        offsets[n] = base + inc - dg;
        atomicAdd(&hcnt[dg > 255 ? 255 : dg], 1);           // LDS histogram
    }
    #pragma unroll
    for (int o = 32; o > 0; o >>= 1) v += __shfl_down(v, o, 64);
    if (lane == 0) atomicAdd(logsum, v);
    __syncthreads();
    if (hcnt[t]) atomicAdd(&bucketCnt[t], hcnt[t]);         // spread over 256 addrs
}

// 1-block: exclusive prefix over bucket counts + zero-background gate flags
__global__ __launch_bounds__(256) void bucket_prefix_kernel(
    const int* __restrict__ bucketCnt, int* __restrict__ bucketCursor,
    const float* __restrict__ layer_b, int* __restrict__ zb) {
    __shared__ int s[256];
    int t = threadIdx.x;
    s[t] = bucketCnt[t];
    __syncthreads();
    for (int off = 1; off < 256; off <<= 1) {
        int v = (t >= off) ? s[t - off] : 0;
        __syncthreads();
        s[t] += v;
        __syncthreads();
    }
    bucketCursor[t] = s[t] - bucketCnt[t];       // exclusive base
    if (t == 0) {
        int a = 1, b = 1;
        for (int j = 0; j < ND; ++j) {
            if (layer_b[j] > 0.f) a = 0;
            if (layer_b[ND + j] > 0.f) b = 0;
        }
        zb[0] = a;            // background of hidden1 is zero
        zb[1] = a && b;       // background of hidden2 is zero
    }
}

// parallel per-node: bucket placement (LDS rank + slab atomic); also invp (pos->node)
__global__ __launch_bounds__(256) void sortmap_kernel(
    const int* __restrict__ indeg, const int* __restrict__ offsets,
    int* __restrict__ bucketCursor, const float* __restrict__ logsum,
    int* __restrict__ ipern, int* __restrict__ invp, int2* __restrict__ begdeg,
    float2* __restrict__ scales2, int* __restrict__ hpos,
    const int* __restrict__ h_index) {
    __shared__ int hcnt[256];
    __shared__ int hbase[256];
    int t = threadIdx.x;
    hcnt[t] = 0;
    __syncthreads();

    int n = blockIdx.x * 256 + t;
    int dg = 0, bkt = 0, rank = 0;
    if (n < NN) {
        dg = indeg[n];
        bkt = dg > 255 ? 255 : dg;
        rank = atomicAdd(&hcnt[bkt], 1);         // intra-block rank (LDS)
    }
    __syncthreads();
    if (hcnt[t]) hbase[t] = atomicAdd(&bucketCursor[t], hcnt[t]);  // slab per (block,bucket)
    __syncthreads();
    if (n >= NN) return;
    int pos = hbase[bkt] + rank;
    ipern[n] = pos;
    invp[pos] = n;
    begdeg[pos] = make_int2(offsets[n], dg);
    float fac = (float)NN / *logsum;
    float scl = logf((float)(dg + 2)) * fac;
    scales2[pos] = make_float2(scl, 1.0f / fmaxf(scl, 1e-2f));
    #pragma unroll
    for (int b = 0; b < NB; ++b)
        if (n == h_index[b]) hpos[b] = pos;
}

// csr scatter + f2n propagation (f1n complete) + affList + head rows (tail block)
#define SCAT_BLKS (NE / 256)   // 1875 exact
__global__ __launch_bounds__(256) void scatter_kernel(const int* __restrict__ src,
                                                      const int* __restrict__ dst,
                                                      const int* __restrict__ etype,
                                                      const int* __restrict__ offsets,
                                                      const int* __restrict__ ipern,
                                                      int* __restrict__ cursor,
                                                      int2* __restrict__ csr,
                                                      const int* __restrict__ h_index,
                                                      const int* __restrict__ hpos,
                                                      const int* __restrict__ f1n,
                                                      int* __restrict__ f2n,
                                                      int* __restrict__ affCnt,
                                                      int4* __restrict__ affList) {
    if (blockIdx.x == SCAT_BLKS) {               // head-row affList entries
        int b = threadIdx.x;
        if (b < NB) {
            int p = atomicAdd(affCnt, 1);
            if (p < AFF_CAP) affList[p] = make_int4(b, hpos[b], -1, 0);
        }
        return;
    }
    int e = blockIdx.x * 256 + threadIdx.x;
    int dn = dst[e];
    int sn = src[e];
    int pos = atomicAdd(&cursor[dn], 1);
    csr[offsets[dn] + pos] = make_int2(ipern[sn] * (ND * 4), etype[e] * (ND * 4));
    int v = f1n[sn];
    if (v) atomicOr(&f2n[dn], v);                // frontier2 = neighbors of frontier1
    #pragma unroll
    for (int b = 0; b < NB; ++b) {
        if (sn == h_index[b]) {
            int p = atomicAdd(affCnt, 1);
            if (p < AFF_CAP) affList[p] = make_int4(b, ipern[dn], etype[e], 0);
        }
    }
}

// compact (bit b of fa|fb|fc over nodes, or everything if !zb[zidx]) into work list.
__global__ __launch_bounds__(256) void compact_kernel(
    const int* __restrict__ fa, const int* __restrict__ fb,
    const int* __restrict__ fc, const int* __restrict__ invp,
    const int* __restrict__ zb, int zidx,
    int* __restrict__ cnt, int* __restrict__ list) {
    int i = blockIdx.x * 256 + threadIdx.x;
    bool take = false;
    if (i < M_TOT) {
        int b = i / NN;
        int pos = i - b * NN;
        int n = invp[pos];
        int m = fa[n] | fb[n] | fc[n];
        take = (!zb[zidx]) || ((m >> b) & 1);
    }
    unsigned long long msk = __ballot(take);
    int lane = threadIdx.x & 63;
    int nw = __popcll(msk);
    int base = 0;
    if (lane == 0 && nw) base = atomicAdd(cnt, nw);
    base = __shfl(base, 0, 64);
    if (take) list[base + __popcll(msk & ((1ULL << lane) - 1))] = i;
}

// per-t-row affected test: bit of (f1|f2)[t] OR any in-edge src flagged. Wave per entry.
__global__ __launch_bounds__(64) void taffect_kernel(
    const int* __restrict__ t_index, const int* __restrict__ ipern,
    const int* __restrict__ invp, const int2* __restrict__ begdeg,
    const int2* __restrict__ csr,
    const int* __restrict__ f1n, const int* __restrict__ f2n,
    const int* __restrict__ zb, unsigned char* __restrict__ taff) {
    int i = blockIdx.x;                       // 0..NB*NT-1
    int b = i / NT;
    int lane = threadIdx.x;
    int node = t_index[i];
    int aff = ((f1n[node] | f2n[node]) >> b) & 1;
    int pos = ipern[node];
    int2 bd = begdeg[pos];
    int a = 0;
    for (int e = bd.x + lane; e < bd.x + bd.y; e += 64) {
        int sn = invp[csr[e].x >> 7];         // src node (byte off / 128)
        a |= ((f1n[sn] | f2n[sn]) >> b) & 1;
    }
    aff |= (__ballot(a) != 0ULL);
    if (!zb[1]) aff = 1;                      // dense fallback: everything computed
    if (lane == 0) taff[i] = (unsigned char)aff;
}

// layer-2 list: flagged t rows only (or all M_TOT rows in dense fallback)
__global__ __launch_bounds__(256) void compact3_kernel(
    const int* __restrict__ t_index, const int* __restrict__ ipern,
    const unsigned char* __restrict__ taff, const int* __restrict__ zb,
    int* __restrict__ cnt, int* __restrict__ list) {
    int i = blockIdx.x * 256 + threadIdx.x;
    bool take = false; int val = 0;
    if (!zb[1]) {
        if (i < M_TOT) { take = true; val = i; }
    } else if (i < NB * NT) {
        take = taff[i] != 0;
        val = (i / NT) * NN + ipern[t_index[i]];
    }
    unsigned long long msk = __ballot(take);
    int lane = threadIdx.x & 63;
    int nw = __popcll(msk);
    int base = 0;
    if (lane == 0 && nw) base = atomicAdd(cnt, nw);
    base = __shfl(base, 0, 64);
    if (take) list[base + __popcll(msk & ((1ULL << lane) - 1))] = val;
}

// uniform-background fill: out = relu(bias) everywhere (list kernel overwrites frontier)
__global__ __launch_bounds__(256) void fill_kernel(float* __restrict__ hnew,
                                                   const float* __restrict__ bias) {
    __shared__ float rb[ND];
    if (threadIdx.x < ND) rb[threadIdx.x] = fmaxf(bias[threadIdx.x], 0.f);
    __syncthreads();
    int i = blockIdx.x * 256 + threadIdx.x;      // over M_TOT*8 float4 slots
    if (i >= M_TOT * 8) return;
    int q = (i & 7) * 4;
    ((float4*)hnew)[i] = make_float4(rb[q], rb[q + 1], rb[q + 2], rb[q + 3]);
}

// layer-0 exact recompute for affected rows (messages = q (x) rel0[et] only)
__global__ __launch_bounds__(64) void fixup_kernel(
    float* __restrict__ hnew,
    const float* __restrict__ rel0, const float* __restrict__ W0,
    const float* __restrict__ bias, const float2* __restrict__ scales2,
    const int2* __restrict__ begdeg,
    const int* __restrict__ hpos, const int* __restrict__ r_index,
    const float* __restrict__ qw,
    const int* __restrict__ affCnt, const int4* __restrict__ affList) {
    __shared__ float F[5][ND];
    __shared__ int4 ent[AFF_CAP];
    int cnt = *affCnt;
    if (cnt > AFF_CAP) cnt = AFF_CAP;
    int t = threadIdx.x;
    for (int i = t; i < cnt; i += 64) ent[i] = affList[i];
    __syncthreads();
    if (blockIdx.x >= cnt) return;

    int4 me = ent[blockIdx.x];
    int b = me.x, row = me.y;
    for (int i = 0; i < (int)blockIdx.x; ++i) {      // dedupe
        int4 o = ent[i];
        if (o.x == b && o.y == row) return;
    }
    int hp = hpos[b];
    const float* q = qw + r_index[b] * ND;
    int deg = begdeg[row].y;

    if (t < ND) {
        int j = t;
        float qj = q[j];
        int nhead = 0;
        float s = 0.f, ss = 0.f, mx = -INFINITY, mn = INFINITY;
        for (int i = 0; i < cnt; ++i) {
            int4 o = ent[i];
            if (o.x == b && o.y == row && o.z >= 0) {
                float m = qj * rel0[((size_t)b * NR + o.z) * ND + j];
                s += m; ss = fmaf(m, m, ss);
                mx = fmaxf(mx, m); mn = fminf(mn, m);
                ++nhead;
            }
        }
        float bm = (row == hp) ? qj : 0.f;
        s += bm; ss = fmaf(bm, bm, ss);
        mx = fmaxf(mx, bm); mn = fminf(mn, bm);
        if (deg - nhead > 0) { mx = fmaxf(mx, 0.f); mn = fminf(mn, 0.f); }
        float inv = 1.0f / (float)(deg + 1);
        float mean = s * inv;
        F[0][j] = bm;
        F[1][j] = mean;
        F[2][j] = mx;
        F[3][j] = mn;
        F[4][j] = sqrtf(fmaxf(ss * inv - mean * mean, 0.f));
    }
    __syncthreads();

    int j = t & 31, kh = t >> 5;
    float2 sc = scales2[row];
    float acc = (kh == 0) ? bias[j] : 0.f;
    #pragma unroll
    for (int kk = 0; kk < 16; ++kk) {
        int k = kh * 16 + kk;
        acc = fmaf(F[0][k], W0[k * 32 + j], acc);
    }
    #pragma unroll
    for (int f = 1; f < 5; ++f) {
        #pragma unroll
        for (int kk = 0; kk < 16; ++kk) {
            int k = kh * 16 + kk;
            float a = F[f][k];
            int r0 = (f - 1) * 32 + 32 + k;
            acc = fmaf(a, W0[r0 * 32 + j], acc);
            acc = fmaf(a * sc.x, W0[(r0 + 128) * 32 + j], acc);
            acc = fmaf(a * sc.y, W0[(r0 + 256) * 32 + j], acc);
        }
    }
    acc += __shfl_down(acc, 32, 64);
    if (t < ND) {
        size_t o = ((size_t)b * NN + row) * ND + j;
        hnew[o] = fmaxf(acc, 0.f) + F[0][j];
    }
}

// ---------------- rel embeddings (4 batches/thread) + W pack, one kernel ----------------
#define REL_T (NL * NR * ND)              // 45504
#define REL_BLOCKS ((REL_T + 255) / 256)  // 178
__global__ __launch_bounds__(256) void relwpack_kernel(
    const float* __restrict__ qw, const int* __restrict__ r_index,
    const float* __restrict__ rlw, float* __restrict__ rel,
    const float* __restrict__ W, unsigned short* __restrict__ Wph,
    unsigned short* __restrict__ Wpl) {
    if (blockIdx.x < REL_BLOCKS) {
        int i = blockIdx.x * 256 + threadIdx.x;
        if (i >= REL_T) return;
        int d = i & (ND - 1);
        int rd = i >> 5;
        int r = rd % NR;
        int l = rd / NR;
        const float* q0 = qw + r_index[0] * ND;
        const float* q1 = qw + r_index[1] * ND;
        const float* q2 = qw + r_index[2] * ND;
        const float* q3 = qw + r_index[3] * ND;
        const float* w = rlw + (size_t)l * ND * NR * ND + (size_t)r * ND + d;
        float a0 = 0.f, a1 = 0.f, a2 = 0.f, a3 = 0.f;
        #pragma unroll
        for (int k = 0; k < ND; ++k) {
            float wk = w[(size_t)k * NR * ND];
            a0 = fmaf(q0[k], wk, a0); a1 = fmaf(q1[k], wk, a1);
            a2 = fmaf(q2[k], wk, a2); a3 = fmaf(q3[k], wk, a3);
        }
        size_t o = ((size_t)l * NB * NR + r) * ND + d;
        rel[o] = a0;
        rel[o + (size_t)NR * ND] = a1;
        rel[o + (size_t)2 * NR * ND] = a2;
        rel[o + (size_t)3 * NR * ND] = a3;
    } else {
        int t = (blockIdx.x - REL_BLOCKS) * 256 + threadIdx.x;
        if (t >= NL * 2 * 13 * 64) return;
        int lane = t & 63;
        int u = t >> 6;
        int s = u % 13;
        int nt = (u / 13) % 2;
        int l = u / 26;
        int n = nt * 16 + (lane & 15);
        int k0 = s * 32 + (lane >> 4) * 8;
        size_t ob = (size_t)t * 8;
        #pragma unroll
        for (int e = 0; e < 8; ++e) {
            float w = W[(size_t)l * 416 * 32 + (size_t)(k0 + e) * 32 + n];
            unsigned short h8, l8;
            bf16split(w, h8, l8);
            Wph[ob + e] = h8;
            Wpl[ob + e] = l8;
        }
    }
}

// ---------------- list-driven fused layer (R14 body; rows from work list) ----------------
__global__ __launch_bounds__(256, 4) void list_layer_kernel(
    const float* __restrict__ hin, float* __restrict__ hnew,
    const float* __restrict__ rel,               // [B][R][D] this layer
    const unsigned short* __restrict__ Wph, const unsigned short* __restrict__ Wpl,
    const float* __restrict__ bias, const float2* __restrict__ scales2,
    const int2* __restrict__ begdeg, const int2* __restrict__ csr,
    const int* __restrict__ hpos, const int* __restrict__ r_index,
    const float* __restrict__ qw,
    const int* __restrict__ cnt, const int* __restrict__ list) {
    __shared__ __align__(16) unsigned short ldsAh[32][LROW];
    __shared__ __align__(16) unsigned short ldsAl[32][LROW];

    int n = *cnt;
    int blk = blockIdx.x;
    if (blk * 32 >= n) return;                   // block-uniform early exit

    int tid = threadIdx.x;
    int lane = tid & 63;
    int w = tid >> 6;                            // 0..3
    int r8 = lane >> 3;
    int d0 = (lane & 7) * 4;                     // dim quartet
    int d4 = d0 * 4;                             // byte offset
    int rowl = w * 8 + r8;                       // 0..31
    int li = blk * 32 + rowl;
    bool act = li < n;
    int idx = act ? list[li] : list[0];          // dummy -> valid row 0
    int b = idx / NN;
    int sidx = idx - b * NN;
    const char* hbB = (const char*)hin + (size_t)b * (NN * ND * 4) + d4;
    const char* reB = (const char*)rel + (size_t)b * (NR * ND * 4) + d4;

    float sv[4], ssv[4], mxv[4], mnv[4];
    {
        float4 bm4 = make_float4(0.f, 0.f, 0.f, 0.f);
        if (sidx == hpos[b]) bm4 = *(const float4*)(qw + r_index[b] * ND + d0);
        float bm[4] = {bm4.x, bm4.y, bm4.z, bm4.w};
        #pragma unroll
        for (int c = 0; c < 4; ++c) {
            sv[c] = bm[c]; ssv[c] = bm[c] * bm[c]; mxv[c] = bm[c]; mnv[c] = bm[c];
        }
    }

    int2 bd = begdeg[sidx];
    int beg = bd.x, dg = bd.y, end = beg + dg;
#define EDGE1(E)                                                                  \
    {                                                                             \
        int2 a0 = csr[E];                                                         \
        float4 h0 = *(const float4*)(hbB + a0.x);                                 \
        float4 r0 = *(const float4*)(reB + a0.y);                                 \
        float m0[4] = {h0.x * r0.x, h0.y * r0.y, h0.z * r0.z, h0.w * r0.w};       \
        _Pragma("unroll")                                                         \
        for (int c = 0; c < 4; ++c) {                                             \
            sv[c] += m0[c];                                                       \
            ssv[c] = fmaf(m0[c], m0[c], ssv[c]);                                  \
            mxv[c] = fmaxf(mxv[c], m0[c]);                                        \
            mnv[c] = fminf(mnv[c], m0[c]);                                        \
        }                                                                         \
    }
    int e = beg;
    if ((e & 1) && e < end) { EDGE1(e); ++e; }   // align to 16B for int4 loads
    int n8 = (end - e) >> 3;                     // 8-edge chunks
    const int4* cp = (const int4*)(csr + e);
    e += n8 * 8;
    int4 k0, k1, k2, k3;
    if (n8 > 0) { k0 = cp[0]; k1 = cp[1]; k2 = cp[2]; k3 = cp[3]; }
    for (int i = 0; i < n8; ++i) {
        float4 h0 = *(const float4*)(hbB + k0.x), r0 = *(const float4*)(reB + k0.y);
        float4 h1 = *(const float4*)(hbB + k0.z), r1 = *(const float4*)(reB + k0.w);
        float4 h2 = *(const float4*)(hbB + k1.x), r2 = *(const float4*)(reB + k1.y);
        float4 h3 = *(const float4*)(hbB + k1.z), r3 = *(const float4*)(reB + k1.w);
        float4 h4 = *(const float4*)(hbB + k2.x), r4 = *(const float4*)(reB + k2.y);
        float4 h5 = *(const float4*)(hbB + k2.z), r5 = *(const float4*)(reB + k2.w);
        float4 h6 = *(const float4*)(hbB + k3.x), r6 = *(const float4*)(reB + k3.y);
        float4 h7 = *(const float4*)(hbB + k3.z), r7 = *(const float4*)(reB + k3.w);
        cp += 4;
        if (i + 1 < n8) { k0 = cp[0]; k1 = cp[1]; k2 = cp[2]; k3 = cp[3]; }
        float m0[4] = {h0.x * r0.x, h0.y * r0.y, h0.z * r0.z, h0.w * r0.w};
        float m1[4] = {h1.x * r1.x, h1.y * r1.y, h1.z * r1.z, h1.w * r1.w};
        float m2[4] = {h2.x * r2.x, h2.y * r2.y, h2.z * r2.z, h2.w * r2.w};
        float m3[4] = {h3.x * r3.x, h3.y * r3.y, h3.z * r3.z, h3.w * r3.w};
        float m4[4] = {h4.x * r4.x, h4.y * r4.y, h4.z * r4.z, h4.w * r4.w};
        float m5[4] = {h5.x * r5.x, h5.y * r5.y, h5.z * r5.z, h5.w * r5.w};
        float m6[4] = {h6.x * r6.x, h6.y * r6.y, h6.z * r6.z, h6.w * r6.w};
        float m7[4] = {h7.x * r7.x, h7.y * r7.y, h7.z * r7.z, h7.w * r7.w};
        #pragma unroll
        for (int c = 0; c < 4; ++c) {
            sv[c] += ((m0[c] + m1[c]) + (m2[c] + m3[c])) +
                     ((m4[c] + m5[c]) + (m6[c] + m7[c]));
            ssv[c] = fmaf(m0[c], m0[c], ssv[c]);
            ssv[c] = fmaf(m1[c], m1[c], ssv[c]);
            ssv[c] = fmaf(m2[c], m2[c], ssv[c]);
            ssv[c] = fmaf(m3[c], m3[c], ssv[c]);
            ssv[c] = fmaf(m4[c], m4[c], ssv[c]);
            ssv[c] = fmaf(m5[c], m5[c], ssv[c]);
            ssv[c] = fmaf(m6[c], m6[c], ssv[c]);
            ssv[c] = fmaf(m7[c], m7[c], ssv[c]);
            mxv[c] = fmaxf(fmaxf(mxv[c], m0[c]), m1[c]);
            mxv[c] = fmaxf(fmaxf(mxv[c], m2[c]), m3[c]);
            mxv[c] = fmaxf(fmaxf(mxv[c], m4[c]), m5[c]);
            mxv[c] = fmaxf(fmaxf(mxv[c], m6[c]), m7[c]);
            mnv[c] = fminf(fminf(mnv[c], m0[c]), m1[c]);
            mnv[c] = fminf(fminf(mnv[c], m2[c]), m3[c]);
            mnv[c] = fminf(fminf(mnv[c], m4[c]), m5[c]);
            mnv[c] = fminf(fminf(mnv[c], m6[c]), m7[c]);
        }
    }
    if (e + 4 <= end) {                          // one 4-edge block
        int4 c01 = *(const int4*)(csr + e);
        int4 c23 = *(const int4*)(csr + e + 2);
        float4 h0 = *(const float4*)(hbB + c01.x), r0 = *(const float4*)(reB + c01.y);
        float4 h1 = *(const float4*)(hbB + c01.z), r1 = *(const float4*)(reB + c01.w);
        float4 h2 = *(const float4*)(hbB + c23.x), r2 = *(const float4*)(reB + c23.y);
        float4 h3 = *(const float4*)(hbB + c23.z), r3 = *(const float4*)(reB + c23.w);
        float m0[4] = {h0.x * r0.x, h0.y * r0.y, h0.z * r0.z, h0.w * r0.w};
        float m1[4] = {h1.x * r1.x, h1.y * r1.y, h1.z * r1.z, h1.w * r1.w};
        float m2[4] = {h2.x * r2.x, h2.y * r2.y, h2.z * r2.z, h2.w * r2.w};
        float m3[4] = {h3.x * r3.x, h3.y * r3.y, h3.z * r3.z, h3.w * r3.w};
        #pragma unroll
        for (int c = 0; c < 4; ++c) {
            sv[c] += (m0[c] + m1[c]) + (m2[c] + m3[c]);
            ssv[c] = fmaf(m0[c], m0[c], ssv[c]);
            ssv[c] = fmaf(m1[c], m1[c], ssv[c]);
            ssv[c] = fmaf(m2[c], m2[c], ssv[c]);
            ssv[c] = fmaf(m3[c], m3[c], ssv[c]);
            mxv[c] = fmaxf(fmaxf(mxv[c], m0[c]), m1[c]);
            mxv[c] = fmaxf(fmaxf(mxv[c], m2[c]), m3[c]);
            mnv[c] = fminf(fminf(mnv[c], m0[c]), m1[c]);
            mnv[c] = fminf(fminf(mnv[c], m2[c]), m3[c]);
        }
        e += 4;
    }
    for (; e < end; ++e) EDGE1(e);
#undef EDGE1

    float degf = (float)(dg + 1);
    float inv = 1.0f / degf;
    float4 h4 = *(const float4*)(hbB + sidx * (ND * 4));
    float hself[4] = {h4.x, h4.y, h4.z, h4.w};

    #pragma unroll
    for (int f = 0; f < 5; ++f) {
        float vals[4];
        #pragma unroll
        for (int c = 0; c < 4; ++c) {
            float v;
            if (f == 0) v = hself[c];
            else if (f == 1) v = sv[c] * inv;
            else if (f == 2) v = mxv[c];
            else if (f == 3) v = mnv[c];
            else {
                float mean = sv[c] * inv;
                v = sqrtf(fmaxf(ssv[c] * inv - mean * mean, 0.f));
            }
            vals[c] = v;
        }
        ushort4 vh, vl;
        bf16split(vals[0], vh.x, vl.x);
        bf16split(vals[1], vh.y, vl.y);
        bf16split(vals[2], vh.z, vl.z);
        bf16split(vals[3], vh.w, vl.w);
        *(ushort4*)&ldsAh[rowl][f * 32 + d0] = vh;
        *(ushort4*)&ldsAl[rowl][f * 32 + d0] = vl;
    }
    __syncthreads();

    // -------- phase 2: MFMA update --------
    int mt = w >> 1, nt = w & 1;
    int am = lane & 15, kg = lane >> 4;
    int arow = mt * 16 + am;
    const bf16x8v* Bh = (const bf16x8v*)(Wph + (size_t)nt * 13 * 64 * 8);
    const bf16x8v* Bl = (const bf16x8v*)(Wpl + (size_t)nt * 13 * 64 * 8);

    f32x4v acc_a = {0.f, 0.f, 0.f, 0.f};
    f32x4v acc2  = {0.f, 0.f, 0.f, 0.f};
    f32x4v acc3  = {0.f, 0.f, 0.f, 0.f};

#define STEP(S, ACC)                                                              \
    {                                                                             \
        bf16x8v bh = Bh[(S) * 64 + lane];                                         \
        bf16x8v bl = Bl[(S) * 64 + lane];                                         \
        ACC = __builtin_amdgcn_mfma_f32_16x16x32_bf16(ah, bh, ACC, 0, 0, 0);      \
        ACC = __builtin_amdgcn_mfma_f32_16x16x32_bf16(ah, bl, ACC, 0, 0, 0);      \
        ACC = __builtin_amdgcn_mfma_f32_16x16x32_bf16(al, bh, ACC, 0, 0, 0);      \
    }
    #pragma unroll
    for (int c = 0; c < 5; ++c) {
        bf16x8v ah = *(const bf16x8v*)&ldsAh[arow][c * 32 + kg * 8];
        bf16x8v al = *(const bf16x8v*)&ldsAl[arow][c * 32 + kg * 8];
        if (c == 0) {
            STEP(0, acc_a)
        } else {
            STEP(c, acc_a)
            STEP(c + 4, acc2)
            STEP(c + 8, acc3)
        }
    }
#undef STEP

    int j = nt * 16 + am;
    float bj = bias[j];
    #pragma unroll
    for (int rr = 0; rr < 4; ++rr) {
        int gi = blk * 32 + mt * 16 + 4 * kg + rr;
        if (gi < n) {
            int ix = list[gi];
            int bb = ix / NN;
            int pp = ix - bb * NN;
            float2 sc = scales2[pp];
            float v = acc_a[rr] + sc.x * acc2[rr] + sc.y * acc3[rr] + bj;
            size_t o = (size_t)ix * 32 + j;
            hnew[o] = fmaxf(v, 0.f) + hin[o];
        }
    }
}

// ---------------- final MLP scorer: block per (b,t); uniform fallback via taff ----------------
__global__ __launch_bounds__(64) void score_kernel(
    const float* __restrict__ hidden, const int* __restrict__ t_index,
    const int* __restrict__ ipern, const unsigned char* __restrict__ taff,
    const float* __restrict__ b2l,
    const int* __restrict__ r_index, const float* __restrict__ qw,
    const float* __restrict__ w1, const float* __restrict__ b1,
    const float* __restrict__ w2, const float* __restrict__ b2,
    float* __restrict__ out) {
    int i = blockIdx.x;                       // 0..NB*NT-1
    int b = i / NT;
    int j = threadIdx.x;                      // 0..63
    int node = ipern[t_index[i]];             // sorted-space row
    __shared__ float feat[2 * ND];
    if (j < ND) {
        feat[j] = taff[i] ? hidden[((size_t)b * NN + node) * ND + j]
                          : fmaxf(b2l[j], 0.f);   // uniform background hidden3
    } else {
        feat[j] = qw[r_index[b] * ND + (j - ND)];
    }
    __syncthreads();
    float a = b1[j];
    #pragma unroll
    for (int kk = 0; kk < 2 * ND; ++kk) a = fmaf(feat[kk], w1[kk * 2 * ND + j], a);
    float v = fmaxf(a, 0.f) * w2[j];
    #pragma unroll
    for (int off = 32; off > 0; off >>= 1) v += __shfl_down(v, off, 64);
    if (j == 0) out[i] = v + b2[0];
}

extern "C" void kernel_launch(void* const* d_in, const int* in_sizes, int n_in,
                              void* d_out, int out_size, void* d_ws, size_t ws_size,
                              hipStream_t stream) {
    (void)in_sizes; (void)n_in; (void)out_size; (void)ws_size;
    const int* edge_index = (const int*)d_in[0];     // [2][E]
    const int* edge_type  = (const int*)d_in[1];     // [E]
    const int* h_index    = (const int*)d_in[2];     // [B]
    const int* r_index    = (const int*)d_in[3];     // [B]
    const int* t_index    = (const int*)d_in[4];     // [B][T]
    const float* query_weight = (const float*)d_in[5];  // [R][D]
    const float* rel_lin_w    = (const float*)d_in[6];  // [L][D][R*D]
    const float* layer_w      = (const float*)d_in[7];  // [L][13D][D]
    const float* layer_b      = (const float*)d_in[8];  // [L][D]
    const float* mlp_w1 = (const float*)d_in[9];
    const float* mlp_b1 = (const float*)d_in[10];
    const float* mlp_w2 = (const float*)d_in[11];
    const float* mlp_b2 = (const float*)d_in[12];
    float* out = (float*)d_out;

    const int* src = edge_index;
    const int* dst = edge_index + NE;

    char* wsp = (char*)d_ws;
    size_t off = 0;
    auto alloc = [&](size_t bytes) -> void* {
        void* p = wsp + off;
        off += (bytes + 255) & ~(size_t)255;
        return p;
    };
    float* hA      = (float*)alloc(sizeof(float) * M_TOT * ND);
    float* hB      = (float*)alloc(sizeof(float) * M_TOT * ND);
    unsigned short* Wph = (unsigned short*)alloc(sizeof(unsigned short) * NL * 2 * 13 * 64 * 8);
    unsigned short* Wpl = (unsigned short*)alloc(sizeof(unsigned short) * NL * 2 * 13 * 64 * 8);
    float* rel     = (float*)alloc(sizeof(float) * NL * NB * NR * ND);
    int2*  csr     = (int2*)alloc(sizeof(int2) * NE);
    int*   offsets = (int*)alloc(sizeof(int) * NN);
    int*   ic      = (int*)alloc(sizeof(int) * 2 * NN);   // indeg | cursor
    int*   indeg   = ic;
    int*   cursor  = ic + NN;
    int*   ipern   = (int*)alloc(sizeof(int) * NN);
    int*   invp    = (int*)alloc(sizeof(int) * NN);
    int2*  begdeg  = (int2*)alloc(sizeof(int2) * NN);
    float2* scales2 = (float2*)alloc(sizeof(float2) * NN);
    int*   hpos    = (int*)alloc(sizeof(int) * NB);
    // ---- zeroed region start ----
    int*   bucketCnt    = (int*)alloc(sizeof(int) * 256);
    int*   bucketCursor = (int*)alloc(sizeof(int) * 256);
    float* logsum  = (float*)alloc(sizeof(float) * 1);
    int*   edgeTotal = (int*)alloc(sizeof(int) * 1);
    int*   affCnt  = (int*)alloc(sizeof(int) * 1);
    int*   cnt2    = (int*)alloc(sizeof(int) * 1);
    int*   cnt3    = (int*)alloc(sizeof(int) * 1);
    int*   f1n     = (int*)alloc(sizeof(int) * NN);
    int*   f2n     = (int*)alloc(sizeof(int) * NN);
    size_t zbytes = (size_t)((char*)(f2n + NN) - (char*)bucketCnt);
    // ---- zeroed region end ----
    int*   zb      = (int*)alloc(sizeof(int) * 2);
    int4*  affList = (int4*)alloc(sizeof(int4) * AFF_CAP);
    int*   list2   = (int*)alloc(sizeof(int) * M_TOT);
    int*   list3   = (int*)alloc(sizeof(int) * M_TOT);
    unsigned char* taff = (unsigned char*)alloc(NB * NT);

    hipMemsetAsync(ic, 0, sizeof(int) * 2 * NN, stream);
    hipMemsetAsync(bucketCnt, 0, zbytes, stream);

    count_kernel<<<(NE + 255) / 256, 256, 0, stream>>>(src, dst, h_index, indeg, f1n);
    nodeprep_kernel<<<(NN + 255) / 256, 256, 0, stream>>>(indeg, offsets, bucketCnt,
                                                          logsum, edgeTotal);
    bucket_prefix_kernel<<<1, 256, 0, stream>>>(bucketCnt, bucketCursor, layer_b, zb);
    sortmap_kernel<<<(NN + 255) / 256, 256, 0, stream>>>(indeg, offsets, bucketCursor,
                                                         logsum, ipern, invp, begdeg,
                                                         scales2, hpos, h_index);
    scatter_kernel<<<SCAT_BLKS + 1, 256, 0, stream>>>(src, dst, edge_type, offsets,
                                                      ipern, cursor, csr,
                                                      h_index, hpos, f1n, f2n,
                                                      affCnt, affList);
    relwpack_kernel<<<REL_BLOCKS + (NL * 2 * 13 * 64 + 255) / 256, 256, 0, stream>>>(
        query_weight, r_index, rel_lin_w, rel, layer_w, Wph, Wpl);

    // ---- layer 0: fill + sparse fixup (boundary sparsity is structural) ----
    fill_kernel<<<(M_TOT * 8 + 255) / 256, 256, 0, stream>>>(hA, layer_b);
    fixup_kernel<<<AFF_CAP, 64, 0, stream>>>(hA, rel, layer_w, layer_b, scales2,
                                             begdeg, hpos, r_index, query_weight,
                                             affCnt, affList);

    // ---- layer 1: frontier2 = f1|f2 (or all rows if background nonzero) ----
    compact_kernel<<<(M_TOT + 255) / 256, 256, 0, stream>>>(f1n, f2n, f2n, invp, zb, 0,
                                                            cnt2, list2);
    fill_kernel<<<(M_TOT * 8 + 255) / 256, 256, 0, stream>>>(hB, layer_b + ND);
    list_layer_kernel<<<M_TOT / 32, 256, 0, stream>>>(
        hA, hB, rel + (size_t)1 * NB * NR * ND,
        Wph + (size_t)1 * 2 * 13 * 64 * 8, Wpl + (size_t)1 * 2 * 13 * 64 * 8,
        layer_b + ND, scales2, begdeg, csr, hpos, r_index, query_weight, cnt2, list2);

    // ---- layer 2: backward-sliced to flagged t rows (or all rows in fallback) ----
    taffect_kernel<<<NB * NT, 64, 0, stream>>>(t_index, ipern, invp, begdeg, csr,
                                               f1n, f2n, zb, taff);
    compact3_kernel<<<(M_TOT + 255) / 256, 256, 0, stream>>>(t_index, ipern, taff, zb,
                                                             cnt3, list3);
    list_layer_kernel<<<M_TOT / 32, 256, 0, stream>>>(
        hB, hA, rel + (size_t)2 * NB * NR * ND,
        Wph + (size_t)2 * 2 * 13 * 64 * 8, Wpl + (size_t)2 * 2 * 13 * 64 * 8,
        layer_b + 2 * ND, scales2, begdeg, csr, hpos, r_index, query_weight, cnt3, list3);

    score_kernel<<<NB * NT, 64, 0, stream>>>(hA, t_index, ipern, taff, layer_b + 2 * ND,
                                             r_index, query_weight,
                                             mlp_w1, mlp_b1, mlp_w2, mlp_b2, out);
}

// Round 21
// 153.174 us; speedup vs baseline: 1.4576x; 1.0615x over previous
//
#include <hip/hip_runtime.h>
#include <math.h>

#define NN 20000   // nodes
#define NE 480000  // edges
#define NB 4       // batch
#define ND 32      // dim
#define NR 474     // relations
#define NL 3       // layers
#define NT 64      // tails
#define M_TOT (NB * NN)   // 80000 node-rows
#define LROW 168          // padded LDS row (bf16 units)
#define AFF_CAP 1024      // layer-0 affected entries (~100)
#define FILLB (M_TOT * 8 / 256)   // 2500 fill blocks per buffer

typedef __attribute__((ext_vector_type(8))) short bf16x8v;
typedef __attribute__((ext_vector_type(4))) float f32x4v;

// RNE split of f32 into bf16 hi + bf16 lo (a ~= hi + lo, err ~2^-18 rel)
__device__ inline void bf16split(float a, unsigned short& h, unsigned short& l) {
    unsigned u = __float_as_uint(a);
    unsigned r = u + 0x7FFFu + ((u >> 16) & 1u);
    h = (unsigned short)(r >> 16);
    float fh = __uint_as_float((unsigned)h << 16);
    float res = a - fh;
    unsigned v = __float_as_uint(res);
    unsigned r2 = v + 0x7FFFu + ((v >> 16) & 1u);
    l = (unsigned short)(r2 >> 16);
}

// ---------------- CSR count + layer-0 frontier bits ----------------
__global__ __launch_bounds__(256) void count_kernel(const int* __restrict__ src,
                                                    const int* __restrict__ dst,
                                                    const int* __restrict__ h_index,
                                                    int* __restrict__ indeg,
                                                    int* __restrict__ f1n) {
    int e = blockIdx.x * blockDim.x + threadIdx.x;
    if (e < NB) atomicOr(&f1n[h_index[e]], 1 << e);       // head rows
    if (e >= NE) return;
    int dn = dst[e];
    atomicAdd(&indeg[dn], 1);
    int sn = src[e];
    #pragma unroll
    for (int b = 0; b < NB; ++b)
        if (sn == h_index[b]) atomicOr(&f1n[dn], 1 << b);
}

// offsets via wave-scan + ONE atomic/wave slab alloc; log-degree sum
__global__ __launch_bounds__(256) void nodeprep_kernel(
    const int* __restrict__ indeg, int* __restrict__ offsets,
    float* __restrict__ logsum, int* __restrict__ edgeTotal) {
    int t = threadIdx.x;
    int n = blockIdx.x * 256 + t;
    int lane = t & 63;
    int dg = (n < NN) ? indeg[n] : 0;
    float v = (n < NN) ? logf((float)(dg + 2)) : 0.f;   // log(deg+1), deg = indeg+1

    int inc = dg;
    #pragma unroll
    for (int o = 1; o < 64; o <<= 1) {
        int u = __shfl_up(inc, o, 64);
        if (lane >= o) inc += u;
    }
    int waveTot = __shfl(inc, 63, 64);
    int base = 0;
    if (lane == 63) base = atomicAdd(edgeTotal, waveTot);   // 1 atomic per wave
    base = __shfl(base, 63, 64);
    if (n < NN) offsets[n] = base + inc - dg;
    #pragma unroll
    for (int o = 32; o > 0; o >>= 1) v += __shfl_down(v, o, 64);
    if (lane == 0) atomicAdd(logsum, v);
}

// begdeg + PNA scales (identity node order) + zero-background gate flags
__global__ __launch_bounds__(256) void zbscales_kernel(
    const int* __restrict__ indeg, const int* __restrict__ offsets,
    const float* __restrict__ logsum, int2* __restrict__ begdeg,
    float2* __restrict__ scales2,
    const float* __restrict__ layer_b, int* __restrict__ zb) {
    int n = blockIdx.x * 256 + threadIdx.x;
    if (blockIdx.x == 0 && threadIdx.x == 0) {
        int a = 1, b = 1;
        for (int j = 0; j < ND; ++j) {
            if (layer_b[j] > 0.f) a = 0;
            if (layer_b[ND + j] > 0.f) b = 0;
        }
        zb[0] = a;            // background of hidden1 is zero
        zb[1] = a && b;       // background of hidden2 is zero
    }
    if (n >= NN) return;
    int dg = indeg[n];
    begdeg[n] = make_int2(offsets[n], dg);
    float fac = (float)NN / *logsum;
    float scl = logf((float)(dg + 2)) * fac;
    scales2[n] = make_float2(scl, 1.0f / fmaxf(scl, 1e-2f));
}

// csr scatter (csr.x = src*128 byte off) + f2n propagation + affList (+ head rows)
#define SCAT_BLKS (NE / 256)   // 1875 exact
__global__ __launch_bounds__(256) void scatter_kernel(const int* __restrict__ src,
                                                      const int* __restrict__ dst,
                                                      const int* __restrict__ etype,
                                                      const int* __restrict__ offsets,
                                                      int* __restrict__ cursor,
                                                      int2* __restrict__ csr,
                                                      const int* __restrict__ h_index,
                                                      const int* __restrict__ f1n,
                                                      int* __restrict__ f2n,
                                                      int* __restrict__ affCnt,
                                                      int4* __restrict__ affList) {
    if (blockIdx.x == SCAT_BLKS) {               // head-row affList entries
        int b = threadIdx.x;
        if (b < NB) {
            int p = atomicAdd(affCnt, 1);
            if (p < AFF_CAP) affList[p] = make_int4(b, h_index[b], -1, 0);
        }
        return;
    }
    int e = blockIdx.x * 256 + threadIdx.x;
    int dn = dst[e];
    int sn = src[e];
    int pos = atomicAdd(&cursor[dn], 1);
    csr[offsets[dn] + pos] = make_int2(sn * (ND * 4), etype[e] * (ND * 4));
    int v = f1n[sn];
    if (v) atomicOr(&f2n[dn], v);                // frontier2 = neighbors of frontier1
    #pragma unroll
    for (int b = 0; b < NB; ++b) {
        if (sn == h_index[b]) {
            int p = atomicAdd(affCnt, 1);
            if (p < AFF_CAP) affList[p] = make_int4(b, dn, etype[e], 0);
        }
    }
}

// ---------------- rel embeddings (4 batches/thread) + W pack, one kernel ----------------
#define REL_T (NL * NR * ND)              // 45504
#define REL_BLOCKS ((REL_T + 255) / 256)  // 178
__global__ __launch_bounds__(256) void relwpack_kernel(
    const float* __restrict__ qw, const int* __restrict__ r_index,
    const float* __restrict__ rlw, float* __restrict__ rel,
    const float* __restrict__ W, unsigned short* __restrict__ Wph,
    unsigned short* __restrict__ Wpl) {
    if (blockIdx.x < REL_BLOCKS) {
        int i = blockIdx.x * 256 + threadIdx.x;
        if (i >= REL_T) return;
        int d = i & (ND - 1);
        int rd = i >> 5;
        int r = rd % NR;
        int l = rd / NR;
        const float* q0 = qw + r_index[0] * ND;
        const float* q1 = qw + r_index[1] * ND;
        const float* q2 = qw + r_index[2] * ND;
        const float* q3 = qw + r_index[3] * ND;
        const float* w = rlw + (size_t)l * ND * NR * ND + (size_t)r * ND + d;
        float a0 = 0.f, a1 = 0.f, a2 = 0.f, a3 = 0.f;
        #pragma unroll
        for (int k = 0; k < ND; ++k) {
            float wk = w[(size_t)k * NR * ND];
            a0 = fmaf(q0[k], wk, a0); a1 = fmaf(q1[k], wk, a1);
            a2 = fmaf(q2[k], wk, a2); a3 = fmaf(q3[k], wk, a3);
        }
        size_t o = ((size_t)l * NB * NR + r) * ND + d;
        rel[o] = a0;
        rel[o + (size_t)NR * ND] = a1;
        rel[o + (size_t)2 * NR * ND] = a2;
        rel[o + (size_t)3 * NR * ND] = a3;
    } else {
        int t = (blockIdx.x - REL_BLOCKS) * 256 + threadIdx.x;
        if (t >= NL * 2 * 13 * 64) return;
        int lane = t & 63;
        int u = t >> 6;
        int s = u % 13;
        int nt = (u / 13) % 2;
        int l = u / 26;
        int n = nt * 16 + (lane & 15);
        int k0 = s * 32 + (lane >> 4) * 8;
        size_t ob = (size_t)t * 8;
        #pragma unroll
        for (int e = 0; e < 8; ++e) {
            float w = W[(size_t)l * 416 * 32 + (size_t)(k0 + e) * 32 + n];
            unsigned short h8, l8;
            bf16split(w, h8, l8);
            Wph[ob + e] = h8;
            Wpl[ob + e] = l8;
        }
    }
}

// ---------------- bigfill: fill hA (skip f1 rows) | fill hB | layer-0 fixup ----------------
// blocks [0,FILLB): hA = relu(b0) except f1-marked rows (fixup writes those; disjoint)
// blocks [FILLB,2*FILLB): hB = relu(b1)
// blocks [2*FILLB, 2*FILLB+AFF_CAP): fixup of affList entries (wave 0 active)
__global__ __launch_bounds__(256) void bigfill_kernel(
    float* __restrict__ hA, float* __restrict__ hB,
    const float* __restrict__ rel0, const float* __restrict__ W0,
    const float* __restrict__ layer_b, const float2* __restrict__ scales2,
    const int2* __restrict__ begdeg, const int* __restrict__ f1n,
    const int* __restrict__ h_index, const int* __restrict__ r_index,
    const float* __restrict__ qw,
    const int* __restrict__ affCnt, const int4* __restrict__ affList) {
    int blk = blockIdx.x;
    if (blk < 2 * FILLB) {                       // fills
        bool isA = blk < FILLB;
        const float* bias = isA ? layer_b : layer_b + ND;
        float* dst = isA ? hA : hB;
        __shared__ float rb[ND];
        if (threadIdx.x < ND) rb[threadIdx.x] = fmaxf(bias[threadIdx.x], 0.f);
        __syncthreads();
        int i = (isA ? blk : blk - FILLB) * 256 + threadIdx.x;   // float4 slot
        if (i >= M_TOT * 8) return;
        if (isA) {
            int row = i >> 3;
            int b = row / NN, node = row - b * NN;
            if ((f1n[node] >> b) & 1) return;    // fixup owns this row
        }
        int q = (i & 7) * 4;
        ((float4*)dst)[i] = make_float4(rb[q], rb[q + 1], rb[q + 2], rb[q + 3]);
        return;
    }
    // ---- fixup part (messages = q (x) rel0[et] only; hidden0 = boundary) ----
    __shared__ float F[5][ND];
    __shared__ int4 ent[AFF_CAP];
    int cnt = *affCnt;
    if (cnt > AFF_CAP) cnt = AFF_CAP;
    int fb = blk - 2 * FILLB;
    int t = threadIdx.x;
    for (int i = t; i < cnt; i += 256) ent[i] = affList[i];
    __syncthreads();
    if (fb >= cnt) return;

    int4 me = ent[fb];
    int b = me.x, row = me.y;
    for (int i = 0; i < fb; ++i) {               // dedupe (block-uniform)
        int4 o = ent[i];
        if (o.x == b && o.y == row) return;
    }
    int hn = h_index[b];
    const float* q = qw + r_index[b] * ND;
    int deg = begdeg[row].y;

    if (t < ND) {
        int j = t;
        float qj = q[j];
        int nhead = 0;
        float s = 0.f, ss = 0.f, mx = -INFINITY, mn = INFINITY;
        for (int i = 0; i < cnt; ++i) {
            int4 o = ent[i];
            if (o.x == b && o.y == row && o.z >= 0) {
                float m = qj * rel0[((size_t)b * NR + o.z) * ND + j];
                s += m; ss = fmaf(m, m, ss);
                mx = fmaxf(mx, m); mn = fminf(mn, m);
                ++nhead;
            }
        }
        float bm = (row == hn) ? qj : 0.f;
        s += bm; ss = fmaf(bm, bm, ss);
        mx = fmaxf(mx, bm); mn = fminf(mn, bm);
        if (deg - nhead > 0) { mx = fmaxf(mx, 0.f); mn = fminf(mn, 0.f); }
        float inv = 1.0f / (float)(deg + 1);
        float mean = s * inv;
        F[0][j] = bm;
        F[1][j] = mean;
        F[2][j] = mx;
        F[3][j] = mn;
        F[4][j] = sqrtf(fmaxf(ss * inv - mean * mean, 0.f));
    }
    __syncthreads();
    if (t >= 64) return;                          // wave 0 does the GEMV

    int j = t & 31, kh = t >> 5;
    float2 sc = scales2[row];
    float acc = (kh == 0) ? layer_b[j] : 0.f;
    #pragma unroll
    for (int kk = 0; kk < 16; ++kk) {
        int k = kh * 16 + kk;
        acc = fmaf(F[0][k], W0[k * 32 + j], acc);
    }
    #pragma unroll
    for (int f = 1; f < 5; ++f) {
        #pragma unroll
        for (int kk = 0; kk < 16; ++kk) {
            int k = kh * 16 + kk;
            float a = F[f][k];
            int r0 = (f - 1) * 32 + 32 + k;
            acc = fmaf(a, W0[r0 * 32 + j], acc);
            acc = fmaf(a * sc.x, W0[(r0 + 128) * 32 + j], acc);
            acc = fmaf(a * sc.y, W0[(r0 + 256) * 32 + j], acc);
        }
    }
    acc += __shfl_down(acc, 32, 64);
    if (t < ND) {
        size_t o = ((size_t)b * NN + row) * ND + j;
        hA[o] = fmaxf(acc, 0.f) + F[0][j];
    }
}

// ---------------- fused compact2 + taffect ----------------
// blocks [0, C2B): compact (f1|f2 bit b, or all if !zb[0]) -> list2/cnt2
// blocks [C2B, C2B+64): taffect, 4 entries/block (wave per entry)
#define C2B ((M_TOT + 255) / 256)   // 313
__global__ __launch_bounds__(256) void c2taff_kernel(
    const int* __restrict__ f1n, const int* __restrict__ f2n,
    const int* __restrict__ zb,
    int* __restrict__ cnt2, int* __restrict__ list2,
    const int* __restrict__ t_index, const int2* __restrict__ begdeg,
    const int2* __restrict__ csr, unsigned char* __restrict__ taff) {
    if (blockIdx.x < C2B) {
        int i = blockIdx.x * 256 + threadIdx.x;
        bool take = false;
        if (i < M_TOT) {
            int b = i / NN;
            int node = i - b * NN;
            int m = f1n[node] | f2n[node];
            take = (!zb[0]) || ((m >> b) & 1);
        }
        unsigned long long msk = __ballot(take);
        int lane = threadIdx.x & 63;
        int nw = __popcll(msk);
        int base = 0;
        if (lane == 0 && nw) base = atomicAdd(cnt2, nw);
        base = __shfl(base, 0, 64);
        if (take) list2[base + __popcll(msk & ((1ULL << lane) - 1))] = i;
        return;
    }
    // taffect: entry per wave
    int i = (blockIdx.x - C2B) * 4 + (threadIdx.x >> 6);
    if (i >= NB * NT) return;
    int b = i / NT;
    int lane = threadIdx.x & 63;
    int node = t_index[i];
    int aff = ((f1n[node] | f2n[node]) >> b) & 1;
    int2 bd = begdeg[node];
    int a = 0;
    for (int e = bd.x + lane; e < bd.x + bd.y; e += 64) {
        int sn = csr[e].x >> 7;               // src node (byte off / 128)
        a |= ((f1n[sn] | f2n[sn]) >> b) & 1;
    }
    aff |= (__ballot(a) != 0ULL);
    if (!zb[1]) aff = 1;                      // dense fallback: everything computed
    if (lane == 0) taff[i] = (unsigned char)aff;
}

// layer-2 list: flagged t rows only (or all M_TOT rows in dense fallback)
__global__ __launch_bounds__(256) void compact3_kernel(
    const int* __restrict__ t_index,
    const unsigned char* __restrict__ taff, const int* __restrict__ zb,
    int* __restrict__ cnt, int* __restrict__ list) {
    int i = blockIdx.x * 256 + threadIdx.x;
    bool take = false; int val = 0;
    if (!zb[1]) {
        if (i < M_TOT) { take = true; val = i; }
    } else if (i < NB * NT) {
        take = taff[i] != 0;
        val = (i / NT) * NN + t_index[i];
    }
    unsigned long long msk = __ballot(take);
    int lane = threadIdx.x & 63;
    int nw = __popcll(msk);
    int base = 0;
    if (lane == 0 && nw) base = atomicAdd(cnt, nw);
    base = __shfl(base, 0, 64);
    if (take) list[base + __popcll(msk & ((1ULL << lane) - 1))] = val;
}

// ---------------- list-driven fused layer (rows from work list) ----------------
__global__ __launch_bounds__(256, 4) void list_layer_kernel(
    const float* __restrict__ hin, float* __restrict__ hnew,
    const float* __restrict__ rel,               // [B][R][D] this layer
    const unsigned short* __restrict__ Wph, const unsigned short* __restrict__ Wpl,
    const float* __restrict__ bias, const float2* __restrict__ scales2,
    const int2* __restrict__ begdeg, const int2* __restrict__ csr,
    const int* __restrict__ h_index, const int* __restrict__ r_index,
    const float* __restrict__ qw,
    const int* __restrict__ cnt, const int* __restrict__ list) {
    __shared__ __align__(16) unsigned short ldsAh[32][LROW];
    __shared__ __align__(16) unsigned short ldsAl[32][LROW];

    int n = *cnt;
    int blk = blockIdx.x;
    if (blk * 32 >= n) return;                   // block-uniform early exit

    int tid = threadIdx.x;
    int lane = tid & 63;
    int w = tid >> 6;                            // 0..3
    int r8 = lane >> 3;
    int d0 = (lane & 7) * 4;                     // dim quartet
    int d4 = d0 * 4;                             // byte offset
    int rowl = w * 8 + r8;                       // 0..31
    int li = blk * 32 + rowl;
    bool act = li < n;
    int idx = act ? list[li] : list[0];          // dummy -> valid row 0
    int b = idx / NN;
    int sidx = idx - b * NN;                     // node (identity order)
    const char* hbB = (const char*)hin + (size_t)b * (NN * ND * 4) + d4;
    const char* reB = (const char*)rel + (size_t)b * (NR * ND * 4) + d4;

    float sv[4], ssv[4], mxv[4], mnv[4];
    {
        float4 bm4 = make_float4(0.f, 0.f, 0.f, 0.f);
        if (sidx == h_index[b]) bm4 = *(const float4*)(qw + r_index[b] * ND + d0);
        float bm[4] = {bm4.x, bm4.y, bm4.z, bm4.w};
        #pragma unroll
        for (int c = 0; c < 4; ++c) {
            sv[c] = bm[c]; ssv[c] = bm[c] * bm[c]; mxv[c] = bm[c]; mnv[c] = bm[c];
        }
    }

    int2 bd = begdeg[sidx];
    int beg = bd.x, dg = bd.y, end = beg + dg;
#define EDGE1(E)                                                                  \
    {                                                                             \
        int2 a0 = csr[E];                                                         \
        float4 h0 = *(const float4*)(hbB + a0.x);                                 \
        float4 r0 = *(const float4*)(reB + a0.y);                                 \
        float m0[4] = {h0.x * r0.x, h0.y * r0.y, h0.z * r0.z, h0.w * r0.w};       \
        _Pragma("unroll")                                                         \
        for (int c = 0; c < 4; ++c) {                                             \
            sv[c] += m0[c];                                                       \
            ssv[c] = fmaf(m0[c], m0[c], ssv[c]);                                  \
            mxv[c] = fmaxf(mxv[c], m0[c]);                                        \
            mnv[c] = fminf(mnv[c], m0[c]);                                        \
        }                                                                         \
    }
    int e = beg;
    if ((e & 1) && e < end) { EDGE1(e); ++e; }   // align to 16B for int4 loads
    int n8 = (end - e) >> 3;                     // 8-edge chunks
    const int4* cp = (const int4*)(csr + e);
    e += n8 * 8;
    int4 k0, k1, k2, k3;
    if (n8 > 0) { k0 = cp[0]; k1 = cp[1]; k2 = cp[2]; k3 = cp[3]; }
    for (int i = 0; i < n8; ++i) {
        float4 h0 = *(const float4*)(hbB + k0.x), r0 = *(const float4*)(reB + k0.y);
        float4 h1 = *(const float4*)(hbB + k0.z), r1 = *(const float4*)(reB + k0.w);
        float4 h2 = *(const float4*)(hbB + k1.x), r2 = *(const float4*)(reB + k1.y);
        float4 h3 = *(const float4*)(hbB + k1.z), r3 = *(const float4*)(reB + k1.w);
        float4 h4 = *(const float4*)(hbB + k2.x), r4 = *(const float4*)(reB + k2.y);
        float4 h5 = *(const float4*)(hbB + k2.z), r5 = *(const float4*)(reB + k2.w);
        float4 h6 = *(const float4*)(hbB + k3.x), r6 = *(const float4*)(reB + k3.y);
        float4 h7 = *(const float4*)(hbB + k3.z), r7 = *(const float4*)(reB + k3.w);
        cp += 4;
        if (i + 1 < n8) { k0 = cp[0]; k1 = cp[1]; k2 = cp[2]; k3 = cp[3]; }
        float m0[4] = {h0.x * r0.x, h0.y * r0.y, h0.z * r0.z, h0.w * r0.w};
        float m1[4] = {h1.x * r1.x, h1.y * r1.y, h1.z * r1.z, h1.w * r1.w};
        float m2[4] = {h2.x * r2.x, h2.y * r2.y, h2.z * r2.z, h2.w * r2.w};
        float m3[4] = {h3.x * r3.x, h3.y * r3.y, h3.z * r3.z, h3.w * r3.w};
        float m4[4] = {h4.x * r4.x, h4.y * r4.y, h4.z * r4.z, h4.w * r4.w};
        float m5[4] = {h5.x * r5.x, h5.y * r5.y, h5.z * r5.z, h5.w * r5.w};
        float m6[4] = {h6.x * r6.x, h6.y * r6.y, h6.z * r6.z, h6.w * r6.w};
        float m7[4] = {h7.x * r7.x, h7.y * r7.y, h7.z * r7.z, h7.w * r7.w};
        #pragma unroll
        for (int c = 0; c < 4; ++c) {
            sv[c] += ((m0[c] + m1[c]) + (m2[c] + m3[c])) +
                     ((m4[c] + m5[c]) + (m6[c] + m7[c]));
            ssv[c] = fmaf(m0[c], m0[c], ssv[c]);
            ssv[c] = fmaf(m1[c], m1[c], ssv[c]);
            ssv[c] = fmaf(m2[c], m2[c], ssv[c]);
            ssv[c] = fmaf(m3[c], m3[c], ssv[c]);
            ssv[c] = fmaf(m4[c], m4[c], ssv[c]);
            ssv[c] = fmaf(m5[c], m5[c], ssv[c]);
            ssv[c] = fmaf(m6[c], m6[c], ssv[c]);
            ssv[c] = fmaf(m7[c], m7[c], ssv[c]);
            mxv[c] = fmaxf(fmaxf(mxv[c], m0[c]), m1[c]);
            mxv[c] = fmaxf(fmaxf(mxv[c], m2[c]), m3[c]);
            mxv[c] = fmaxf(fmaxf(mxv[c], m4[c]), m5[c]);
            mxv[c] = fmaxf(fmaxf(mxv[c], m6[c]), m7[c]);
            mnv[c] = fminf(fminf(mnv[c], m0[c]), m1[c]);
            mnv[c] = fminf(fminf(mnv[c], m2[c]), m3[c]);
            mnv[c] = fminf(fminf(mnv[c], m4[c]), m5[c]);
            mnv[c] = fminf(fminf(mnv[c], m6[c]), m7[c]);
        }
    }
    if (e + 4 <= end) {                          // one 4-edge block
        int4 c01 = *(const int4*)(csr + e);
        int4 c23 = *(const int4*)(csr + e + 2);
        float4 h0 = *(const float4*)(hbB + c01.x), r0 = *(const float4*)(reB + c01.y);
        float4 h1 = *(const float4*)(hbB + c01.z), r1 = *(const float4*)(reB + c01.w);
        float4 h2 = *(const float4*)(hbB + c23.x), r2 = *(const float4*)(reB + c23.y);
        float4 h3 = *(const float4*)(hbB + c23.z), r3 = *(const float4*)(reB + c23.w);
        float m0[4] = {h0.x * r0.x, h0.y * r0.y, h0.z * r0.z, h0.w * r0.w};
        float m1[4] = {h1.x * r1.x, h1.y * r1.y, h1.z * r1.z, h1.w * r1.w};
        float m2[4] = {h2.x * r2.x, h2.y * r2.y, h2.z * r2.z, h2.w * r2.w};
        float m3[4] = {h3.x * r3.x, h3.y * r3.y, h3.z * r3.z, h3.w * r3.w};
        #pragma unroll
        for (int c = 0; c < 4; ++c) {
            sv[c] += (m0[c] + m1[c]) + (m2[c] + m3[c]);
            ssv[c] = fmaf(m0[c], m0[c], ssv[c]);
            ssv[c] = fmaf(m1[c], m1[c], ssv[c]);
            ssv[c] = fmaf(m2[c], m2[c], ssv[c]);
            ssv[c] = fmaf(m3[c], m3[c], ssv[c]);
            mxv[c] = fmaxf(fmaxf(mxv[c], m0[c]), m1[c]);
            mxv[c] = fmaxf(fmaxf(mxv[c], m2[c]), m3[c]);
            mnv[c] = fminf(fminf(mnv[c], m0[c]), m1[c]);
            mnv[c] = fminf(fminf(mnv[c], m2[c]), m3[c]);
        }
        e += 4;
    }
    for (; e < end; ++e) EDGE1(e);
#undef EDGE1

    float degf = (float)(dg + 1);
    float inv = 1.0f / degf;
    float4 h4 = *(const float4*)(hbB + sidx * (ND * 4));
    float hself[4] = {h4.x, h4.y, h4.z, h4.w};

    #pragma unroll
    for (int f = 0; f < 5; ++f) {
        float vals[4];
        #pragma unroll
        for (int c = 0; c < 4; ++c) {
            float v;
            if (f == 0) v = hself[c];
            else if (f == 1) v = sv[c] * inv;
            else if (f == 2) v = mxv[c];
            else if (f == 3) v = mnv[c];
            else {
                float mean = sv[c] * inv;
                v = sqrtf(fmaxf(ssv[c] * inv - mean * mean, 0.f));
            }
            vals[c] = v;
        }
        ushort4 vh, vl;
        bf16split(vals[0], vh.x, vl.x);
        bf16split(vals[1], vh.y, vl.y);
        bf16split(vals[2], vh.z, vl.z);
        bf16split(vals[3], vh.w, vl.w);
        *(ushort4*)&ldsAh[rowl][f * 32 + d0] = vh;
        *(ushort4*)&ldsAl[rowl][f * 32 + d0] = vl;
    }
    __syncthreads();

    // -------- phase 2: MFMA update --------
    int mt = w >> 1, nt = w & 1;
    int am = lane & 15, kg = lane >> 4;
    int arow = mt * 16 + am;
    const bf16x8v* Bh = (const bf16x8v*)(Wph + (size_t)nt * 13 * 64 * 8);
    const bf16x8v* Bl = (const bf16x8v*)(Wpl + (size_t)nt * 13 * 64 * 8);

    f32x4v acc_a = {0.f, 0.f, 0.f, 0.f};
    f32x4v acc2  = {0.f, 0.f, 0.f, 0.f};
    f32x4v acc3  = {0.f, 0.f, 0.f, 0.f};

#define STEP(S, ACC)                                                              \
    {                                                                             \
        bf16x8v bh = Bh[(S) * 64 + lane];                                         \
        bf16x8v bl = Bl[(S) * 64 + lane];                                         \
        ACC = __builtin_amdgcn_mfma_f32_16x16x32_bf16(ah, bh, ACC, 0, 0, 0);      \
        ACC = __builtin_amdgcn_mfma_f32_16x16x32_bf16(ah, bl, ACC, 0, 0, 0);      \
        ACC = __builtin_amdgcn_mfma_f32_16x16x32_bf16(al, bh, ACC, 0, 0, 0);      \
    }
    #pragma unroll
    for (int c = 0; c < 5; ++c) {
        bf16x8v ah = *(const bf16x8v*)&ldsAh[arow][c * 32 + kg * 8];
        bf16x8v al = *(const bf16x8v*)&ldsAl[arow][c * 32 + kg * 8];
        if (c == 0) {
            STEP(0, acc_a)
        } else {
            STEP(c, acc_a)
            STEP(c + 4, acc2)
            STEP(c + 8, acc3)
        }
    }
#undef STEP

    int j = nt * 16 + am;
    float bj = bias[j];
    #pragma unroll
    for (int rr = 0; rr < 4; ++rr) {
        int gi = blk * 32 + mt * 16 + 4 * kg + rr;
        if (gi < n) {
            int ix = list[gi];
            int bb = ix / NN;
            int pp = ix - bb * NN;
            float2 sc = scales2[pp];
            float v = acc_a[rr] + sc.x * acc2[rr] + sc.y * acc3[rr] + bj;
            size_t o = (size_t)ix * 32 + j;
            hnew[o] = fmaxf(v, 0.f) + hin[o];
        }
    }
}

// ---------------- final MLP scorer: block per (b,t); uniform fallback via taff ----------------
__global__ __launch_bounds__(64) void score_kernel(
    const float* __restrict__ hidden, const int* __restrict__ t_index,
    const unsigned char* __restrict__ taff,
    const float* __restrict__ b2l,
    const int* __restrict__ r_index, const float* __restrict__ qw,
    const float* __restrict__ w1, const float* __restrict__ b1,
    const float* __restrict__ w2, const float* __restrict__ b2,
    float* __restrict__ out) {
    int i = blockIdx.x;                       // 0..NB*NT-1
    int b = i / NT;
    int j = threadIdx.x;                      // 0..63
    int node = t_index[i];
    __shared__ float feat[2 * ND];
    if (j < ND) {
        feat[j] = taff[i] ? hidden[((size_t)b * NN + node) * ND + j]
                          : fmaxf(b2l[j], 0.f);   // uniform background hidden3
    } else {
        feat[j] = qw[r_index[b] * ND + (j - ND)];
    }
    __syncthreads();
    float a = b1[j];
    #pragma unroll
    for (int kk = 0; kk < 2 * ND; ++kk) a = fmaf(feat[kk], w1[kk * 2 * ND + j], a);
    float v = fmaxf(a, 0.f) * w2[j];
    #pragma unroll
    for (int off = 32; off > 0; off >>= 1) v += __shfl_down(v, off, 64);
    if (j == 0) out[i] = v + b2[0];
}

extern "C" void kernel_launch(void* const* d_in, const int* in_sizes, int n_in,
                              void* d_out, int out_size, void* d_ws, size_t ws_size,
                              hipStream_t stream) {
    (void)in_sizes; (void)n_in; (void)out_size; (void)ws_size;
    const int* edge_index = (const int*)d_in[0];     // [2][E]
    const int* edge_type  = (const int*)d_in[1];     // [E]
    const int* h_index    = (const int*)d_in[2];     // [B]
    const int* r_index    = (const int*)d_in[3];     // [B]
    const int* t_index    = (const int*)d_in[4];     // [B][T]
    const float* query_weight = (const float*)d_in[5];  // [R][D]
    const float* rel_lin_w    = (const float*)d_in[6];  // [L][D][R*D]
    const float* layer_w      = (const float*)d_in[7];  // [L][13D][D]
    const float* layer_b      = (const float*)d_in[8];  // [L][D]
    const float* mlp_w1 = (const float*)d_in[9];
    const float* mlp_b1 = (const float*)d_in[10];
    const float* mlp_w2 = (const float*)d_in[11];
    const float* mlp_b2 = (const float*)d_in[12];
    float* out = (float*)d_out;

    const int* src = edge_index;
    const int* dst = edge_index + NE;

    char* wsp = (char*)d_ws;
    size_t off = 0;
    auto alloc = [&](size_t bytes) -> void* {
        void* p = wsp + off;
        off += (bytes + 255) & ~(size_t)255;
        return p;
    };
    float* hA      = (float*)alloc(sizeof(float) * M_TOT * ND);
    float* hB      = (float*)alloc(sizeof(float) * M_TOT * ND);
    unsigned short* Wph = (unsigned short*)alloc(sizeof(unsigned short) * NL * 2 * 13 * 64 * 8);
    unsigned short* Wpl = (unsigned short*)alloc(sizeof(unsigned short) * NL * 2 * 13 * 64 * 8);
    float* rel     = (float*)alloc(sizeof(float) * NL * NB * NR * ND);
    int2*  csr     = (int2*)alloc(sizeof(int2) * NE);
    int*   offsets = (int*)alloc(sizeof(int) * NN);
    int2*  begdeg  = (int2*)alloc(sizeof(int2) * NN);
    float2* scales2 = (float2*)alloc(sizeof(float2) * NN);
    // ---- zeroed region start (contiguous allocs) ----
    int*   indeg   = (int*)alloc(sizeof(int) * NN);
    int*   cursor  = (int*)alloc(sizeof(int) * NN);
    float* logsum  = (float*)alloc(sizeof(float) * 1);
    int*   edgeTotal = (int*)alloc(sizeof(int) * 1);
    int*   affCnt  = (int*)alloc(sizeof(int) * 1);
    int*   cnt2    = (int*)alloc(sizeof(int) * 1);
    int*   cnt3    = (int*)alloc(sizeof(int) * 1);
    int*   f1n     = (int*)alloc(sizeof(int) * NN);
    int*   f2n     = (int*)alloc(sizeof(int) * NN);
    size_t zbytes = (size_t)((char*)(f2n + NN) - (char*)indeg);
    // ---- zeroed region end ----
    int*   zb      = (int*)alloc(sizeof(int) * 2);
    int4*  affList = (int4*)alloc(sizeof(int4) * AFF_CAP);
    int*   list2   = (int*)alloc(sizeof(int) * M_TOT);
    int*   list3   = (int*)alloc(sizeof(int) * M_TOT);
    unsigned char* taff = (unsigned char*)alloc(NB * NT);

    hipMemsetAsync(indeg, 0, zbytes, stream);

    count_kernel<<<(NE + 255) / 256, 256, 0, stream>>>(src, dst, h_index, indeg, f1n);
    nodeprep_kernel<<<(NN + 255) / 256, 256, 0, stream>>>(indeg, offsets, logsum,
                                                          edgeTotal);
    zbscales_kernel<<<(NN + 255) / 256, 256, 0, stream>>>(indeg, offsets, logsum,
                                                          begdeg, scales2, layer_b, zb);
    scatter_kernel<<<SCAT_BLKS + 1, 256, 0, stream>>>(src, dst, edge_type, offsets,
                                                      cursor, csr, h_index,
                                                      f1n, f2n, affCnt, affList);
    relwpack_kernel<<<REL_BLOCKS + (NL * 2 * 13 * 64 + 255) / 256, 256, 0, stream>>>(
        query_weight, r_index, rel_lin_w, rel, layer_w, Wph, Wpl);

    // layer 0: fills + sparse fixup, one kernel (write-disjoint via f1 skip)
    bigfill_kernel<<<2 * FILLB + AFF_CAP, 256, 0, stream>>>(
        hA, hB, rel, layer_w, layer_b, scales2, begdeg, f1n,
        h_index, r_index, query_weight, affCnt, affList);

    // compact2 + taffect fused
    c2taff_kernel<<<C2B + (NB * NT + 3) / 4, 256, 0, stream>>>(
        f1n, f2n, zb, cnt2, list2, t_index, begdeg, csr, taff);

    // layer 1 over frontier2
    list_layer_kernel<<<M_TOT / 32, 256, 0, stream>>>(
        hA, hB, rel + (size_t)1 * NB * NR * ND,
        Wph + (size_t)1 * 2 * 13 * 64 * 8, Wpl + (size_t)1 * 2 * 13 * 64 * 8,
        layer_b + ND, scales2, begdeg, csr, h_index, r_index, query_weight, cnt2, list2);

    // layer 2 backward-sliced to flagged t rows
    compact3_kernel<<<(M_TOT + 255) / 256, 256, 0, stream>>>(t_index, taff, zb,
                                                             cnt3, list3);
    list_layer_kernel<<<M_TOT / 32, 256, 0, stream>>>(
        hB, hA, rel + (size_t)2 * NB * NR * ND,
        Wph + (size_t)2 * 2 * 13 * 64 * 8, Wpl + (size_t)2 * 2 * 13 * 64 * 8,
        layer_b + 2 * ND, scales2, begdeg, csr, h_index, r_index, query_weight,
        cnt3, list3);

    score_kernel<<<NB * NT, 64, 0, stream>>>(hA, t_index, taff, layer_b + 2 * ND,
                                             r_index, query_weight,
                                             mlp_w1, mlp_b1, mlp_w2, mlp_b2, out);
}

// Round 22
// 146.912 us; speedup vs baseline: 1.5197x; 1.0426x over previous
//
#include <hip/hip_runtime.h>
#include <math.h>

#define NN 20000   // nodes
#define NE 480000  // edges
#define NB 4       // batch
#define ND 32      // dim
#define NR 474     // relations
#define NL 3       // layers
#define NT 64      // tails
#define M_TOT (NB * NN)   // 80000 node-rows
#define LROW 168          // padded LDS row (bf16 units)
#define AFF_CAP 1024      // layer-0 affected entries (~100)
#define FILLB (M_TOT * 8 / 256)   // 2500 fill blocks per buffer

typedef __attribute__((ext_vector_type(8))) short bf16x8v;
typedef __attribute__((ext_vector_type(4))) float f32x4v;

// RNE split of f32 into bf16 hi + bf16 lo (a ~= hi + lo, err ~2^-18 rel)
__device__ inline void bf16split(float a, unsigned short& h, unsigned short& l) {
    unsigned u = __float_as_uint(a);
    unsigned r = u + 0x7FFFu + ((u >> 16) & 1u);
    h = (unsigned short)(r >> 16);
    float fh = __uint_as_float((unsigned)h << 16);
    float res = a - fh;
    unsigned v = __float_as_uint(res);
    unsigned r2 = v + 0x7FFFu + ((v >> 16) & 1u);
    l = (unsigned short)(r2 >> 16);
}

// inline PNA scales from degree: scl = log(dg+2) * NN/logsum
__device__ inline float2 pna_scales(int dg, float fac) {
    float scl = logf((float)(dg + 2)) * fac;
    return make_float2(scl, 1.0f / fmaxf(scl, 1e-2f));
}

// ---------------- CSR count + layer-0 frontier bits + zb gate ----------------
__global__ __launch_bounds__(256) void count_kernel(const int* __restrict__ src,
                                                    const int* __restrict__ dst,
                                                    const int* __restrict__ h_index,
                                                    const float* __restrict__ layer_b,
                                                    int* __restrict__ indeg,
                                                    int* __restrict__ f1n,
                                                    int* __restrict__ zb) {
    int e = blockIdx.x * blockDim.x + threadIdx.x;
    if (e == 0) {                                 // zero-background gate flags
        int a = 1, b = 1;
        for (int j = 0; j < ND; ++j) {
            if (layer_b[j] > 0.f) a = 0;
            if (layer_b[ND + j] > 0.f) b = 0;
        }
        zb[0] = a;            // background of hidden1 is zero
        zb[1] = a && b;       // background of hidden2 is zero
    }
    if (e < NB) atomicOr(&f1n[h_index[e]], 1 << e);       // head rows
    if (e >= NE) return;
    int dn = dst[e];
    atomicAdd(&indeg[dn], 1);
    int sn = src[e];
    #pragma unroll
    for (int b = 0; b < NB; ++b)
        if (sn == h_index[b]) atomicOr(&f1n[dn], 1 << b);
}

// offsets via wave-scan + ONE atomic/wave slab alloc; log-degree sum; begdeg
__global__ __launch_bounds__(256) void nodeprep_kernel(
    const int* __restrict__ indeg, int* __restrict__ offsets,
    int2* __restrict__ begdeg,
    float* __restrict__ logsum, int* __restrict__ edgeTotal) {
    int t = threadIdx.x;
    int n = blockIdx.x * 256 + t;
    int lane = t & 63;
    int dg = (n < NN) ? indeg[n] : 0;
    float v = (n < NN) ? logf((float)(dg + 2)) : 0.f;   // log(deg+1), deg = indeg+1

    int inc = dg;
    #pragma unroll
    for (int o = 1; o < 64; o <<= 1) {
        int u = __shfl_up(inc, o, 64);
        if (lane >= o) inc += u;
    }
    int waveTot = __shfl(inc, 63, 64);
    int base = 0;
    if (lane == 63) base = atomicAdd(edgeTotal, waveTot);   // 1 atomic per wave
    base = __shfl(base, 63, 64);
    if (n < NN) {
        int o = base + inc - dg;
        offsets[n] = o;
        begdeg[n] = make_int2(o, dg);
    }
    #pragma unroll
    for (int o = 32; o > 0; o >>= 1) v += __shfl_down(v, o, 64);
    if (lane == 0) atomicAdd(logsum, v);
}

// csr scatter (csr.x = src*128 byte off) + f2n propagation + affList (+ head rows)
#define SCAT_BLKS (NE / 256)   // 1875 exact
__global__ __launch_bounds__(256) void scatter_kernel(const int* __restrict__ src,
                                                      const int* __restrict__ dst,
                                                      const int* __restrict__ etype,
                                                      const int* __restrict__ offsets,
                                                      int* __restrict__ cursor,
                                                      int2* __restrict__ csr,
                                                      const int* __restrict__ h_index,
                                                      const int* __restrict__ f1n,
                                                      int* __restrict__ f2n,
                                                      int* __restrict__ affCnt,
                                                      int4* __restrict__ affList) {
    if (blockIdx.x == SCAT_BLKS) {               // head-row affList entries
        int b = threadIdx.x;
        if (b < NB) {
            int p = atomicAdd(affCnt, 1);
            if (p < AFF_CAP) affList[p] = make_int4(b, h_index[b], -1, 0);
        }
        return;
    }
    int e = blockIdx.x * 256 + threadIdx.x;
    int dn = dst[e];
    int sn = src[e];
    int pos = atomicAdd(&cursor[dn], 1);
    csr[offsets[dn] + pos] = make_int2(sn * (ND * 4), etype[e] * (ND * 4));
    int v = f1n[sn];
    if (v) atomicOr(&f2n[dn], v);                // frontier2 = neighbors of frontier1
    #pragma unroll
    for (int b = 0; b < NB; ++b) {
        if (sn == h_index[b]) {
            int p = atomicAdd(affCnt, 1);
            if (p < AFF_CAP) affList[p] = make_int4(b, dn, etype[e], 0);
        }
    }
}

// ---------------- rel embeddings (4 batches/thread) + W pack, one kernel ----------------
#define REL_T (NL * NR * ND)              // 45504
#define REL_BLOCKS ((REL_T + 255) / 256)  // 178
__global__ __launch_bounds__(256) void relwpack_kernel(
    const float* __restrict__ qw, const int* __restrict__ r_index,
    const float* __restrict__ rlw, float* __restrict__ rel,
    const float* __restrict__ W, unsigned short* __restrict__ Wph,
    unsigned short* __restrict__ Wpl) {
    if (blockIdx.x < REL_BLOCKS) {
        int i = blockIdx.x * 256 + threadIdx.x;
        if (i >= REL_T) return;
        int d = i & (ND - 1);
        int rd = i >> 5;
        int r = rd % NR;
        int l = rd / NR;
        const float* q0 = qw + r_index[0] * ND;
        const float* q1 = qw + r_index[1] * ND;
        const float* q2 = qw + r_index[2] * ND;
        const float* q3 = qw + r_index[3] * ND;
        const float* w = rlw + (size_t)l * ND * NR * ND + (size_t)r * ND + d;
        float a0 = 0.f, a1 = 0.f, a2 = 0.f, a3 = 0.f;
        #pragma unroll
        for (int k = 0; k < ND; ++k) {
            float wk = w[(size_t)k * NR * ND];
            a0 = fmaf(q0[k], wk, a0); a1 = fmaf(q1[k], wk, a1);
            a2 = fmaf(q2[k], wk, a2); a3 = fmaf(q3[k], wk, a3);
        }
        size_t o = ((size_t)l * NB * NR + r) * ND + d;
        rel[o] = a0;
        rel[o + (size_t)NR * ND] = a1;
        rel[o + (size_t)2 * NR * ND] = a2;
        rel[o + (size_t)3 * NR * ND] = a3;
    } else {
        int t = (blockIdx.x - REL_BLOCKS) * 256 + threadIdx.x;
        if (t >= NL * 2 * 13 * 64) return;
        int lane = t & 63;
        int u = t >> 6;
        int s = u % 13;
        int nt = (u / 13) % 2;
        int l = u / 26;
        int n = nt * 16 + (lane & 15);
        int k0 = s * 32 + (lane >> 4) * 8;
        size_t ob = (size_t)t * 8;
        #pragma unroll
        for (int e = 0; e < 8; ++e) {
            float w = W[(size_t)l * 416 * 32 + (size_t)(k0 + e) * 32 + n];
            unsigned short h8, l8;
            bf16split(w, h8, l8);
            Wph[ob + e] = h8;
            Wpl[ob + e] = l8;
        }
    }
}

// ---------------- bigfill: fill hA (skip f1 rows) | fill hB | layer-0 fixup ----------------
__global__ __launch_bounds__(256) void bigfill_kernel(
    float* __restrict__ hA, float* __restrict__ hB,
    const float* __restrict__ rel0, const float* __restrict__ W0,
    const float* __restrict__ layer_b,
    const int2* __restrict__ begdeg, const int* __restrict__ f1n,
    const int* __restrict__ h_index, const int* __restrict__ r_index,
    const float* __restrict__ qw, const float* __restrict__ logsum,
    const int* __restrict__ affCnt, const int4* __restrict__ affList) {
    int blk = blockIdx.x;
    if (blk < 2 * FILLB) {                       // fills
        bool isA = blk < FILLB;
        const float* bias = isA ? layer_b : layer_b + ND;
        float* dst = isA ? hA : hB;
        __shared__ float rb[ND];
        if (threadIdx.x < ND) rb[threadIdx.x] = fmaxf(bias[threadIdx.x], 0.f);
        __syncthreads();
        int i = (isA ? blk : blk - FILLB) * 256 + threadIdx.x;   // float4 slot
        if (i >= M_TOT * 8) return;
        if (isA) {
            int row = i >> 3;
            int b = row / NN, node = row - b * NN;
            if ((f1n[node] >> b) & 1) return;    // fixup owns this row
        }
        int q = (i & 7) * 4;
        ((float4*)dst)[i] = make_float4(rb[q], rb[q + 1], rb[q + 2], rb[q + 3]);
        return;
    }
    // ---- fixup part (messages = q (x) rel0[et] only; hidden0 = boundary) ----
    __shared__ float F[5][ND];
    __shared__ int4 ent[AFF_CAP];
    int cnt = *affCnt;
    if (cnt > AFF_CAP) cnt = AFF_CAP;
    int fb = blk - 2 * FILLB;
    int t = threadIdx.x;
    for (int i = t; i < cnt; i += 256) ent[i] = affList[i];
    __syncthreads();
    if (fb >= cnt) return;

    int4 me = ent[fb];
    int b = me.x, row = me.y;
    for (int i = 0; i < fb; ++i) {               // dedupe (block-uniform)
        int4 o = ent[i];
        if (o.x == b && o.y == row) return;
    }
    int hn = h_index[b];
    const float* q = qw + r_index[b] * ND;
    int deg = begdeg[row].y;

    if (t < ND) {
        int j = t;
        float qj = q[j];
        int nhead = 0;
        float s = 0.f, ss = 0.f, mx = -INFINITY, mn = INFINITY;
        for (int i = 0; i < cnt; ++i) {
            int4 o = ent[i];
            if (o.x == b && o.y == row && o.z >= 0) {
                float m = qj * rel0[((size_t)b * NR + o.z) * ND + j];
                s += m; ss = fmaf(m, m, ss);
                mx = fmaxf(mx, m); mn = fminf(mn, m);
                ++nhead;
            }
        }
        float bm = (row == hn) ? qj : 0.f;
        s += bm; ss = fmaf(bm, bm, ss);
        mx = fmaxf(mx, bm); mn = fminf(mn, bm);
        if (deg - nhead > 0) { mx = fmaxf(mx, 0.f); mn = fminf(mn, 0.f); }
        float inv = 1.0f / (float)(deg + 1);
        float mean = s * inv;
        F[0][j] = bm;
        F[1][j] = mean;
        F[2][j] = mx;
        F[3][j] = mn;
        F[4][j] = sqrtf(fmaxf(ss * inv - mean * mean, 0.f));
    }
    __syncthreads();
    if (t >= 64) return;                          // wave 0 does the GEMV

    int j = t & 31, kh = t >> 5;
    float2 sc = pna_scales(deg, (float)NN / *logsum);
    float acc = (kh == 0) ? layer_b[j] : 0.f;
    #pragma unroll
    for (int kk = 0; kk < 16; ++kk) {
        int k = kh * 16 + kk;
        acc = fmaf(F[0][k], W0[k * 32 + j], acc);
    }
    #pragma unroll
    for (int f = 1; f < 5; ++f) {
        #pragma unroll
        for (int kk = 0; kk < 16; ++kk) {
            int k = kh * 16 + kk;
            float a = F[f][k];
            int r0 = (f - 1) * 32 + 32 + k;
            acc = fmaf(a, W0[r0 * 32 + j], acc);
            acc = fmaf(a * sc.x, W0[(r0 + 128) * 32 + j], acc);
            acc = fmaf(a * sc.y, W0[(r0 + 256) * 32 + j], acc);
        }
    }
    acc += __shfl_down(acc, 32, 64);
    if (t < ND) {
        size_t o = ((size_t)b * NN + row) * ND + j;
        hA[o] = fmaxf(acc, 0.f) + F[0][j];
    }
}

// ---------------- fused compact2 + taffect ----------------
#define C2B ((M_TOT + 255) / 256)   // 313
__global__ __launch_bounds__(256) void c2taff_kernel(
    const int* __restrict__ f1n, const int* __restrict__ f2n,
    const int* __restrict__ zb,
    int* __restrict__ cnt2, int* __restrict__ list2,
    const int* __restrict__ t_index, const int2* __restrict__ begdeg,
    const int2* __restrict__ csr, unsigned char* __restrict__ taff) {
    if (blockIdx.x < C2B) {
        int i = blockIdx.x * 256 + threadIdx.x;
        bool take = false;
        if (i < M_TOT) {
            int b = i / NN;
            int node = i - b * NN;
            int m = f1n[node] | f2n[node];
            take = (!zb[0]) || ((m >> b) & 1);
        }
        unsigned long long msk = __ballot(take);
        int lane = threadIdx.x & 63;
        int nw = __popcll(msk);
        int base = 0;
        if (lane == 0 && nw) base = atomicAdd(cnt2, nw);
        base = __shfl(base, 0, 64);
        if (take) list2[base + __popcll(msk & ((1ULL << lane) - 1))] = i;
        return;
    }
    // taffect: entry per wave
    int i = (blockIdx.x - C2B) * 4 + (threadIdx.x >> 6);
    if (i >= NB * NT) return;
    int b = i / NT;
    int lane = threadIdx.x & 63;
    int node = t_index[i];
    int aff = ((f1n[node] | f2n[node]) >> b) & 1;
    int2 bd = begdeg[node];
    int a = 0;
    for (int e = bd.x + lane; e < bd.x + bd.y; e += 64) {
        int sn = csr[e].x >> 7;               // src node (byte off / 128)
        a |= ((f1n[sn] | f2n[sn]) >> b) & 1;
    }
    aff |= (__ballot(a) != 0ULL);
    if (!zb[1]) aff = 1;                      // dense fallback: everything computed
    if (lane == 0) taff[i] = (unsigned char)aff;
}

// layer-2 list: flagged t rows only (or all M_TOT rows in dense fallback)
__global__ __launch_bounds__(256) void compact3_kernel(
    const int* __restrict__ t_index,
    const unsigned char* __restrict__ taff, const int* __restrict__ zb,
    int* __restrict__ cnt, int* __restrict__ list) {
    int i = blockIdx.x * 256 + threadIdx.x;
    bool take = false; int val = 0;
    if (!zb[1]) {
        if (i < M_TOT) { take = true; val = i; }
    } else if (i < NB * NT) {
        take = taff[i] != 0;
        val = (i / NT) * NN + t_index[i];
    }
    unsigned long long msk = __ballot(take);
    int lane = threadIdx.x & 63;
    int nw = __popcll(msk);
    int base = 0;
    if (lane == 0 && nw) base = atomicAdd(cnt, nw);
    base = __shfl(base, 0, 64);
    if (take) list[base + __popcll(msk & ((1ULL << lane) - 1))] = val;
}

// ---------------- list-driven fused layer (rows from work list) ----------------
__global__ __launch_bounds__(256, 4) void list_layer_kernel(
    const float* __restrict__ hin, float* __restrict__ hnew,
    const float* __restrict__ rel,               // [B][R][D] this layer
    const unsigned short* __restrict__ Wph, const unsigned short* __restrict__ Wpl,
    const float* __restrict__ bias, const float* __restrict__ logsum,
    const int2* __restrict__ begdeg, const int2* __restrict__ csr,
    const int* __restrict__ h_index, const int* __restrict__ r_index,
    const float* __restrict__ qw,
    const int* __restrict__ cnt, const int* __restrict__ list) {
    __shared__ __align__(16) unsigned short ldsAh[32][LROW];
    __shared__ __align__(16) unsigned short ldsAl[32][LROW];

    int n = *cnt;
    int blk = blockIdx.x;
    if (blk * 32 >= n) return;                   // block-uniform early exit

    int tid = threadIdx.x;
    int lane = tid & 63;
    int w = tid >> 6;                            // 0..3
    int r8 = lane >> 3;
    int d0 = (lane & 7) * 4;                     // dim quartet
    int d4 = d0 * 4;                             // byte offset
    int rowl = w * 8 + r8;                       // 0..31
    int li = blk * 32 + rowl;
    bool act = li < n;
    int idx = act ? list[li] : list[0];          // dummy -> valid row 0
    int b = idx / NN;
    int sidx = idx - b * NN;                     // node (identity order)
    const char* hbB = (const char*)hin + (size_t)b * (NN * ND * 4) + d4;
    const char* reB = (const char*)rel + (size_t)b * (NR * ND * 4) + d4;

    float sv[4], ssv[4], mxv[4], mnv[4];
    {
        float4 bm4 = make_float4(0.f, 0.f, 0.f, 0.f);
        if (sidx == h_index[b]) bm4 = *(const float4*)(qw + r_index[b] * ND + d0);
        float bm[4] = {bm4.x, bm4.y, bm4.z, bm4.w};
        #pragma unroll
        for (int c = 0; c < 4; ++c) {
            sv[c] = bm[c]; ssv[c] = bm[c] * bm[c]; mxv[c] = bm[c]; mnv[c] = bm[c];
        }
    }

    int2 bd = begdeg[sidx];
    int beg = bd.x, dg = bd.y, end = beg + dg;
#define EDGE1(E)                                                                  \
    {                                                                             \
        int2 a0 = csr[E];                                                         \
        float4 h0 = *(const float4*)(hbB + a0.x);                                 \
        float4 r0 = *(const float4*)(reB + a0.y);                                 \
        float m0[4] = {h0.x * r0.x, h0.y * r0.y, h0.z * r0.z, h0.w * r0.w};       \
        _Pragma("unroll")                                                         \
        for (int c = 0; c < 4; ++c) {                                             \
            sv[c] += m0[c];                                                       \
            ssv[c] = fmaf(m0[c], m0[c], ssv[c]);                                  \
            mxv[c] = fmaxf(mxv[c], m0[c]);                                        \
            mnv[c] = fminf(mnv[c], m0[c]);                                        \
        }                                                                         \
    }
    int e = beg;
    if ((e & 1) && e < end) { EDGE1(e); ++e; }   // align to 16B for int4 loads
    int n8 = (end - e) >> 3;                     // 8-edge chunks
    const int4* cp = (const int4*)(csr + e);
    e += n8 * 8;
    int4 k0, k1, k2, k3;
    if (n8 > 0) { k0 = cp[0]; k1 = cp[1]; k2 = cp[2]; k3 = cp[3]; }
    for (int i = 0; i < n8; ++i) {
        float4 h0 = *(const float4*)(hbB + k0.x), r0 = *(const float4*)(reB + k0.y);
        float4 h1 = *(const float4*)(hbB + k0.z), r1 = *(const float4*)(reB + k0.w);
        float4 h2 = *(const float4*)(hbB + k1.x), r2 = *(const float4*)(reB + k1.y);
        float4 h3 = *(const float4*)(hbB + k1.z), r3 = *(const float4*)(reB + k1.w);
        float4 h4 = *(const float4*)(hbB + k2.x), r4 = *(const float4*)(reB + k2.y);
        float4 h5 = *(const float4*)(hbB + k2.z), r5 = *(const float4*)(reB + k2.w);
        float4 h6 = *(const float4*)(hbB + k3.x), r6 = *(const float4*)(reB + k3.y);
        float4 h7 = *(const float4*)(hbB + k3.z), r7 = *(const float4*)(reB + k3.w);
        cp += 4;
        if (i + 1 < n8) { k0 = cp[0]; k1 = cp[1]; k2 = cp[2]; k3 = cp[3]; }
        float m0[4] = {h0.x * r0.x, h0.y * r0.y, h0.z * r0.z, h0.w * r0.w};
        float m1[4] = {h1.x * r1.x, h1.y * r1.y, h1.z * r1.z, h1.w * r1.w};
        float m2[4] = {h2.x * r2.x, h2.y * r2.y, h2.z * r2.z, h2.w * r2.w};
        float m3[4] = {h3.x * r3.x, h3.y * r3.y, h3.z * r3.z, h3.w * r3.w};
        float m4[4] = {h4.x * r4.x, h4.y * r4.y, h4.z * r4.z, h4.w * r4.w};
        float m5[4] = {h5.x * r5.x, h5.y * r5.y, h5.z * r5.z, h5.w * r5.w};
        float m6[4] = {h6.x * r6.x, h6.y * r6.y, h6.z * r6.z, h6.w * r6.w};
        float m7[4] = {h7.x * r7.x, h7.y * r7.y, h7.z * r7.z, h7.w * r7.w};
        #pragma unroll
        for (int c = 0; c < 4; ++c) {
            sv[c] += ((m0[c] + m1[c]) + (m2[c] + m3[c])) +
                     ((m4[c] + m5[c]) + (m6[c] + m7[c]));
            ssv[c] = fmaf(m0[c], m0[c], ssv[c]);
            ssv[c] = fmaf(m1[c], m1[c], ssv[c]);
            ssv[c] = fmaf(m2[c], m2[c], ssv[c]);
            ssv[c] = fmaf(m3[c], m3[c], ssv[c]);
            ssv[c] = fmaf(m4[c], m4[c], ssv[c]);
            ssv[c] = fmaf(m5[c], m5[c], ssv[c]);
            ssv[c] = fmaf(m6[c], m6[c], ssv[c]);
            ssv[c] = fmaf(m7[c], m7[c], ssv[c]);
            mxv[c] = fmaxf(fmaxf(mxv[c], m0[c]), m1[c]);
            mxv[c] = fmaxf(fmaxf(mxv[c], m2[c]), m3[c]);
            mxv[c] = fmaxf(fmaxf(mxv[c], m4[c]), m5[c]);
            mxv[c] = fmaxf(fmaxf(mxv[c], m6[c]), m7[c]);
            mnv[c] = fminf(fminf(mnv[c], m0[c]), m1[c]);
            mnv[c] = fminf(fminf(mnv[c], m2[c]), m3[c]);
            mnv[c] = fminf(fminf(mnv[c], m4[c]), m5[c]);
            mnv[c] = fminf(fminf(mnv[c], m6[c]), m7[c]);
        }
    }
    if (e + 4 <= end) {                          // one 4-edge block
        int4 c01 = *(const int4*)(csr + e);
        int4 c23 = *(const int4*)(csr + e + 2);
        float4 h0 = *(const float4*)(hbB + c01.x), r0 = *(const float4*)(reB + c01.y);
        float4 h1 = *(const float4*)(hbB + c01.z), r1 = *(const float4*)(reB + c01.w);
        float4 h2 = *(const float4*)(hbB + c23.x), r2 = *(const float4*)(reB + c23.y);
        float4 h3 = *(const float4*)(hbB + c23.z), r3 = *(const float4*)(reB + c23.w);
        float m0[4] = {h0.x * r0.x, h0.y * r0.y, h0.z * r0.z, h0.w * r0.w};
        float m1[4] = {h1.x * r1.x, h1.y * r1.y, h1.z * r1.z, h1.w * r1.w};
        float m2[4] = {h2.x * r2.x, h2.y * r2.y, h2.z * r2.z, h2.w * r2.w};
        float m3[4] = {h3.x * r3.x, h3.y * r3.y, h3.z * r3.z, h3.w * r3.w};
        #pragma unroll
        for (int c = 0; c < 4; ++c) {
            sv[c] += (m0[c] + m1[c]) + (m2[c] + m3[c]);
            ssv[c] = fmaf(m0[c], m0[c], ssv[c]);
            ssv[c] = fmaf(m1[c], m1[c], ssv[c]);
            ssv[c] = fmaf(m2[c], m2[c], ssv[c]);
            ssv[c] = fmaf(m3[c], m3[c], ssv[c]);
            mxv[c] = fmaxf(fmaxf(mxv[c], m0[c]), m1[c]);
            mxv[c] = fmaxf(fmaxf(mxv[c], m2[c]), m3[c]);
            mnv[c] = fminf(fminf(mnv[c], m0[c]), m1[c]);
            mnv[c] = fminf(fminf(mnv[c], m2[c]), m3[c]);
        }
        e += 4;
    }
    for (; e < end; ++e) EDGE1(e);
#undef EDGE1

    float degf = (float)(dg + 1);
    float inv = 1.0f / degf;
    float4 h4 = *(const float4*)(hbB + sidx * (ND * 4));
    float hself[4] = {h4.x, h4.y, h4.z, h4.w};

    #pragma unroll
    for (int f = 0; f < 5; ++f) {
        float vals[4];
        #pragma unroll
        for (int c = 0; c < 4; ++c) {
            float v;
            if (f == 0) v = hself[c];
            else if (f == 1) v = sv[c] * inv;
            else if (f == 2) v = mxv[c];
            else if (f == 3) v = mnv[c];
            else {
                float mean = sv[c] * inv;
                v = sqrtf(fmaxf(ssv[c] * inv - mean * mean, 0.f));
            }
            vals[c] = v;
        }
        ushort4 vh, vl;
        bf16split(vals[0], vh.x, vl.x);
        bf16split(vals[1], vh.y, vl.y);
        bf16split(vals[2], vh.z, vl.z);
        bf16split(vals[3], vh.w, vl.w);
        *(ushort4*)&ldsAh[rowl][f * 32 + d0] = vh;
        *(ushort4*)&ldsAl[rowl][f * 32 + d0] = vl;
    }
    __syncthreads();

    // -------- phase 2: MFMA update --------
    int mt = w >> 1, nt = w & 1;
    int am = lane & 15, kg = lane >> 4;
    int arow = mt * 16 + am;
    const bf16x8v* Bh = (const bf16x8v*)(Wph + (size_t)nt * 13 * 64 * 8);
    const bf16x8v* Bl = (const bf16x8v*)(Wpl + (size_t)nt * 13 * 64 * 8);

    f32x4v acc_a = {0.f, 0.f, 0.f, 0.f};
    f32x4v acc2  = {0.f, 0.f, 0.f, 0.f};
    f32x4v acc3  = {0.f, 0.f, 0.f, 0.f};

#define STEP(S, ACC)                                                              \
    {                                                                             \
        bf16x8v bh = Bh[(S) * 64 + lane];                                         \
        bf16x8v bl = Bl[(S) * 64 + lane];                                         \
        ACC = __builtin_amdgcn_mfma_f32_16x16x32_bf16(ah, bh, ACC, 0, 0, 0);      \
        ACC = __builtin_amdgcn_mfma_f32_16x16x32_bf16(ah, bl, ACC, 0, 0, 0);      \
        ACC = __builtin_amdgcn_mfma_f32_16x16x32_bf16(al, bh, ACC, 0, 0, 0);      \
    }
    #pragma unroll
    for (int c = 0; c < 5; ++c) {
        bf16x8v ah = *(const bf16x8v*)&ldsAh[arow][c * 32 + kg * 8];
        bf16x8v al = *(const bf16x8v*)&ldsAl[arow][c * 32 + kg * 8];
        if (c == 0) {
            STEP(0, acc_a)
        } else {
            STEP(c, acc_a)
            STEP(c + 4, acc2)
            STEP(c + 8, acc3)
        }
    }
#undef STEP

    int j = nt * 16 + am;
    float bj = bias[j];
    float fac = (float)NN / *logsum;
    #pragma unroll
    for (int rr = 0; rr < 4; ++rr) {
        int gi = blk * 32 + mt * 16 + 4 * kg + rr;
        if (gi < n) {
            int ix = list[gi];
            int bb = ix / NN;
            int pp = ix - bb * NN;
            float2 sc = pna_scales(begdeg[pp].y, fac);
            float v = acc_a[rr] + sc.x * acc2[rr] + sc.y * acc3[rr] + bj;
            size_t o = (size_t)ix * 32 + j;
            hnew[o] = fmaxf(v, 0.f) + hin[o];
        }
    }
}

// ---------------- final MLP scorer: block per (b,t); uniform fallback via taff ----------------
__global__ __launch_bounds__(64) void score_kernel(
    const float* __restrict__ hidden, const int* __restrict__ t_index,
    const unsigned char* __restrict__ taff,
    const float* __restrict__ b2l,
    const int* __restrict__ r_index, const float* __restrict__ qw,
    const float* __restrict__ w1, const float* __restrict__ b1,
    const float* __restrict__ w2, const float* __restrict__ b2,
    float* __restrict__ out) {
    int i = blockIdx.x;                       // 0..NB*NT-1
    int b = i / NT;
    int j = threadIdx.x;                      // 0..63
    int node = t_index[i];
    __shared__ float feat[2 * ND];
    if (j < ND) {
        feat[j] = taff[i] ? hidden[((size_t)b * NN + node) * ND + j]
                          : fmaxf(b2l[j], 0.f);   // uniform background hidden3
    } else {
        feat[j] = qw[r_index[b] * ND + (j - ND)];
    }
    __syncthreads();
    float a = b1[j];
    #pragma unroll
    for (int kk = 0; kk < 2 * ND; ++kk) a = fmaf(feat[kk], w1[kk * 2 * ND + j], a);
    float v = fmaxf(a, 0.f) * w2[j];
    #pragma unroll
    for (int off = 32; off > 0; off >>= 1) v += __shfl_down(v, off, 64);
    if (j == 0) out[i] = v + b2[0];
}

extern "C" void kernel_launch(void* const* d_in, const int* in_sizes, int n_in,
                              void* d_out, int out_size, void* d_ws, size_t ws_size,
                              hipStream_t stream) {
    (void)in_sizes; (void)n_in; (void)out_size; (void)ws_size;
    const int* edge_index = (const int*)d_in[0];     // [2][E]
    const int* edge_type  = (const int*)d_in[1];     // [E]
    const int* h_index    = (const int*)d_in[2];     // [B]
    const int* r_index    = (const int*)d_in[3];     // [B]
    const int* t_index    = (const int*)d_in[4];     // [B][T]
    const float* query_weight = (const float*)d_in[5];  // [R][D]
    const float* rel_lin_w    = (const float*)d_in[6];  // [L][D][R*D]
    const float* layer_w      = (const float*)d_in[7];  // [L][13D][D]
    const float* layer_b      = (const float*)d_in[8];  // [L][D]
    const float* mlp_w1 = (const float*)d_in[9];
    const float* mlp_b1 = (const float*)d_in[10];
    const float* mlp_w2 = (const float*)d_in[11];
    const float* mlp_b2 = (const float*)d_in[12];
    float* out = (float*)d_out;

    const int* src = edge_index;
    const int* dst = edge_index + NE;

    char* wsp = (char*)d_ws;
    size_t off = 0;
    auto alloc = [&](size_t bytes) -> void* {
        void* p = wsp + off;
        off += (bytes + 255) & ~(size_t)255;
        return p;
    };
    float* hA      = (float*)alloc(sizeof(float) * M_TOT * ND);
    float* hB      = (float*)alloc(sizeof(float) * M_TOT * ND);
    unsigned short* Wph = (unsigned short*)alloc(sizeof(unsigned short) * NL * 2 * 13 * 64 * 8);
    unsigned short* Wpl = (unsigned short*)alloc(sizeof(unsigned short) * NL * 2 * 13 * 64 * 8);
    float* rel     = (float*)alloc(sizeof(float) * NL * NB * NR * ND);
    int2*  csr     = (int2*)alloc(sizeof(int2) * NE);
    int*   offsets = (int*)alloc(sizeof(int) * NN);
    int2*  begdeg  = (int2*)alloc(sizeof(int2) * NN);
    // ---- zeroed region start (contiguous allocs) ----
    int*   indeg   = (int*)alloc(sizeof(int) * NN);
    int*   cursor  = (int*)alloc(sizeof(int) * NN);
    float* logsum  = (float*)alloc(sizeof(float) * 1);
    int*   edgeTotal = (int*)alloc(sizeof(int) * 1);
    int*   affCnt  = (int*)alloc(sizeof(int) * 1);
    int*   cnt2    = (int*)alloc(sizeof(int) * 1);
    int*   cnt3    = (int*)alloc(sizeof(int) * 1);
    int*   f1n     = (int*)alloc(sizeof(int) * NN);
    int*   f2n     = (int*)alloc(sizeof(int) * NN);
    size_t zbytes = (size_t)((char*)(f2n + NN) - (char*)indeg);
    // ---- zeroed region end ----
    int*   zb      = (int*)alloc(sizeof(int) * 2);
    int4*  affList = (int4*)alloc(sizeof(int4) * AFF_CAP);
    int*   list2   = (int*)alloc(sizeof(int) * M_TOT);
    int*   list3   = (int*)alloc(sizeof(int) * M_TOT);
    unsigned char* taff = (unsigned char*)alloc(NB * NT);

    hipMemsetAsync(indeg, 0, zbytes, stream);

    count_kernel<<<(NE + 255) / 256, 256, 0, stream>>>(src, dst, h_index, layer_b,
                                                       indeg, f1n, zb);
    nodeprep_kernel<<<(NN + 255) / 256, 256, 0, stream>>>(indeg, offsets, begdeg,
                                                          logsum, edgeTotal);
    scatter_kernel<<<SCAT_BLKS + 1, 256, 0, stream>>>(src, dst, edge_type, offsets,
                                                      cursor, csr, h_index,
                                                      f1n, f2n, affCnt, affList);
    relwpack_kernel<<<REL_BLOCKS + (NL * 2 * 13 * 64 + 255) / 256, 256, 0, stream>>>(
        query_weight, r_index, rel_lin_w, rel, layer_w, Wph, Wpl);

    // layer 0: fills + sparse fixup, one kernel (write-disjoint via f1 skip)
    bigfill_kernel<<<2 * FILLB + AFF_CAP, 256, 0, stream>>>(
        hA, hB, rel, layer_w, layer_b, begdeg, f1n,
        h_index, r_index, query_weight, logsum, affCnt, affList);

    // compact2 + taffect fused
    c2taff_kernel<<<C2B + (NB * NT + 3) / 4, 256, 0, stream>>>(
        f1n, f2n, zb, cnt2, list2, t_index, begdeg, csr, taff);

    // layer 1 over frontier2
    list_layer_kernel<<<M_TOT / 32, 256, 0, stream>>>(
        hA, hB, rel + (size_t)1 * NB * NR * ND,
        Wph + (size_t)1 * 2 * 13 * 64 * 8, Wpl + (size_t)1 * 2 * 13 * 64 * 8,
        layer_b + ND, logsum, begdeg, csr, h_index, r_index, query_weight, cnt2, list2);

    // layer 2 backward-sliced to flagged t rows
    compact3_kernel<<<(M_TOT + 255) / 256, 256, 0, stream>>>(t_index, taff, zb,
                                                             cnt3, list3);
    list_layer_kernel<<<M_TOT / 32, 256, 0, stream>>>(
        hB, hA, rel + (size_t)2 * NB * NR * ND,
        Wph + (size_t)2 * 2 * 13 * 64 * 8, Wpl + (size_t)2 * 2 * 13 * 64 * 8,
        layer_b + 2 * ND, logsum, begdeg, csr, h_index, r_index, query_weight,
        cnt3, list3);

    score_kernel<<<NB * NT, 64, 0, stream>>>(hA, t_index, taff, layer_b + 2 * ND,
                                             r_index, query_weight,
                                             mlp_w1, mlp_b1, mlp_w2, mlp_b2, out);
}

// Round 23
// 127.454 us; speedup vs baseline: 1.7518x; 1.1527x over previous
//
#include <hip/hip_runtime.h>
#include <math.h>

#define NN 20000   // nodes
#define NE 480000  // edges
#define NB 4       // batch
#define ND 32      // dim
#define NR 474     // relations
#define NL 3       // layers
#define NT 64      // tails
#define M_TOT (NB * NN)   // 80000 node-rows
#define LROW 168          // padded LDS row (bf16 units)
#define AFF_CAP 1024      // layer-0 affected entries (~100)
#define FILLB (M_TOT * 8 / 256)   // 2500 fill blocks per buffer

typedef __attribute__((ext_vector_type(8))) short bf16x8v;
typedef __attribute__((ext_vector_type(4))) float f32x4v;

// RNE split of f32 into bf16 hi + bf16 lo (a ~= hi + lo, err ~2^-18 rel)
__device__ inline void bf16split(float a, unsigned short& h, unsigned short& l) {
    unsigned u = __float_as_uint(a);
    unsigned r = u + 0x7FFFu + ((u >> 16) & 1u);
    h = (unsigned short)(r >> 16);
    float fh = __uint_as_float((unsigned)h << 16);
    float res = a - fh;
    unsigned v = __float_as_uint(res);
    unsigned r2 = v + 0x7FFFu + ((v >> 16) & 1u);
    l = (unsigned short)(r2 >> 16);
}

// inline PNA scales from degree: scl = log(dg+2) * NN/logsum
__device__ inline float2 pna_scales(int dg, float fac) {
    float scl = logf((float)(dg + 2)) * fac;
    return make_float2(scl, 1.0f / fmaxf(scl, 1e-2f));
}

// ---------------- prep: CSR count + f1n + zb  |  rel embeddings + W pack ----------------
#define CNT_B (NE / 256)                        // 1875 exact
#define REL_T (NL * NR * ND)                    // 45504
#define REL_BLOCKS ((REL_T + 255) / 256)        // 178
#define WP_T (NL * 2 * 13 * 64)                 // 4992
#define WP_B ((WP_T + 255) / 256)               // 20
__global__ __launch_bounds__(256) void prep_kernel(
    const int* __restrict__ src, const int* __restrict__ dst,
    const int* __restrict__ h_index, const float* __restrict__ layer_b,
    int* __restrict__ indeg, int* __restrict__ f1n, int* __restrict__ zb,
    const float* __restrict__ qw, const int* __restrict__ r_index,
    const float* __restrict__ rlw, float* __restrict__ rel,
    const float* __restrict__ W, unsigned short* __restrict__ Wph,
    unsigned short* __restrict__ Wpl) {
    int blk = blockIdx.x;
    if (blk < CNT_B) {
        int e = blk * 256 + threadIdx.x;
        if (e == 0) {                             // zero-background gate flags
            int a = 1, b = 1;
            for (int j = 0; j < ND; ++j) {
                if (layer_b[j] > 0.f) a = 0;
                if (layer_b[ND + j] > 0.f) b = 0;
            }
            zb[0] = a;            // background of hidden1 is zero
            zb[1] = a && b;       // background of hidden2 is zero
        }
        if (e < NB) atomicOr(&f1n[h_index[e]], 1 << e);   // head rows
        int dn = dst[e];
        atomicAdd(&indeg[dn], 1);
        int sn = src[e];
        #pragma unroll
        for (int b = 0; b < NB; ++b)
            if (sn == h_index[b]) atomicOr(&f1n[dn], 1 << b);
        return;
    }
    if (blk < CNT_B + REL_BLOCKS) {
        int i = (blk - CNT_B) * 256 + threadIdx.x;
        if (i >= REL_T) return;
        int d = i & (ND - 1);
        int rd = i >> 5;
        int r = rd % NR;
        int l = rd / NR;
        const float* q0 = qw + r_index[0] * ND;
        const float* q1 = qw + r_index[1] * ND;
        const float* q2 = qw + r_index[2] * ND;
        const float* q3 = qw + r_index[3] * ND;
        const float* w = rlw + (size_t)l * ND * NR * ND + (size_t)r * ND + d;
        float a0 = 0.f, a1 = 0.f, a2 = 0.f, a3 = 0.f;
        #pragma unroll
        for (int k = 0; k < ND; ++k) {
            float wk = w[(size_t)k * NR * ND];
            a0 = fmaf(q0[k], wk, a0); a1 = fmaf(q1[k], wk, a1);
            a2 = fmaf(q2[k], wk, a2); a3 = fmaf(q3[k], wk, a3);
        }
        size_t o = ((size_t)l * NB * NR + r) * ND + d;
        rel[o] = a0;
        rel[o + (size_t)NR * ND] = a1;
        rel[o + (size_t)2 * NR * ND] = a2;
        rel[o + (size_t)3 * NR * ND] = a3;
        return;
    }
    int t = (blk - CNT_B - REL_BLOCKS) * 256 + threadIdx.x;
    if (t >= WP_T) return;
    int lane = t & 63;
    int u = t >> 6;
    int s = u % 13;
    int nt = (u / 13) % 2;
    int l = u / 26;
    int n = nt * 16 + (lane & 15);
    int k0 = s * 32 + (lane >> 4) * 8;
    size_t ob = (size_t)t * 8;
    #pragma unroll
    for (int e = 0; e < 8; ++e) {
        float w = W[(size_t)l * 416 * 32 + (size_t)(k0 + e) * 32 + n];
        unsigned short h8, l8;
        bf16split(w, h8, l8);
        Wph[ob + e] = h8;
        Wpl[ob + e] = l8;
    }
}

// offsets via wave-scan + ONE atomic/wave slab alloc; log-degree sum; begdeg
__global__ __launch_bounds__(256) void nodeprep_kernel(
    const int* __restrict__ indeg, int* __restrict__ offsets,
    int2* __restrict__ begdeg,
    float* __restrict__ logsum, int* __restrict__ edgeTotal) {
    int t = threadIdx.x;
    int n = blockIdx.x * 256 + t;
    int lane = t & 63;
    int dg = (n < NN) ? indeg[n] : 0;
    float v = (n < NN) ? logf((float)(dg + 2)) : 0.f;   // log(deg+1), deg = indeg+1

    int inc = dg;
    #pragma unroll
    for (int o = 1; o < 64; o <<= 1) {
        int u = __shfl_up(inc, o, 64);
        if (lane >= o) inc += u;
    }
    int waveTot = __shfl(inc, 63, 64);
    int base = 0;
    if (lane == 63) base = atomicAdd(edgeTotal, waveTot);   // 1 atomic per wave
    base = __shfl(base, 63, 64);
    if (n < NN) {
        int o = base + inc - dg;
        offsets[n] = o;
        begdeg[n] = make_int2(o, dg);
    }
    #pragma unroll
    for (int o = 32; o > 0; o >>= 1) v += __shfl_down(v, o, 64);
    if (lane == 0) atomicAdd(logsum, v);
}

// csr scatter (csr.x = src*128 byte off) + f2n propagation + affList (+ head rows)
#define SCAT_BLKS (NE / 256)   // 1875 exact
__global__ __launch_bounds__(256) void scatter_kernel(const int* __restrict__ src,
                                                      const int* __restrict__ dst,
                                                      const int* __restrict__ etype,
                                                      const int* __restrict__ offsets,
                                                      int* __restrict__ cursor,
                                                      int2* __restrict__ csr,
                                                      const int* __restrict__ h_index,
                                                      const int* __restrict__ f1n,
                                                      int* __restrict__ f2n,
                                                      int* __restrict__ affCnt,
                                                      int4* __restrict__ affList) {
    if (blockIdx.x == SCAT_BLKS) {               // head-row affList entries
        int b = threadIdx.x;
        if (b < NB) {
            int p = atomicAdd(affCnt, 1);
            if (p < AFF_CAP) affList[p] = make_int4(b, h_index[b], -1, 0);
        }
        return;
    }
    int e = blockIdx.x * 256 + threadIdx.x;
    int dn = dst[e];
    int sn = src[e];
    int pos = atomicAdd(&cursor[dn], 1);
    csr[offsets[dn] + pos] = make_int2(sn * (ND * 4), etype[e] * (ND * 4));
    int v = f1n[sn];
    if (v) atomicOr(&f2n[dn], v);                // frontier2 = neighbors of frontier1
    #pragma unroll
    for (int b = 0; b < NB; ++b) {
        if (sn == h_index[b]) {
            int p = atomicAdd(affCnt, 1);
            if (p < AFF_CAP) affList[p] = make_int4(b, dn, etype[e], 0);
        }
    }
}

// ---------------- mega: fill hA | fill hB | fixup | compact2(+list3 dense) | taffect(+list3) ----------------
#define C2B ((M_TOT + 255) / 256)   // 313
#define TAFF_B ((NB * NT + 3) / 4)  // 64
__global__ __launch_bounds__(256) void mega_kernel(
    float* __restrict__ hA, float* __restrict__ hB,
    const float* __restrict__ rel0, const float* __restrict__ W0,
    const float* __restrict__ layer_b,
    const int2* __restrict__ begdeg, const int* __restrict__ f1n,
    const int* __restrict__ f2n, const int* __restrict__ zb,
    const int* __restrict__ h_index, const int* __restrict__ r_index,
    const float* __restrict__ qw, const float* __restrict__ logsum,
    const int* __restrict__ affCnt, const int4* __restrict__ affList,
    int* __restrict__ cnt2, int* __restrict__ list2,
    int* __restrict__ cnt3, int* __restrict__ list3,
    const int* __restrict__ t_index, const int2* __restrict__ csr,
    unsigned char* __restrict__ taff) {
    int blk = blockIdx.x;
    if (blk < 2 * FILLB) {                       // fills
        bool isA = blk < FILLB;
        const float* bias = isA ? layer_b : layer_b + ND;
        float* dst = isA ? hA : hB;
        __shared__ float rb[ND];
        if (threadIdx.x < ND) rb[threadIdx.x] = fmaxf(bias[threadIdx.x], 0.f);
        __syncthreads();
        int i = (isA ? blk : blk - FILLB) * 256 + threadIdx.x;   // float4 slot
        if (i >= M_TOT * 8) return;
        if (isA) {
            int row = i >> 3;
            int b = row / NN, node = row - b * NN;
            if ((f1n[node] >> b) & 1) return;    // fixup owns this row
        }
        int q = (i & 7) * 4;
        ((float4*)dst)[i] = make_float4(rb[q], rb[q + 1], rb[q + 2], rb[q + 3]);
        return;
    }
    if (blk < 2 * FILLB + AFF_CAP) {
        // ---- fixup part (messages = q (x) rel0[et] only; hidden0 = boundary) ----
        __shared__ float F[5][ND];
        __shared__ int4 ent[AFF_CAP];
        int cnt = *affCnt;
        if (cnt > AFF_CAP) cnt = AFF_CAP;
        int fb = blk - 2 * FILLB;
        int t = threadIdx.x;
        for (int i = t; i < cnt; i += 256) ent[i] = affList[i];
        __syncthreads();
        if (fb >= cnt) return;

        int4 me = ent[fb];
        int b = me.x, row = me.y;
        for (int i = 0; i < fb; ++i) {           // dedupe (block-uniform)
            int4 o = ent[i];
            if (o.x == b && o.y == row) return;
        }
        int hn = h_index[b];
        const float* q = qw + r_index[b] * ND;
        int deg = begdeg[row].y;

        if (t < ND) {
            int j = t;
            float qj = q[j];
            int nhead = 0;
            float s = 0.f, ss = 0.f, mx = -INFINITY, mn = INFINITY;
            for (int i = 0; i < cnt; ++i) {
                int4 o = ent[i];
                if (o.x == b && o.y == row && o.z >= 0) {
                    float m = qj * rel0[((size_t)b * NR + o.z) * ND + j];
                    s += m; ss = fmaf(m, m, ss);
                    mx = fmaxf(mx, m); mn = fminf(mn, m);
                    ++nhead;
                }
            }
            float bm = (row == hn) ? qj : 0.f;
            s += bm; ss = fmaf(bm, bm, ss);
            mx = fmaxf(mx, bm); mn = fminf(mn, bm);
            if (deg - nhead > 0) { mx = fmaxf(mx, 0.f); mn = fminf(mn, 0.f); }
            float inv = 1.0f / (float)(deg + 1);
            float mean = s * inv;
            F[0][j] = bm;
            F[1][j] = mean;
            F[2][j] = mx;
            F[3][j] = mn;
            F[4][j] = sqrtf(fmaxf(ss * inv - mean * mean, 0.f));
        }
        __syncthreads();
        if (t >= 64) return;                      // wave 0 does the GEMV

        int j = t & 31, kh = t >> 5;
        float2 sc = pna_scales(deg, (float)NN / *logsum);
        float acc = (kh == 0) ? layer_b[j] : 0.f;
        #pragma unroll
        for (int kk = 0; kk < 16; ++kk) {
            int k = kh * 16 + kk;
            acc = fmaf(F[0][k], W0[k * 32 + j], acc);
        }
        #pragma unroll
        for (int f = 1; f < 5; ++f) {
            #pragma unroll
            for (int kk = 0; kk < 16; ++kk) {
                int k = kh * 16 + kk;
                float a = F[f][k];
                int r0 = (f - 1) * 32 + 32 + k;
                acc = fmaf(a, W0[r0 * 32 + j], acc);
                acc = fmaf(a * sc.x, W0[(r0 + 128) * 32 + j], acc);
                acc = fmaf(a * sc.y, W0[(r0 + 256) * 32 + j], acc);
            }
        }
        acc += __shfl_down(acc, 32, 64);
        if (t < ND) {
            size_t o = ((size_t)b * NN + row) * ND + j;
            hA[o] = fmaxf(acc, 0.f) + F[0][j];
        }
        return;
    }
    if (blk < 2 * FILLB + AFF_CAP + C2B) {
        // ---- compact2 (list2) + dense-fallback list3 ----
        int i = (blk - 2 * FILLB - AFF_CAP) * 256 + threadIdx.x;
        int lane = threadIdx.x & 63;
        bool in = i < M_TOT;
        bool take = false;
        if (in) {
            int b = i / NN;
            int node = i - b * NN;
            int m = f1n[node] | f2n[node];
            take = (!zb[0]) || ((m >> b) & 1);
        }
        unsigned long long msk = __ballot(take);
        int nw = __popcll(msk);
        int base = 0;
        if (lane == 0 && nw) base = atomicAdd(cnt2, nw);
        base = __shfl(base, 0, 64);
        if (take) list2[base + __popcll(msk & ((1ULL << lane) - 1))] = i;
        // dense fallback: list3 = all rows
        bool take3 = in && !zb[1];
        unsigned long long m3 = __ballot(take3);
        int nw3 = __popcll(m3);
        int b3 = 0;
        if (lane == 0 && nw3) b3 = atomicAdd(cnt3, nw3);
        b3 = __shfl(b3, 0, 64);
        if (take3) list3[b3 + __popcll(m3 & ((1ULL << lane) - 1))] = i;
        return;
    }
    // ---- taffect: entry per wave; appends flagged t rows to list3 (zb[1] path) ----
    int i = (blk - 2 * FILLB - AFF_CAP - C2B) * 4 + (threadIdx.x >> 6);
    if (i >= NB * NT) return;
    int b = i / NT;
    int lane = threadIdx.x & 63;
    int node = t_index[i];
    int aff = ((f1n[node] | f2n[node]) >> b) & 1;
    int2 bd = begdeg[node];
    int a = 0;
    for (int e = bd.x + lane; e < bd.x + bd.y; e += 64) {
        int sn = csr[e].x >> 7;               // src node (byte off / 128)
        a |= ((f1n[sn] | f2n[sn]) >> b) & 1;
    }
    aff |= (__ballot(a) != 0ULL);
    if (!zb[1]) aff = 1;                      // dense fallback: everything computed
    if (lane == 0) {
        taff[i] = (unsigned char)aff;
        if (aff && zb[1]) {
            int p = atomicAdd(cnt3, 1);
            list3[p] = b * NN + node;
        }
    }
}

// ---------------- list-driven fused layer (rows from work list) ----------------
__global__ __launch_bounds__(256, 4) void list_layer_kernel(
    const float* __restrict__ hin, float* __restrict__ hnew,
    const float* __restrict__ rel,               // [B][R][D] this layer
    const unsigned short* __restrict__ Wph, const unsigned short* __restrict__ Wpl,
    const float* __restrict__ bias, const float* __restrict__ logsum,
    const int2* __restrict__ begdeg, const int2* __restrict__ csr,
    const int* __restrict__ h_index, const int* __restrict__ r_index,
    const float* __restrict__ qw,
    const int* __restrict__ cnt, const int* __restrict__ list) {
    __shared__ __align__(16) unsigned short ldsAh[32][LROW];
    __shared__ __align__(16) unsigned short ldsAl[32][LROW];

    int n = *cnt;
    int blk = blockIdx.x;
    if (blk * 32 >= n) return;                   // block-uniform early exit

    int tid = threadIdx.x;
    int lane = tid & 63;
    int w = tid >> 6;                            // 0..3
    int r8 = lane >> 3;
    int d0 = (lane & 7) * 4;                     // dim quartet
    int d4 = d0 * 4;                             // byte offset
    int rowl = w * 8 + r8;                       // 0..31
    int li = blk * 32 + rowl;
    bool act = li < n;
    int idx = act ? list[li] : list[0];          // dummy -> valid row 0
    int b = idx / NN;
    int sidx = idx - b * NN;                     // node (identity order)
    const char* hbB = (const char*)hin + (size_t)b * (NN * ND * 4) + d4;
    const char* reB = (const char*)rel + (size_t)b * (NR * ND * 4) + d4;

    float sv[4], ssv[4], mxv[4], mnv[4];
    {
        float4 bm4 = make_float4(0.f, 0.f, 0.f, 0.f);
        if (sidx == h_index[b]) bm4 = *(const float4*)(qw + r_index[b] * ND + d0);
        float bm[4] = {bm4.x, bm4.y, bm4.z, bm4.w};
        #pragma unroll
        for (int c = 0; c < 4; ++c) {
            sv[c] = bm[c]; ssv[c] = bm[c] * bm[c]; mxv[c] = bm[c]; mnv[c] = bm[c];
        }
    }

    int2 bd = begdeg[sidx];
    int beg = bd.x, dg = bd.y, end = beg + dg;
#define EDGE1(E)                                                                  \
    {                                                                             \
        int2 a0 = csr[E];                                                         \
        float4 h0 = *(const float4*)(hbB + a0.x);                                 \
        float4 r0 = *(const float4*)(reB + a0.y);                                 \
        float m0[4] = {h0.x * r0.x, h0.y * r0.y, h0.z * r0.z, h0.w * r0.w};       \
        _Pragma("unroll")                                                         \
        for (int c = 0; c < 4; ++c) {                                             \
            sv[c] += m0[c];                                                       \
            ssv[c] = fmaf(m0[c], m0[c], ssv[c]);                                  \
            mxv[c] = fmaxf(mxv[c], m0[c]);                                        \
            mnv[c] = fminf(mnv[c], m0[c]);                                        \
        }                                                                         \
    }
    int e = beg;
    if ((e & 1) && e < end) { EDGE1(e); ++e; }   // align to 16B for int4 loads
    int n8 = (end - e) >> 3;                     // 8-edge chunks
    const int4* cp = (const int4*)(csr + e);
    e += n8 * 8;
    int4 k0, k1, k2, k3;
    if (n8 > 0) { k0 = cp[0]; k1 = cp[1]; k2 = cp[2]; k3 = cp[3]; }
    for (int i = 0; i < n8; ++i) {
        float4 h0 = *(const float4*)(hbB + k0.x), r0 = *(const float4*)(reB + k0.y);
        float4 h1 = *(const float4*)(hbB + k0.z), r1 = *(const float4*)(reB + k0.w);
        float4 h2 = *(const float4*)(hbB + k1.x), r2 = *(const float4*)(reB + k1.y);
        float4 h3 = *(const float4*)(hbB + k1.z), r3 = *(const float4*)(reB + k1.w);
        float4 h4 = *(const float4*)(hbB + k2.x), r4 = *(const float4*)(reB + k2.y);
        float4 h5 = *(const float4*)(hbB + k2.z), r5 = *(const float4*)(reB + k2.w);
        float4 h6 = *(const float4*)(hbB + k3.x), r6 = *(const float4*)(reB + k3.y);
        float4 h7 = *(const float4*)(hbB + k3.z), r7 = *(const float4*)(reB + k3.w);
        cp += 4;
        if (i + 1 < n8) { k0 = cp[0]; k1 = cp[1]; k2 = cp[2]; k3 = cp[3]; }
        float m0[4] = {h0.x * r0.x, h0.y * r0.y, h0.z * r0.z, h0.w * r0.w};
        float m1[4] = {h1.x * r1.x, h1.y * r1.y, h1.z * r1.z, h1.w * r1.w};
        float m2[4] = {h2.x * r2.x, h2.y * r2.y, h2.z * r2.z, h2.w * r2.w};
        float m3[4] = {h3.x * r3.x, h3.y * r3.y, h3.z * r3.z, h3.w * r3.w};
        float m4[4] = {h4.x * r4.x, h4.y * r4.y, h4.z * r4.z, h4.w * r4.w};
        float m5[4] = {h5.x * r5.x, h5.y * r5.y, h5.z * r5.z, h5.w * r5.w};
        float m6[4] = {h6.x * r6.x, h6.y * r6.y, h6.z * r6.z, h6.w * r6.w};
        float m7[4] = {h7.x * r7.x, h7.y * r7.y, h7.z * r7.z, h7.w * r7.w};
        #pragma unroll
        for (int c = 0; c < 4; ++c) {
            sv[c] += ((m0[c] + m1[c]) + (m2[c] + m3[c])) +
                     ((m4[c] + m5[c]) + (m6[c] + m7[c]));
            ssv[c] = fmaf(m0[c], m0[c], ssv[c]);
            ssv[c] = fmaf(m1[c], m1[c], ssv[c]);
            ssv[c] = fmaf(m2[c], m2[c], ssv[c]);
            ssv[c] = fmaf(m3[c], m3[c], ssv[c]);
            ssv[c] = fmaf(m4[c], m4[c], ssv[c]);
            ssv[c] = fmaf(m5[c], m5[c], ssv[c]);
            ssv[c] = fmaf(m6[c], m6[c], ssv[c]);
            ssv[c] = fmaf(m7[c], m7[c], ssv[c]);
            mxv[c] = fmaxf(fmaxf(mxv[c], m0[c]), m1[c]);
            mxv[c] = fmaxf(fmaxf(mxv[c], m2[c]), m3[c]);
            mxv[c] = fmaxf(fmaxf(mxv[c], m4[c]), m5[c]);
            mxv[c] = fmaxf(fmaxf(mxv[c], m6[c]), m7[c]);
            mnv[c] = fminf(fminf(mnv[c], m0[c]), m1[c]);
            mnv[c] = fminf(fminf(mnv[c], m2[c]), m3[c]);
            mnv[c] = fminf(fminf(mnv[c], m4[c]), m5[c]);
            mnv[c] = fminf(fminf(mnv[c], m6[c]), m7[c]);
        }
    }
    if (e + 4 <= end) {                          // one 4-edge block
        int4 c01 = *(const int4*)(csr + e);
        int4 c23 = *(const int4*)(csr + e + 2);
        float4 h0 = *(const float4*)(hbB + c01.x), r0 = *(const float4*)(reB + c01.y);
        float4 h1 = *(const float4*)(hbB + c01.z), r1 = *(const float4*)(reB + c01.w);
        float4 h2 = *(const float4*)(hbB + c23.x), r2 = *(const float4*)(reB + c23.y);
        float4 h3 = *(const float4*)(hbB + c23.z), r3 = *(const float4*)(reB + c23.w);
        float m0[4] = {h0.x * r0.x, h0.y * r0.y, h0.z * r0.z, h0.w * r0.w};
        float m1[4] = {h1.x * r1.x, h1.y * r1.y, h1.z * r1.z, h1.w * r1.w};
        float m2[4] = {h2.x * r2.x, h2.y * r2.y, h2.z * r2.z, h2.w * r2.w};
        float m3[4] = {h3.x * r3.x, h3.y * r3.y, h3.z * r3.z, h3.w * r3.w};
        #pragma unroll
        for (int c = 0; c < 4; ++c) {
            sv[c] += (m0[c] + m1[c]) + (m2[c] + m3[c]);
            ssv[c] = fmaf(m0[c], m0[c], ssv[c]);
            ssv[c] = fmaf(m1[c], m1[c], ssv[c]);
            ssv[c] = fmaf(m2[c], m2[c], ssv[c]);
            ssv[c] = fmaf(m3[c], m3[c], ssv[c]);
            mxv[c] = fmaxf(fmaxf(mxv[c], m0[c]), m1[c]);
            mxv[c] = fmaxf(fmaxf(mxv[c], m2[c]), m3[c]);
            mnv[c] = fminf(fminf(mnv[c], m0[c]), m1[c]);
            mnv[c] = fminf(fminf(mnv[c], m2[c]), m3[c]);
        }
        e += 4;
    }
    for (; e < end; ++e) EDGE1(e);
#undef EDGE1

    float degf = (float)(dg + 1);
    float inv = 1.0f / degf;
    float4 h4 = *(const float4*)(hbB + sidx * (ND * 4));
    float hself[4] = {h4.x, h4.y, h4.z, h4.w};

    #pragma unroll
    for (int f = 0; f < 5; ++f) {
        float vals[4];
        #pragma unroll
        for (int c = 0; c < 4; ++c) {
            float v;
            if (f == 0) v = hself[c];
            else if (f == 1) v = sv[c] * inv;
            else if (f == 2) v = mxv[c];
            else if (f == 3) v = mnv[c];
            else {
                float mean = sv[c] * inv;
                v = sqrtf(fmaxf(ssv[c] * inv - mean * mean, 0.f));
            }
            vals[c] = v;
        }
        ushort4 vh, vl;
        bf16split(vals[0], vh.x, vl.x);
        bf16split(vals[1], vh.y, vl.y);
        bf16split(vals[2], vh.z, vl.z);
        bf16split(vals[3], vh.w, vl.w);
        *(ushort4*)&ldsAh[rowl][f * 32 + d0] = vh;
        *(ushort4*)&ldsAl[rowl][f * 32 + d0] = vl;
    }
    __syncthreads();

    // -------- phase 2: MFMA update --------
    int mt = w >> 1, nt = w & 1;
    int am = lane & 15, kg = lane >> 4;
    int arow = mt * 16 + am;
    const bf16x8v* Bh = (const bf16x8v*)(Wph + (size_t)nt * 13 * 64 * 8);
    const bf16x8v* Bl = (const bf16x8v*)(Wpl + (size_t)nt * 13 * 64 * 8);

    f32x4v acc_a = {0.f, 0.f, 0.f, 0.f};
    f32x4v acc2  = {0.f, 0.f, 0.f, 0.f};
    f32x4v acc3  = {0.f, 0.f, 0.f, 0.f};

#define STEP(S, ACC)                                                              \
    {                                                                             \
        bf16x8v bh = Bh[(S) * 64 + lane];                                         \
        bf16x8v bl = Bl[(S) * 64 + lane];                                         \
        ACC = __builtin_amdgcn_mfma_f32_16x16x32_bf16(ah, bh, ACC, 0, 0, 0);      \
        ACC = __builtin_amdgcn_mfma_f32_16x16x32_bf16(ah, bl, ACC, 0, 0, 0);      \
        ACC = __builtin_amdgcn_mfma_f32_16x16x32_bf16(al, bh, ACC, 0, 0, 0);      \
    }
    #pragma unroll
    for (int c = 0; c < 5; ++c) {
        bf16x8v ah = *(const bf16x8v*)&ldsAh[arow][c * 32 + kg * 8];
        bf16x8v al = *(const bf16x8v*)&ldsAl[arow][c * 32 + kg * 8];
        if (c == 0) {
            STEP(0, acc_a)
        } else {
            STEP(c, acc_a)
            STEP(c + 4, acc2)
            STEP(c + 8, acc3)
        }
    }
#undef STEP

    int j = nt * 16 + am;
    float bj = bias[j];
    float fac = (float)NN / *logsum;
    #pragma unroll
    for (int rr = 0; rr < 4; ++rr) {
        int gi = blk * 32 + mt * 16 + 4 * kg + rr;
        if (gi < n) {
            int ix = list[gi];
            int bb = ix / NN;
            int pp = ix - bb * NN;
            float2 sc = pna_scales(begdeg[pp].y, fac);
            float v = acc_a[rr] + sc.x * acc2[rr] + sc.y * acc3[rr] + bj;
            size_t o = (size_t)ix * 32 + j;
            hnew[o] = fmaxf(v, 0.f) + hin[o];
        }
    }
}

// ---------------- final MLP scorer: block per (b,t); uniform fallback via taff ----------------
__global__ __launch_bounds__(64) void score_kernel(
    const float* __restrict__ hidden, const int* __restrict__ t_index,
    const unsigned char* __restrict__ taff,
    const float* __restrict__ b2l,
    const int* __restrict__ r_index, const float* __restrict__ qw,
    const float* __restrict__ w1, const float* __restrict__ b1,
    const float* __restrict__ w2, const float* __restrict__ b2,
    float* __restrict__ out) {
    int i = blockIdx.x;                       // 0..NB*NT-1
    int b = i / NT;
    int j = threadIdx.x;                      // 0..63
    int node = t_index[i];
    __shared__ float feat[2 * ND];
    if (j < ND) {
        feat[j] = taff[i] ? hidden[((size_t)b * NN + node) * ND + j]
                          : fmaxf(b2l[j], 0.f);   // uniform background hidden3
    } else {
        feat[j] = qw[r_index[b] * ND + (j - ND)];
    }
    __syncthreads();
    float a = b1[j];
    #pragma unroll
    for (int kk = 0; kk < 2 * ND; ++kk) a = fmaf(feat[kk], w1[kk * 2 * ND + j], a);
    float v = fmaxf(a, 0.f) * w2[j];
    #pragma unroll
    for (int off = 32; off > 0; off >>= 1) v += __shfl_down(v, off, 64);
    if (j == 0) out[i] = v + b2[0];
}

extern "C" void kernel_launch(void* const* d_in, const int* in_sizes, int n_in,
                              void* d_out, int out_size, void* d_ws, size_t ws_size,
                              hipStream_t stream) {
    (void)in_sizes; (void)n_in; (void)out_size; (void)ws_size;
    const int* edge_index = (const int*)d_in[0];     // [2][E]
    const int* edge_type  = (const int*)d_in[1];     // [E]
    const int* h_index    = (const int*)d_in[2];     // [B]
    const int* r_index    = (const int*)d_in[3];     // [B]
    const int* t_index    = (const int*)d_in[4];     // [B][T]
    const float* query_weight = (const float*)d_in[5];  // [R][D]
    const float* rel_lin_w    = (const float*)d_in[6];  // [L][D][R*D]
    const float* layer_w      = (const float*)d_in[7];  // [L][13D][D]
    const float* layer_b      = (const float*)d_in[8];  // [L][D]
    const float* mlp_w1 = (const float*)d_in[9];
    const float* mlp_b1 = (const float*)d_in[10];
    const float* mlp_w2 = (const float*)d_in[11];
    const float* mlp_b2 = (const float*)d_in[12];
    float* out = (float*)d_out;

    const int* src = edge_index;
    const int* dst = edge_index + NE;

    char* wsp = (char*)d_ws;
    size_t off = 0;
    auto alloc = [&](size_t bytes) -> void* {
        void* p = wsp + off;
        off += (bytes + 255) & ~(size_t)255;
        return p;
    };
    float* hA      = (float*)alloc(sizeof(float) * M_TOT * ND);
    float* hB      = (float*)alloc(sizeof(float) * M_TOT * ND);
    unsigned short* Wph = (unsigned short*)alloc(sizeof(unsigned short) * NL * 2 * 13 * 64 * 8);
    unsigned short* Wpl = (unsigned short*)alloc(sizeof(unsigned short) * NL * 2 * 13 * 64 * 8);
    float* rel     = (float*)alloc(sizeof(float) * NL * NB * NR * ND);
    int2*  csr     = (int2*)alloc(sizeof(int2) * NE);
    int*   offsets = (int*)alloc(sizeof(int) * NN);
    int2*  begdeg  = (int2*)alloc(sizeof(int2) * NN);
    // ---- zeroed region start (contiguous allocs) ----
    int*   indeg   = (int*)alloc(sizeof(int) * NN);
    int*   cursor  = (int*)alloc(sizeof(int) * NN);
    float* logsum  = (float*)alloc(sizeof(float) * 1);
    int*   edgeTotal = (int*)alloc(sizeof(int) * 1);
    int*   affCnt  = (int*)alloc(sizeof(int) * 1);
    int*   cnt2    = (int*)alloc(sizeof(int) * 1);
    int*   cnt3    = (int*)alloc(sizeof(int) * 1);
    int*   f1n     = (int*)alloc(sizeof(int) * NN);
    int*   f2n     = (int*)alloc(sizeof(int) * NN);
    size_t zbytes = (size_t)((char*)(f2n + NN) - (char*)indeg);
    // ---- zeroed region end ----
    int*   zb      = (int*)alloc(sizeof(int) * 2);
    int4*  affList = (int4*)alloc(sizeof(int4) * AFF_CAP);
    int*   list2   = (int*)alloc(sizeof(int) * M_TOT);
    int*   list3   = (int*)alloc(sizeof(int) * M_TOT);
    unsigned char* taff = (unsigned char*)alloc(NB * NT);

    hipMemsetAsync(indeg, 0, zbytes, stream);

    prep_kernel<<<CNT_B + REL_BLOCKS + WP_B, 256, 0, stream>>>(
        src, dst, h_index, layer_b, indeg, f1n, zb,
        query_weight, r_index, rel_lin_w, rel, layer_w, Wph, Wpl);
    nodeprep_kernel<<<(NN + 255) / 256, 256, 0, stream>>>(indeg, offsets, begdeg,
                                                          logsum, edgeTotal);
    scatter_kernel<<<SCAT_BLKS + 1, 256, 0, stream>>>(src, dst, edge_type, offsets,
                                                      cursor, csr, h_index,
                                                      f1n, f2n, affCnt, affList);
    // fills + fixup + compact2 + taffect(+list3), one kernel
    mega_kernel<<<2 * FILLB + AFF_CAP + C2B + TAFF_B, 256, 0, stream>>>(
        hA, hB, rel, layer_w, layer_b, begdeg, f1n, f2n, zb,
        h_index, r_index, query_weight, logsum, affCnt, affList,
        cnt2, list2, cnt3, list3, t_index, csr, taff);

    // layer 1 over frontier2
    list_layer_kernel<<<M_TOT / 32, 256, 0, stream>>>(
        hA, hB, rel + (size_t)1 * NB * NR * ND,
        Wph + (size_t)1 * 2 * 13 * 64 * 8, Wpl + (size_t)1 * 2 * 13 * 64 * 8,
        layer_b + ND, logsum, begdeg, csr, h_index, r_index, query_weight, cnt2, list2);

    // layer 2 backward-sliced to flagged t rows
    list_layer_kernel<<<M_TOT / 32, 256, 0, stream>>>(
        hB, hA, rel + (size_t)2 * NB * NR * ND,
        Wph + (size_t)2 * 2 * 13 * 64 * 8, Wpl + (size_t)2 * 2 * 13 * 64 * 8,
        layer_b + 2 * ND, logsum, begdeg, csr, h_index, r_index, query_weight,
        cnt3, list3);

    score_kernel<<<NB * NT, 64, 0, stream>>>(hA, t_index, taff, layer_b + 2 * ND,
                                             r_index, query_weight,
                                             mlp_w1, mlp_b1, mlp_w2, mlp_b2, out);
}